// Round 8
// baseline (984.909 us; speedup 1.0000x reference)
//
#include <hip/hip_runtime.h>

#define NN 50000
#define NPAD 50048     // 391 * 128
#define NBLK 391
#define NE 400000
#define NBATCH 8
#define NDIM 32
#define EDIM 16
#define H 128
#define NLAYERS 3
#define CHUNK_ELEMS 4096   // node-kernel weight chunk: 2 hilo * 4 nt * 64 lane * 8
#define NODE_CHUNKS 24     // 16 (Wu, K=256) + 8 (uW2, K=128)
#define ZW_CHUNK 8192      // zdzs chunk: 2 hilo * 8 nt * 64 lane * 8
#define EAB 512            // edges per block in edge_aggr (4 waves x 128)

typedef __attribute__((ext_vector_type(8))) __bf16 bf16x8;
typedef __attribute__((ext_vector_type(16))) float f32x16;
typedef __attribute__((ext_vector_type(8))) short short8;

__device__ __forceinline__ void block_sync_lds() {
  asm volatile("s_waitcnt lgkmcnt(0)\ns_barrier" ::: "memory");
}
__device__ __forceinline__ void wait_lds() {
  asm volatile("s_waitcnt lgkmcnt(0)" ::: "memory");
}

// ---------------- node embedding: h = x @ Wn + bn ----------------
__global__ __launch_bounds__(128) void embed_nodes_kernel(
    const float* __restrict__ x, const float* __restrict__ Wn,
    const float* __restrict__ bn, float* __restrict__ h) {
  __shared__ float Ws[NDIM * H];
  __shared__ float xs[16 * NDIM];
  int j = threadIdx.x;
  int nbase = blockIdx.x * 16;
  for (int r = 0; r < NDIM; ++r) Ws[r * H + j] = Wn[r * H + j];
#pragma unroll
  for (int t = 0; t < 4; ++t) {
    int f = j + t * 128;
    xs[f] = x[nbase * NDIM + f];
  }
  __syncthreads();
  float b = bn[j];
  for (int nn = 0; nn < 16; ++nn) {
    float acc = b;
#pragma unroll
    for (int k = 0; k < NDIM; ++k)
      acc = fmaf(xs[nn * NDIM + k], Ws[k * H + j], acc);
    h[(size_t)(nbase + nn) * H + j] = acc;
  }
}

// ---------------- degree histogram over dst ----------------
__global__ __launch_bounds__(256) void degree_kernel(const int* __restrict__ ei,
                                                     int* __restrict__ deg) {
  int e = blockIdx.x * 256 + threadIdx.x;
  if (e < NE) atomicAdd(&deg[ei[NE + e]], 1);
}

// ---------------- exclusive prefix sum of deg -> cursor (one block) ----------------
#define SCAN_T 1024
#define SCAN_C 49  // 1024*49 >= 50000
__global__ __launch_bounds__(SCAN_T) void scan_kernel(
    const int* __restrict__ deg, int* __restrict__ cursor) {
  __shared__ int part[SCAN_T];
  int t = threadIdx.x;
  int base = t * SCAN_C;
  int s = 0;
  for (int i = 0; i < SCAN_C; ++i) {
    int idx = base + i;
    if (idx < NN) s += deg[idx];
  }
  part[t] = s;
  __syncthreads();
  for (int off = 1; off < SCAN_T; off <<= 1) {
    int v = (t >= off) ? part[t - off] : 0;
    __syncthreads();
    part[t] += v;
    __syncthreads();
  }
  int running = part[t] - s;  // exclusive prefix of this thread's segment
  for (int i = 0; i < SCAN_C; ++i) {
    int idx = base + i;
    if (idx < NN) {
      cursor[idx] = running;
      running += deg[idx];
    }
  }
}

// ---------------- counting-sort scatter: edges grouped by dst ----------------
__global__ __launch_bounds__(256) void scatter_kernel(
    const int* __restrict__ ei, int* __restrict__ cursor,
    int* __restrict__ srcSrt, int* __restrict__ dstSrt,
    int* __restrict__ eidSrt) {
  int e = blockIdx.x * 256 + threadIdx.x;
  if (e < NE) {
    int d = ei[NE + e];
    int pos = atomicAdd(&cursor[d], 1);
    dstSrt[pos] = d;
    srcSrt[pos] = ei[e];
    eidSrt[pos] = e;
  }
}

// ---------------- zdzs weights: mW1[0:256] -> hi/lo bf16, frag-swizzled ----------------
// ZW[l][c][hilo][nt8][lane][8]; col n=nt*32+(lane&31); k=c*16+(lane>>5)*8+j
// n<128: W_d = mW1[k][n]; n>=128: W_s = mW1[128+k][n-128]
__global__ __launch_bounds__(256) void precomp_zw_kernel(
    const float* __restrict__ mW1, __bf16* __restrict__ ZW) {
  int l = blockIdx.x / 8;
  int c = blockIdx.x % 8;
  int tid = threadIdx.x;
  const float* w1 = mW1 + (size_t)l * 384 * H;
  __bf16* dst = ZW + ((size_t)l * 8 + c) * ZW_CHUNK;
  for (int it = 0; it < 32; ++it) {
    int flat = it * 256 + tid;
    int j = flat & 7;
    int lane = (flat >> 3) & 63;
    int nt = (flat >> 9) & 7;
    int hilo = flat >> 12;
    int k = c * 16 + ((lane >> 5) << 3) + j;
    int n = nt * 32 + (lane & 31);
    float w = (n < 128) ? w1[(size_t)k * H + n]
                        : w1[(size_t)(128 + k) * H + (n - 128)];
    __bf16 hi = (__bf16)w;
    __bf16 lo = (__bf16)(w - (float)hi);
    dst[flat] = hilo ? lo : hi;
  }
}

// ---------------- Wef = We @ mW1[256:384] (16x128), bm = mb1 + be @ mW1[256:384] ----------------
__global__ __launch_bounds__(128) void precomp_wef_kernel(
    const float* __restrict__ mW1, const float* __restrict__ mb1,
    const float* __restrict__ We, const float* __restrict__ be,
    float* __restrict__ Wef, float* __restrict__ bm) {
  int l = blockIdx.x;
  int n = threadIdx.x;
  const float* w1 = mW1 + (size_t)l * 384 * H;
  for (int i = 0; i < EDIM; ++i) {
    float s = 0.f;
    for (int c = 0; c < H; ++c)
      s = fmaf(We[i * H + c], w1[(size_t)(256 + c) * H + n], s);
    Wef[((size_t)l * EDIM + i) * H + n] = s;
  }
  float s = mb1[l * H + n];
  for (int c = 0; c < H; ++c)
    s = fmaf(be[c], w1[(size_t)(256 + c) * H + n], s);
  bm[l * H + n] = s;
}

// ---------------- precompute folded update weights (fp32 Wu) ----------------
__global__ __launch_bounds__(128) void precomp_wu_kernel(
    const float* __restrict__ uW1, const float* __restrict__ mW2,
    const float* __restrict__ mb2, float* __restrict__ Wu,
    float* __restrict__ va) {
  int l = blockIdx.x / 257;
  int r = blockIdx.x % 257;
  int j = threadIdx.x;
  const float* u1 = uW1 + (size_t)l * 256 * H;
  if (r < 128) {
    Wu[((size_t)l * 256 + r) * H + j] = u1[(size_t)r * H + j];
  } else if (r < 256) {
    int i = r - 128;
    const float* m2 = mW2 + ((size_t)l * H + i) * H;
    float s = 0.f;
    for (int c = 0; c < H; ++c)
      s = fmaf(m2[c], u1[(size_t)(128 + c) * H + j], s);
    Wu[((size_t)l * 256 + r) * H + j] = s;
  } else {
    float s = 0.f;
    for (int c = 0; c < H; ++c)
      s = fmaf(mb2[l * H + c], u1[(size_t)(128 + c) * H + j], s);
    va[l * H + j] = s;
  }
}

// ---------------- swizzle node weights (Wu fp32 + uW2) into hi/lo frag chunks ----------------
__global__ __launch_bounds__(256) void precomp_wns_kernel(
    const float* __restrict__ Wu, const float* __restrict__ uW2,
    __bf16* __restrict__ WnS) {
  int l = blockIdx.x / NODE_CHUNKS;
  int c = blockIdx.x % NODE_CHUNKS;
  int tid = threadIdx.x;
  int nt = tid >> 6, lane = tid & 63;
  int n = nt * 32 + (lane & 31);
  int half = lane >> 5;
  __bf16* dst = WnS + ((size_t)l * NODE_CHUNKS + c) * CHUNK_ELEMS;
#pragma unroll
  for (int j = 0; j < 8; ++j) {
    float w;
    if (c < 16) {
      int k = c * 16 + half * 8 + j;
      w = Wu[((size_t)l * 256 + k) * H + n];
    } else {
      int k = (c - 16) * 16 + half * 8 + j;
      w = uW2[((size_t)l * H + k) * H + n];
    }
    __bf16 hi = (__bf16)w;
    __bf16 lo = (__bf16)(w - (float)hi);
    dst[((0 * 4 + nt) * 64 + lane) * 8 + j] = hi;
    dst[((1 * 4 + nt) * 64 + lane) * 8 + j] = lo;
  }
}

// ---------------- z = h @ [W_d|W_s] (+bm on dst half): dense MFMA GEMM ----------------
// 128 rows/block, 4 waves x (32 rows x 256 cols), K=128 in 8 chunks, 3-term split.
__global__ __launch_bounds__(256) void zdzs_kernel(
    const float* __restrict__ h, const __bf16* __restrict__ ZW,
    const float* __restrict__ bm, float* __restrict__ z) {
  __shared__ __align__(16) __bf16 Bt[2][ZW_CHUNK];  // 32 KB
  int tid = threadIdx.x;
  int wid = tid >> 6, lane = tid & 63, m = lane & 31, half = lane >> 5;
  int nb = blockIdx.x * 128;
  int row = nb + wid * 32 + m;
  const float* aH = h + (size_t)row * H + half * 8;
  const short8* gW = (const short8*)ZW;  // 1024 short8 per chunk
  short8* sB0 = (short8*)&Bt[0][0];
  short8* sB1 = (short8*)&Bt[1][0];
#pragma unroll
  for (int q = 0; q < 4; ++q) sB0[tid + q * 256] = gW[tid + q * 256];
  short8 p0 = gW[1024 + tid], p1 = gW[1024 + tid + 256];
  short8 p2 = gW[1024 + tid + 512], p3 = gW[1024 + tid + 768];
  f32x16 acc[8];
#pragma unroll
  for (int nt = 0; nt < 8; ++nt)
#pragma unroll
    for (int r = 0; r < 16; ++r) acc[nt][r] = 0.f;
  float4 a0 = *(const float4*)aH;
  float4 a1 = *(const float4*)(aH + 4);
  block_sync_lds();

  for (int s = 0; s < 8; ++s) {
    int buf = s & 1;
    float4 na0 = a0, na1 = a1;
    if (s + 1 < 8) {
      const float* pp = aH + (s + 1) * 16;
      na0 = *(const float4*)pp;
      na1 = *(const float4*)(pp + 4);
    }
    if (s + 1 < 8) {
      short8* sb = buf ? sB0 : sB1;
      sb[tid] = p0;
      sb[tid + 256] = p1;
      sb[tid + 512] = p2;
      sb[tid + 768] = p3;
      if (s + 2 < 8) {
        p0 = gW[(size_t)(s + 2) * 1024 + tid];
        p1 = gW[(size_t)(s + 2) * 1024 + tid + 256];
        p2 = gW[(size_t)(s + 2) * 1024 + tid + 512];
        p3 = gW[(size_t)(s + 2) * 1024 + tid + 768];
      }
    }
    float af[8] = {a0.x, a0.y, a0.z, a0.w, a1.x, a1.y, a1.z, a1.w};
    bf16x8 ah, al;
#pragma unroll
    for (int j = 0; j < 8; ++j) {
      __bf16 hi = (__bf16)af[j];
      ah[j] = hi;
      al[j] = (__bf16)(af[j] - (float)hi);
    }
    const __bf16* bb = &Bt[buf][0];
#pragma unroll
    for (int nt = 0; nt < 8; ++nt) {
      bf16x8 bh = *(const bf16x8*)&bb[((0 * 8 + nt) * 64 + lane) * 8];
      bf16x8 bl = *(const bf16x8*)&bb[((1 * 8 + nt) * 64 + lane) * 8];
      acc[nt] = __builtin_amdgcn_mfma_f32_32x32x16_bf16(ah, bh, acc[nt], 0, 0, 0);
      acc[nt] = __builtin_amdgcn_mfma_f32_32x32x16_bf16(al, bh, acc[nt], 0, 0, 0);
      acc[nt] = __builtin_amdgcn_mfma_f32_32x32x16_bf16(ah, bl, acc[nt], 0, 0, 0);
    }
    a0 = na0;
    a1 = na1;
    if (s + 1 < 8) block_sync_lds();
  }

  float bmv[4];
#pragma unroll
  for (int nt = 0; nt < 4; ++nt) bmv[nt] = bm[nt * 32 + m];
#pragma unroll
  for (int nt = 0; nt < 8; ++nt) {
    float bias = (nt < 4) ? bmv[nt] : 0.f;
#pragma unroll
    for (int r = 0; r < 16; ++r) {
      int rowi = (r & 3) + 8 * (r >> 2) + 4 * half;
      z[(size_t)(nb + wid * 32 + rowi) * 256 + nt * 32 + m] = acc[nt][r] + bias;
    }
  }
}

// ---------------- sorted-edge aggregation: aggr[dst] += relu(z_d+z_s+ea@Wef) ----------------
// 4 waves x 128 sorted edges; lane owns col pair c0=lane*2; Wef in registers;
// depth-4 prefetch; segmented accumulation -> coalesced atomics on dst change.
__global__ __launch_bounds__(256) void edge_aggr_kernel(
    const float* __restrict__ z, const int* __restrict__ srcSrt,
    const int* __restrict__ dstSrt, const int* __restrict__ eidSrt,
    const float* __restrict__ ea, const float* __restrict__ Wef,
    float* __restrict__ aggrH) {
  __shared__ int dstW[EAB], srcW[EAB], eidW[EAB];
  int tid = threadIdx.x;
  int e0b = blockIdx.x * EAB;
#pragma unroll
  for (int q = 0; q < 2; ++q) {
    int idx = tid + q * 256;
    int ge = e0b + idx;
    if (ge < NE) {
      dstW[idx] = dstSrt[ge];
      srcW[idx] = srcSrt[ge];
      eidW[idx] = eidSrt[ge];
    }
  }
  __syncthreads();
  int wid = tid >> 6, lane = tid & 63;
  int wb = wid * 128;
  int cnt = NE - (e0b + wb);
  if (cnt > 128) cnt = 128;
  if (cnt < 0) cnt = 0;
  int c0 = lane * 2;
  float wx[16], wy[16];
#pragma unroll
  for (int k = 0; k < 16; ++k) {
    const float* wp = Wef + (size_t)k * H + c0;
    wx[k] = wp[0];
    wy[k] = wp[1];
  }
  float2 zdb[4], zsb[4];
  float4 ea0b[4], ea1b[4], ea2b[4], ea3b[4];
  int db[4];
#define PREF(p, i)                                                     \
  {                                                                    \
    int d_ = dstW[wb + (i)], s_ = srcW[wb + (i)], e_ = eidW[wb + (i)]; \
    db[p] = d_;                                                        \
    zdb[p] = *(const float2*)(z + (size_t)d_ * 256 + c0);              \
    zsb[p] = *(const float2*)(z + (size_t)s_ * 256 + 128 + c0);        \
    const float4* ep_ = (const float4*)(ea + (size_t)e_ * EDIM);       \
    ea0b[p] = ep_[0];                                                  \
    ea1b[p] = ep_[1];                                                  \
    ea2b[p] = ep_[2];                                                  \
    ea3b[p] = ep_[3];                                                  \
  }
#pragma unroll
  for (int p = 0; p < 4; ++p)
    if (p < cnt) PREF(p, p);
  int cur = (cnt > 0) ? dstW[wb] : 0;
  float accx = 0.f, accy = 0.f;
  for (int ib = 0; ib < cnt; ib += 4) {
#pragma unroll
    for (int p = 0; p < 4; ++p) {
      int i = ib + p;
      if (i < cnt) {
        float2 zd = zdb[p], zs = zsb[p];
        float4 g0 = ea0b[p], g1 = ea1b[p], g2 = ea2b[p], g3 = ea3b[p];
        int d = db[p];
        if (i + 4 < cnt) PREF(p, i + 4);
        float zex, zey;
        zex = g0.x * wx[0];               zey = g0.x * wy[0];
        zex = fmaf(g0.y, wx[1], zex);     zey = fmaf(g0.y, wy[1], zey);
        zex = fmaf(g0.z, wx[2], zex);     zey = fmaf(g0.z, wy[2], zey);
        zex = fmaf(g0.w, wx[3], zex);     zey = fmaf(g0.w, wy[3], zey);
        zex = fmaf(g1.x, wx[4], zex);     zey = fmaf(g1.x, wy[4], zey);
        zex = fmaf(g1.y, wx[5], zex);     zey = fmaf(g1.y, wy[5], zey);
        zex = fmaf(g1.z, wx[6], zex);     zey = fmaf(g1.z, wy[6], zey);
        zex = fmaf(g1.w, wx[7], zex);     zey = fmaf(g1.w, wy[7], zey);
        zex = fmaf(g2.x, wx[8], zex);     zey = fmaf(g2.x, wy[8], zey);
        zex = fmaf(g2.y, wx[9], zex);     zey = fmaf(g2.y, wy[9], zey);
        zex = fmaf(g2.z, wx[10], zex);    zey = fmaf(g2.z, wy[10], zey);
        zex = fmaf(g2.w, wx[11], zex);    zey = fmaf(g2.w, wy[11], zey);
        zex = fmaf(g3.x, wx[12], zex);    zey = fmaf(g3.x, wy[12], zey);
        zex = fmaf(g3.y, wx[13], zex);    zey = fmaf(g3.y, wy[13], zey);
        zex = fmaf(g3.z, wx[14], zex);    zey = fmaf(g3.z, wy[14], zey);
        zex = fmaf(g3.w, wx[15], zex);    zey = fmaf(g3.w, wy[15], zey);
        if (d != cur) {
          float* ap = aggrH + (size_t)cur * H + c0;
          unsafeAtomicAdd(ap, accx);
          unsafeAtomicAdd(ap + 1, accy);
          accx = 0.f;
          accy = 0.f;
          cur = d;
        }
        accx += fmaxf(zd.x + zs.x + zex, 0.f);
        accy += fmaxf(zd.y + zs.y + zey, 0.f);
      }
    }
  }
  if (cnt > 0) {
    float* ap = aggrH + (size_t)cur * H + c0;
    unsafeAtomicAdd(ap, accx);
    unsafeAtomicAdd(ap + 1, accy);
  }
#undef PREF
}

// ---------------- MFMA fused node update (unchanged from r7) ----------------
__global__ __launch_bounds__(256) void node_update_mfma_kernel(
    float* __restrict__ h, const float* __restrict__ aggrH,
    const int* __restrict__ deg, const __bf16* __restrict__ WnS,
    const float* __restrict__ ub1, const float* __restrict__ va,
    const float* __restrict__ ub2) {
  __shared__ __align__(16) __bf16 Bt[2][CHUNK_ELEMS];
  __shared__ __bf16 hid[4][32][132];
  __shared__ float degS[128];
  int tid = threadIdx.x;
  int nb = blockIdx.x * 128;
  if (tid < 128) degS[tid] = (float)deg[nb + tid];
  int wid = tid >> 6, lane = tid & 63, m = lane & 31, half = lane >> 5;
  int row = nb + wid * 32 + m;
  const float* aH = h + (size_t)row * H + half * 8;
  const float* aG = aggrH + (size_t)row * H + half * 8;
  const short8* gW = (const short8*)WnS;
  short8* sB0 = (short8*)&Bt[0][0];
  short8* sB1 = (short8*)&Bt[1][0];
  sB0[tid] = gW[tid];
  sB0[tid + 256] = gW[tid + 256];
  short8 p0 = gW[512 + tid], p1 = gW[512 + tid + 256];
  float bv1[4], bva[4];
#pragma unroll
  for (int nt = 0; nt < 4; ++nt) {
    bv1[nt] = ub1[nt * 32 + m];
    bva[nt] = va[nt * 32 + m];
  }
  f32x16 acc[4];
#pragma unroll
  for (int nt = 0; nt < 4; ++nt)
#pragma unroll
    for (int r = 0; r < 16; ++r) acc[nt][r] = 0.f;
  float4 a0 = *(const float4*)aH;
  float4 a1 = *(const float4*)(aH + 4);
  block_sync_lds();

  for (int s = 0; s < 16; ++s) {
    int buf = s & 1;
    float4 na0 = a0, na1 = a1;
    if (s + 1 < 16) {
      int sp = s + 1;
      const float* pp = (sp < 8) ? (aH + sp * 16) : (aG + (sp - 8) * 16);
      na0 = *(const float4*)pp;
      na1 = *(const float4*)(pp + 4);
    }
    {
      short8* sb = buf ? sB0 : sB1;
      sb[tid] = p0;
      sb[tid + 256] = p1;
      if (s + 2 < NODE_CHUNKS) {
        p0 = gW[(size_t)(s + 2) * 512 + tid];
        p1 = gW[(size_t)(s + 2) * 512 + tid + 256];
      }
    }
    float af[8] = {a0.x, a0.y, a0.z, a0.w, a1.x, a1.y, a1.z, a1.w};
    bf16x8 ah;
#pragma unroll
    for (int j = 0; j < 8; ++j) ah[j] = (__bf16)af[j];
    const __bf16* bb = &Bt[buf][0];
#pragma unroll
    for (int nt = 0; nt < 4; ++nt) {
      bf16x8 bh = *(const bf16x8*)&bb[((0 * 4 + nt) * 64 + lane) * 8];
      bf16x8 bl = *(const bf16x8*)&bb[((1 * 4 + nt) * 64 + lane) * 8];
      acc[nt] = __builtin_amdgcn_mfma_f32_32x32x16_bf16(ah, bh, acc[nt], 0, 0, 0);
      acc[nt] = __builtin_amdgcn_mfma_f32_32x32x16_bf16(ah, bl, acc[nt], 0, 0, 0);
    }
    a0 = na0;
    a1 = na1;
    block_sync_lds();
  }

#pragma unroll
  for (int nt = 0; nt < 4; ++nt) {
#pragma unroll
    for (int r = 0; r < 16; ++r) {
      int rowi = (r & 3) + 8 * (r >> 2) + 4 * half;
      float v = acc[nt][r] + bv1[nt] + degS[wid * 32 + rowi] * bva[nt];
      hid[wid][rowi][nt * 32 + m] = (__bf16)fmaxf(v, 0.f);
      acc[nt][r] = 0.f;
    }
  }
  wait_lds();

  for (int s = 16; s < NODE_CHUNKS; ++s) {
    int buf = s & 1;
    if (s + 1 < NODE_CHUNKS) {
      short8* sb = buf ? sB0 : sB1;
      sb[tid] = p0;
      sb[tid + 256] = p1;
      if (s + 2 < NODE_CHUNKS) {
        p0 = gW[(size_t)(s + 2) * 512 + tid];
        p1 = gW[(size_t)(s + 2) * 512 + tid + 256];
      }
    }
    bf16x8 ah = *(const bf16x8*)&hid[wid][m][(s - 16) * 16 + half * 8];
    const __bf16* bb = &Bt[buf][0];
#pragma unroll
    for (int nt = 0; nt < 4; ++nt) {
      bf16x8 bh = *(const bf16x8*)&bb[((0 * 4 + nt) * 64 + lane) * 8];
      bf16x8 bl = *(const bf16x8*)&bb[((1 * 4 + nt) * 64 + lane) * 8];
      acc[nt] = __builtin_amdgcn_mfma_f32_32x32x16_bf16(ah, bh, acc[nt], 0, 0, 0);
      acc[nt] = __builtin_amdgcn_mfma_f32_32x32x16_bf16(ah, bl, acc[nt], 0, 0, 0);
    }
    if (s + 1 < NODE_CHUNKS) block_sync_lds();
  }

#pragma unroll
  for (int nt = 0; nt < 4; ++nt) {
    float b2 = ub2[nt * 32 + m];
#pragma unroll
    for (int r = 0; r < 16; ++r) {
      int rowi = (r & 3) + 8 * (r >> 2) + 4 * half;
      float* hp = h + (size_t)(nb + wid * 32 + rowi) * H + nt * 32 + m;
      *hp += acc[nt][r] + b2;
    }
  }
}

// ---------------- batch mean pooling (batch is sorted) ----------------
__global__ __launch_bounds__(128) void pool_kernel(
    const float* __restrict__ h, const int* __restrict__ batch,
    float* __restrict__ pooled, int* __restrict__ counts) {
  int j = threadIdx.x;
  int nbase = blockIdx.x * 128;
  int nend = nbase + 128;
  if (nend > NN) nend = NN;
  if (nbase >= NN) return;
  int cur = batch[nbase];
  float sum = 0.f;
  int cnt = 0;
  for (int n = nbase; n < nend; ++n) {
    int b = batch[n];
    if (b != cur) {
      unsafeAtomicAdd(&pooled[cur * H + j], sum);
      if (j == 0) atomicAdd(&counts[cur], cnt);
      sum = 0.f; cnt = 0; cur = b;
    }
    sum += h[(size_t)n * H + j];
    cnt++;
  }
  unsafeAtomicAdd(&pooled[cur * H + j], sum);
  if (j == 0) atomicAdd(&counts[cur], cnt);
}

// ---------------- readout MLP ----------------
__global__ __launch_bounds__(128) void readout_kernel(
    const float* __restrict__ pooled, const int* __restrict__ counts,
    const float* __restrict__ gf, const float* __restrict__ Wg,
    const float* __restrict__ bg, const float* __restrict__ rW1,
    const float* __restrict__ rb1, const float* __restrict__ rW2,
    const float* __restrict__ rb2, const float* __restrict__ rW3,
    const float* __restrict__ rb3, float* __restrict__ out) {
  __shared__ float fin[256];
  __shared__ float t1[128];
  __shared__ float t2[64];
  int j = threadIdx.x;
  for (int b = 0; b < NBATCH; ++b) {
    float cnt = (float)counts[b];
    if (cnt < 1.f) cnt = 1.f;
    fin[j] = pooled[b * H + j] / cnt;
    fin[H + j] = fmaf(gf[b], Wg[j], bg[j]);
    __syncthreads();
    float a = rb1[j];
    for (int k = 0; k < 256; ++k) a = fmaf(fin[k], rW1[k * H + j], a);
    t1[j] = fmaxf(a, 0.f);
    __syncthreads();
    if (j < 64) {
      float a2 = rb2[j];
      for (int k = 0; k < 128; ++k) a2 = fmaf(t1[k], rW2[k * 64 + j], a2);
      t2[j] = fmaxf(a2, 0.f);
    }
    __syncthreads();
    if (j < 64) {
      float p = t2[j] * rW3[j];
#pragma unroll
      for (int off = 32; off; off >>= 1) p += __shfl_down(p, off);
      if (j == 0) out[b] = p + rb3[0];
    }
    __syncthreads();
  }
}

extern "C" void kernel_launch(void* const* d_in, const int* in_sizes, int n_in,
                              void* d_out, int out_size, void* d_ws, size_t ws_size,
                              hipStream_t stream) {
  const float* x   = (const float*)d_in[0];
  const float* ea  = (const float*)d_in[1];
  const float* gf  = (const float*)d_in[2];
  const int*   ei  = (const int*)d_in[3];
  const int*   bat = (const int*)d_in[4];
  const float* Wn  = (const float*)d_in[5];
  const float* bn  = (const float*)d_in[6];
  const float* We  = (const float*)d_in[7];
  const float* be  = (const float*)d_in[8];
  const float* Wg  = (const float*)d_in[9];
  const float* bg  = (const float*)d_in[10];
  const float* mW1 = (const float*)d_in[11];
  const float* mb1 = (const float*)d_in[12];
  const float* mW2 = (const float*)d_in[13];
  const float* mb2 = (const float*)d_in[14];
  const float* uW1 = (const float*)d_in[15];
  const float* ub1 = (const float*)d_in[16];
  const float* uW2 = (const float*)d_in[17];
  const float* ub2 = (const float*)d_in[18];
  const float* rW1 = (const float*)d_in[19];
  const float* rb1 = (const float*)d_in[20];
  const float* rW2 = (const float*)d_in[21];
  const float* rb2 = (const float*)d_in[22];
  const float* rW3 = (const float*)d_in[23];
  const float* rb3 = (const float*)d_in[24];

  char* p = (char*)d_ws;
  float*  h      = (float*)p;  p += (size_t)NPAD * H * 4;        // 25.6 MB
  float*  aggrH  = (float*)p;  p += (size_t)NPAD * H * 4;        // 25.6 MB
  float*  z      = (float*)p;  p += (size_t)NPAD * 256 * 4;      // 51.2 MB
  int*    srcSrt = (int*)p;    p += (size_t)NE * 4;              // 1.6 MB
  int*    dstSrt = (int*)p;    p += (size_t)NE * 4;
  int*    eidSrt = (int*)p;    p += (size_t)NE * 4;
  __bf16* ZW     = (__bf16*)p; p += (size_t)NLAYERS * 8 * ZW_CHUNK * 2;        // 384 KB
  __bf16* WnS    = (__bf16*)p; p += (size_t)NLAYERS * NODE_CHUNKS * CHUNK_ELEMS * 2;
  float*  Wef    = (float*)p;  p += (size_t)NLAYERS * EDIM * H * 4;
  float*  bm     = (float*)p;  p += (size_t)NLAYERS * H * 4;
  float*  Wu     = (float*)p;  p += (size_t)NLAYERS * 256 * H * 4;
  float*  va     = (float*)p;  p += (size_t)NLAYERS * H * 4;
  int*    deg    = (int*)p;    p += (size_t)NPAD * 4;
  int*    cursor = (int*)p;    p += (size_t)NPAD * 4;
  float*  pooled = (float*)p;  p += (size_t)NBATCH * H * 4;
  int*    counts = (int*)p;    p += 64;

  hipMemsetAsync(deg, 0, (size_t)NPAD * 4, stream);
  hipMemsetAsync(pooled, 0, (size_t)NBATCH * H * 4, stream);
  hipMemsetAsync(counts, 0, 64, stream);

  embed_nodes_kernel<<<NN / 16, 128, 0, stream>>>(x, Wn, bn, h);
  degree_kernel<<<(NE + 255) / 256, 256, 0, stream>>>(ei, deg);
  scan_kernel<<<1, SCAN_T, 0, stream>>>(deg, cursor);
  scatter_kernel<<<(NE + 255) / 256, 256, 0, stream>>>(ei, cursor, srcSrt,
                                                       dstSrt, eidSrt);
  precomp_zw_kernel<<<NLAYERS * 8, 256, 0, stream>>>(mW1, ZW);
  precomp_wef_kernel<<<NLAYERS, 128, 0, stream>>>(mW1, mb1, We, be, Wef, bm);
  precomp_wu_kernel<<<NLAYERS * 257, 128, 0, stream>>>(uW1, mW2, mb2, Wu, va);
  precomp_wns_kernel<<<NLAYERS * NODE_CHUNKS, 256, 0, stream>>>(Wu, uW2, WnS);

  for (int l = 0; l < NLAYERS; ++l) {
    hipMemsetAsync(aggrH, 0, (size_t)NPAD * H * 4, stream);
    zdzs_kernel<<<NBLK, 256, 0, stream>>>(
        h, ZW + (size_t)l * 8 * ZW_CHUNK, bm + (size_t)l * H, z);
    edge_aggr_kernel<<<(NE + EAB - 1) / EAB, 256, 0, stream>>>(
        z, srcSrt, dstSrt, eidSrt, ea, Wef + (size_t)l * EDIM * H, aggrH);
    node_update_mfma_kernel<<<NBLK, 256, 0, stream>>>(
        h, aggrH, deg, WnS + (size_t)l * NODE_CHUNKS * CHUNK_ELEMS,
        ub1 + (size_t)l * H, va + (size_t)l * H, ub2 + (size_t)l * H);
  }

  pool_kernel<<<(NN + 127) / 128, 128, 0, stream>>>(h, bat, pooled, counts);
  readout_kernel<<<1, 128, 0, stream>>>(pooled, counts, gf, Wg, bg, rW1, rb1,
                                        rW2, rb2, rW3, rb3, (float*)d_out);
}

// Round 9
// 929.025 us; speedup vs baseline: 1.0602x; 1.0602x over previous
//
#include <hip/hip_runtime.h>

#define NN 50000
#define NPAD 50048     // 391 * 128
#define NBLK 391
#define NE 400000
#define NBATCH 8
#define NDIM 32
#define EDIM 16
#define H 128
#define NLAYERS 3
#define CHUNK_ELEMS 4096   // node-kernel weight chunk: 2 hilo * 4 nt * 64 lane * 8
#define NODE_CHUNKS 24     // 16 (Wu, K=256) + 8 (uW2, K=128)
#define ZW_CHUNK 8192      // zdzs chunk: 2 hilo * 8 nt * 64 lane * 8
#define EAB 256            // edges per block in edge_aggr (4 waves x 64)

typedef __attribute__((ext_vector_type(8))) __bf16 bf16x8;
typedef __attribute__((ext_vector_type(16))) float f32x16;
typedef __attribute__((ext_vector_type(8))) short short8;

__device__ __forceinline__ void block_sync_lds() {
  asm volatile("s_waitcnt lgkmcnt(0)\ns_barrier" ::: "memory");
}
__device__ __forceinline__ void wait_lds() {
  asm volatile("s_waitcnt lgkmcnt(0)" ::: "memory");
}

// ---------------- node embedding: h = x @ Wn + bn ----------------
__global__ __launch_bounds__(128) void embed_nodes_kernel(
    const float* __restrict__ x, const float* __restrict__ Wn,
    const float* __restrict__ bn, float* __restrict__ h) {
  __shared__ float Ws[NDIM * H];
  __shared__ float xs[16 * NDIM];
  int j = threadIdx.x;
  int nbase = blockIdx.x * 16;
  for (int r = 0; r < NDIM; ++r) Ws[r * H + j] = Wn[r * H + j];
#pragma unroll
  for (int t = 0; t < 4; ++t) {
    int f = j + t * 128;
    xs[f] = x[nbase * NDIM + f];
  }
  __syncthreads();
  float b = bn[j];
  for (int nn = 0; nn < 16; ++nn) {
    float acc = b;
#pragma unroll
    for (int k = 0; k < NDIM; ++k)
      acc = fmaf(xs[nn * NDIM + k], Ws[k * H + j], acc);
    h[(size_t)(nbase + nn) * H + j] = acc;
  }
}

// ---------------- degree histogram over dst ----------------
__global__ __launch_bounds__(256) void degree_kernel(const int* __restrict__ ei,
                                                     int* __restrict__ deg) {
  int e = blockIdx.x * 256 + threadIdx.x;
  if (e < NE) atomicAdd(&deg[ei[NE + e]], 1);
}

// ---------------- exclusive prefix sum of deg -> cursor (one block) ----------------
#define SCAN_T 1024
#define SCAN_C 49  // 1024*49 >= 50000
__global__ __launch_bounds__(SCAN_T) void scan_kernel(
    const int* __restrict__ deg, int* __restrict__ cursor) {
  __shared__ int part[SCAN_T];
  int t = threadIdx.x;
  int base = t * SCAN_C;
  int s = 0;
  for (int i = 0; i < SCAN_C; ++i) {
    int idx = base + i;
    if (idx < NN) s += deg[idx];
  }
  part[t] = s;
  __syncthreads();
  for (int off = 1; off < SCAN_T; off <<= 1) {
    int v = (t >= off) ? part[t - off] : 0;
    __syncthreads();
    part[t] += v;
    __syncthreads();
  }
  int running = part[t] - s;  // exclusive prefix of this thread's segment
  for (int i = 0; i < SCAN_C; ++i) {
    int idx = base + i;
    if (idx < NN) {
      cursor[idx] = running;
      running += deg[idx];
    }
  }
}

// ---------------- counting-sort scatter: edges grouped by dst ----------------
__global__ __launch_bounds__(256) void scatter_kernel(
    const int* __restrict__ ei, int* __restrict__ cursor,
    int* __restrict__ srcSrt, int* __restrict__ dstSrt,
    int* __restrict__ eidSrt) {
  int e = blockIdx.x * 256 + threadIdx.x;
  if (e < NE) {
    int d = ei[NE + e];
    int pos = atomicAdd(&cursor[d], 1);
    dstSrt[pos] = d;
    srcSrt[pos] = ei[e];
    eidSrt[pos] = e;
  }
}

// ---------------- gather edge attrs into sorted order (once) ----------------
__global__ __launch_bounds__(256) void gather_ea_kernel(
    const float* __restrict__ ea, const int* __restrict__ eidSrt,
    float* __restrict__ eaSrt) {
  int j = blockIdx.x * 1024 + threadIdx.x * 4;  // float4 worth of floats
  int fl = j >> 4;  // edge (16 floats each)
  int q = (j >> 2) & 3;
  if (fl < NE) {
    int e = eidSrt[fl];
    float4 v = ((const float4*)(ea + (size_t)e * EDIM))[q];
    *(float4*)(eaSrt + (size_t)fl * EDIM + q * 4) = v;
  }
}

// ---------------- zdzs weights: mW1[0:256] -> hi/lo bf16, frag-swizzled ----------------
__global__ __launch_bounds__(256) void precomp_zw_kernel(
    const float* __restrict__ mW1, __bf16* __restrict__ ZW) {
  int l = blockIdx.x / 8;
  int c = blockIdx.x % 8;
  int tid = threadIdx.x;
  const float* w1 = mW1 + (size_t)l * 384 * H;
  __bf16* dst = ZW + ((size_t)l * 8 + c) * ZW_CHUNK;
  for (int it = 0; it < 32; ++it) {
    int flat = it * 256 + tid;
    int j = flat & 7;
    int lane = (flat >> 3) & 63;
    int nt = (flat >> 9) & 7;
    int hilo = flat >> 12;
    int k = c * 16 + ((lane >> 5) << 3) + j;
    int n = nt * 32 + (lane & 31);
    float w = (n < 128) ? w1[(size_t)k * H + n]
                        : w1[(size_t)(128 + k) * H + (n - 128)];
    __bf16 hi = (__bf16)w;
    __bf16 lo = (__bf16)(w - (float)hi);
    dst[flat] = hilo ? lo : hi;
  }
}

// ---------------- Wef = We @ mW1[256:384] (16x128), bm = mb1 + be @ ... ----------------
__global__ __launch_bounds__(128) void precomp_wef_kernel(
    const float* __restrict__ mW1, const float* __restrict__ mb1,
    const float* __restrict__ We, const float* __restrict__ be,
    float* __restrict__ Wef, float* __restrict__ bm) {
  int l = blockIdx.x;
  int n = threadIdx.x;
  const float* w1 = mW1 + (size_t)l * 384 * H;
  for (int i = 0; i < EDIM; ++i) {
    float s = 0.f;
    for (int c = 0; c < H; ++c)
      s = fmaf(We[i * H + c], w1[(size_t)(256 + c) * H + n], s);
    Wef[((size_t)l * EDIM + i) * H + n] = s;
  }
  float s = mb1[l * H + n];
  for (int c = 0; c < H; ++c)
    s = fmaf(be[c], w1[(size_t)(256 + c) * H + n], s);
  bm[l * H + n] = s;
}

// ---------------- precompute folded update weights (fp32 Wu) ----------------
__global__ __launch_bounds__(128) void precomp_wu_kernel(
    const float* __restrict__ uW1, const float* __restrict__ mW2,
    const float* __restrict__ mb2, float* __restrict__ Wu,
    float* __restrict__ va) {
  int l = blockIdx.x / 257;
  int r = blockIdx.x % 257;
  int j = threadIdx.x;
  const float* u1 = uW1 + (size_t)l * 256 * H;
  if (r < 128) {
    Wu[((size_t)l * 256 + r) * H + j] = u1[(size_t)r * H + j];
  } else if (r < 256) {
    int i = r - 128;
    const float* m2 = mW2 + ((size_t)l * H + i) * H;
    float s = 0.f;
    for (int c = 0; c < H; ++c)
      s = fmaf(m2[c], u1[(size_t)(128 + c) * H + j], s);
    Wu[((size_t)l * 256 + r) * H + j] = s;
  } else {
    float s = 0.f;
    for (int c = 0; c < H; ++c)
      s = fmaf(mb2[l * H + c], u1[(size_t)(128 + c) * H + j], s);
    va[l * H + j] = s;
  }
}

// ---------------- swizzle node weights into hi/lo frag chunks ----------------
__global__ __launch_bounds__(256) void precomp_wns_kernel(
    const float* __restrict__ Wu, const float* __restrict__ uW2,
    __bf16* __restrict__ WnS) {
  int l = blockIdx.x / NODE_CHUNKS;
  int c = blockIdx.x % NODE_CHUNKS;
  int tid = threadIdx.x;
  int nt = tid >> 6, lane = tid & 63;
  int n = nt * 32 + (lane & 31);
  int half = lane >> 5;
  __bf16* dst = WnS + ((size_t)l * NODE_CHUNKS + c) * CHUNK_ELEMS;
#pragma unroll
  for (int j = 0; j < 8; ++j) {
    float w;
    if (c < 16) {
      int k = c * 16 + half * 8 + j;
      w = Wu[((size_t)l * 256 + k) * H + n];
    } else {
      int k = (c - 16) * 16 + half * 8 + j;
      w = uW2[((size_t)l * H + k) * H + n];
    }
    __bf16 hi = (__bf16)w;
    __bf16 lo = (__bf16)(w - (float)hi);
    dst[((0 * 4 + nt) * 64 + lane) * 8 + j] = hi;
    dst[((1 * 4 + nt) * 64 + lane) * 8 + j] = lo;
  }
}

// ---------------- z = h @ [W_d|W_s] (+bm on dst half): dense MFMA GEMM ----------------
__global__ __launch_bounds__(256) void zdzs_kernel(
    const float* __restrict__ h, const __bf16* __restrict__ ZW,
    const float* __restrict__ bm, float* __restrict__ z) {
  __shared__ __align__(16) __bf16 Bt[2][ZW_CHUNK];  // 32 KB
  int tid = threadIdx.x;
  int wid = tid >> 6, lane = tid & 63, m = lane & 31, half = lane >> 5;
  int nb = blockIdx.x * 128;
  int row = nb + wid * 32 + m;
  const float* aH = h + (size_t)row * H + half * 8;
  const short8* gW = (const short8*)ZW;  // 1024 short8 per chunk
  short8* sB0 = (short8*)&Bt[0][0];
  short8* sB1 = (short8*)&Bt[1][0];
#pragma unroll
  for (int q = 0; q < 4; ++q) sB0[tid + q * 256] = gW[tid + q * 256];
  short8 p0 = gW[1024 + tid], p1 = gW[1024 + tid + 256];
  short8 p2 = gW[1024 + tid + 512], p3 = gW[1024 + tid + 768];
  f32x16 acc[8];
#pragma unroll
  for (int nt = 0; nt < 8; ++nt)
#pragma unroll
    for (int r = 0; r < 16; ++r) acc[nt][r] = 0.f;
  float4 a0 = *(const float4*)aH;
  float4 a1 = *(const float4*)(aH + 4);
  block_sync_lds();

  for (int s = 0; s < 8; ++s) {
    int buf = s & 1;
    float4 na0 = a0, na1 = a1;
    if (s + 1 < 8) {
      const float* pp = aH + (s + 1) * 16;
      na0 = *(const float4*)pp;
      na1 = *(const float4*)(pp + 4);
    }
    if (s + 1 < 8) {
      short8* sb = buf ? sB0 : sB1;
      sb[tid] = p0;
      sb[tid + 256] = p1;
      sb[tid + 512] = p2;
      sb[tid + 768] = p3;
      if (s + 2 < 8) {
        p0 = gW[(size_t)(s + 2) * 1024 + tid];
        p1 = gW[(size_t)(s + 2) * 1024 + tid + 256];
        p2 = gW[(size_t)(s + 2) * 1024 + tid + 512];
        p3 = gW[(size_t)(s + 2) * 1024 + tid + 768];
      }
    }
    float af[8] = {a0.x, a0.y, a0.z, a0.w, a1.x, a1.y, a1.z, a1.w};
    bf16x8 ah, al;
#pragma unroll
    for (int j = 0; j < 8; ++j) {
      __bf16 hi = (__bf16)af[j];
      ah[j] = hi;
      al[j] = (__bf16)(af[j] - (float)hi);
    }
    const __bf16* bb = &Bt[buf][0];
#pragma unroll
    for (int nt = 0; nt < 8; ++nt) {
      bf16x8 bh = *(const bf16x8*)&bb[((0 * 8 + nt) * 64 + lane) * 8];
      bf16x8 bl = *(const bf16x8*)&bb[((1 * 8 + nt) * 64 + lane) * 8];
      acc[nt] = __builtin_amdgcn_mfma_f32_32x32x16_bf16(ah, bh, acc[nt], 0, 0, 0);
      acc[nt] = __builtin_amdgcn_mfma_f32_32x32x16_bf16(al, bh, acc[nt], 0, 0, 0);
      acc[nt] = __builtin_amdgcn_mfma_f32_32x32x16_bf16(ah, bl, acc[nt], 0, 0, 0);
    }
    a0 = na0;
    a1 = na1;
    if (s + 1 < 8) block_sync_lds();
  }

  float bmv[4];
#pragma unroll
  for (int nt = 0; nt < 4; ++nt) bmv[nt] = bm[nt * 32 + m];
#pragma unroll
  for (int nt = 0; nt < 8; ++nt) {
    float bias = (nt < 4) ? bmv[nt] : 0.f;
#pragma unroll
    for (int r = 0; r < 16; ++r) {
      int rowi = (r & 3) + 8 * (r >> 2) + 4 * half;
      z[(size_t)(nb + wid * 32 + rowi) * 256 + nt * 32 + m] = acc[nt][r] + bias;
    }
  }
}

// ---------------- sorted-edge aggregation: aggr[dst] += relu(z_d+z_s+ze) ----------------
// 4 waves x 64 sorted edges; lane owns col pair c0=lane*2; Wef in registers;
// depth-8 z prefetch ring + depth-2 sequential ea ring; segmented accumulation.
__global__ __launch_bounds__(256) void edge_aggr_kernel(
    const float* __restrict__ z, const int* __restrict__ srcSrt,
    const int* __restrict__ dstSrt, const float* __restrict__ eaSrt,
    const float* __restrict__ Wef, float* __restrict__ aggrH) {
  __shared__ int dstW[EAB], srcW[EAB];
  int tid = threadIdx.x;
  int e0b = blockIdx.x * EAB;
  {
    int ge = e0b + tid;
    if (ge < NE) {
      dstW[tid] = dstSrt[ge];
      srcW[tid] = srcSrt[ge];
    }
  }
  __syncthreads();
  int wid = tid >> 6, lane = tid & 63;
  int wb = wid * 64;
  int cnt = NE - (e0b + wb);
  if (cnt > 64) cnt = 64;
  if (cnt < 0) cnt = 0;
  int c0 = lane * 2;
  float wx[16], wy[16];
#pragma unroll
  for (int k = 0; k < 16; ++k) {
    const float* wp = Wef + (size_t)k * H + c0;
    wx[k] = wp[0];
    wy[k] = wp[1];
  }
  const float* eaB = eaSrt + (size_t)(e0b + wb) * EDIM;
  float2 zdb[8], zsb[8];
  int db[8];
  float4 ga[2][4];
#define PREFZ(p, i)                                          \
  {                                                          \
    int d_ = dstW[wb + (i)], s_ = srcW[wb + (i)];            \
    db[p] = d_;                                              \
    zdb[p] = *(const float2*)(z + (size_t)d_ * 256 + c0);    \
    zsb[p] = *(const float2*)(z + (size_t)s_ * 256 + 128 + c0); \
  }
#define PREFA(p, i)                                          \
  {                                                          \
    const float4* ep_ = (const float4*)(eaB + (size_t)(i)*EDIM); \
    ga[p][0] = ep_[0];                                       \
    ga[p][1] = ep_[1];                                       \
    ga[p][2] = ep_[2];                                       \
    ga[p][3] = ep_[3];                                       \
  }
#pragma unroll
  for (int p = 0; p < 8; ++p)
    if (p < cnt) PREFZ(p, p);
#pragma unroll
  for (int p = 0; p < 2; ++p)
    if (p < cnt) PREFA(p, p);
  int cur = (cnt > 0) ? dstW[wb] : 0;
  float accx = 0.f, accy = 0.f;
  for (int ib = 0; ib < cnt; ib += 8) {
#pragma unroll
    for (int p = 0; p < 8; ++p) {
      int i = ib + p;
      if (i < cnt) {
        int pa = i & 1;
        float2 zd = zdb[p], zs = zsb[p];
        int d = db[p];
        float4 g0 = ga[pa][0], g1 = ga[pa][1], g2 = ga[pa][2], g3 = ga[pa][3];
        if (i + 8 < cnt) PREFZ(p, i + 8);
        if (i + 2 < cnt) PREFA(pa, i + 2);
        float zex, zey;
        zex = g0.x * wx[0];               zey = g0.x * wy[0];
        zex = fmaf(g0.y, wx[1], zex);     zey = fmaf(g0.y, wy[1], zey);
        zex = fmaf(g0.z, wx[2], zex);     zey = fmaf(g0.z, wy[2], zey);
        zex = fmaf(g0.w, wx[3], zex);     zey = fmaf(g0.w, wy[3], zey);
        zex = fmaf(g1.x, wx[4], zex);     zey = fmaf(g1.x, wy[4], zey);
        zex = fmaf(g1.y, wx[5], zex);     zey = fmaf(g1.y, wy[5], zey);
        zex = fmaf(g1.z, wx[6], zex);     zey = fmaf(g1.z, wy[6], zey);
        zex = fmaf(g1.w, wx[7], zex);     zey = fmaf(g1.w, wy[7], zey);
        zex = fmaf(g2.x, wx[8], zex);     zey = fmaf(g2.x, wy[8], zey);
        zex = fmaf(g2.y, wx[9], zex);     zey = fmaf(g2.y, wy[9], zey);
        zex = fmaf(g2.z, wx[10], zex);    zey = fmaf(g2.z, wy[10], zey);
        zex = fmaf(g2.w, wx[11], zex);    zey = fmaf(g2.w, wy[11], zey);
        zex = fmaf(g3.x, wx[12], zex);    zey = fmaf(g3.x, wy[12], zey);
        zex = fmaf(g3.y, wx[13], zex);    zey = fmaf(g3.y, wy[13], zey);
        zex = fmaf(g3.z, wx[14], zex);    zey = fmaf(g3.z, wy[14], zey);
        zex = fmaf(g3.w, wx[15], zex);    zey = fmaf(g3.w, wy[15], zey);
        if (d != cur) {
          float* ap = aggrH + (size_t)cur * H + c0;
          unsafeAtomicAdd(ap, accx);
          unsafeAtomicAdd(ap + 1, accy);
          accx = 0.f;
          accy = 0.f;
          cur = d;
        }
        accx += fmaxf(zd.x + zs.x + zex, 0.f);
        accy += fmaxf(zd.y + zs.y + zey, 0.f);
      }
    }
  }
  if (cnt > 0) {
    float* ap = aggrH + (size_t)cur * H + c0;
    unsafeAtomicAdd(ap, accx);
    unsafeAtomicAdd(ap + 1, accy);
  }
#undef PREFZ
#undef PREFA
}

// ---------------- MFMA fused node update ----------------
__global__ __launch_bounds__(256) void node_update_mfma_kernel(
    float* __restrict__ h, const float* __restrict__ aggrH,
    const int* __restrict__ deg, const __bf16* __restrict__ WnS,
    const float* __restrict__ ub1, const float* __restrict__ va,
    const float* __restrict__ ub2) {
  __shared__ __align__(16) __bf16 Bt[2][CHUNK_ELEMS];
  __shared__ __bf16 hid[4][32][132];
  __shared__ float degS[128];
  int tid = threadIdx.x;
  int nb = blockIdx.x * 128;
  if (tid < 128) degS[tid] = (float)deg[nb + tid];
  int wid = tid >> 6, lane = tid & 63, m = lane & 31, half = lane >> 5;
  int row = nb + wid * 32 + m;
  const float* aH = h + (size_t)row * H + half * 8;
  const float* aG = aggrH + (size_t)row * H + half * 8;
  const short8* gW = (const short8*)WnS;
  short8* sB0 = (short8*)&Bt[0][0];
  short8* sB1 = (short8*)&Bt[1][0];
  sB0[tid] = gW[tid];
  sB0[tid + 256] = gW[tid + 256];
  short8 p0 = gW[512 + tid], p1 = gW[512 + tid + 256];
  float bv1[4], bva[4];
#pragma unroll
  for (int nt = 0; nt < 4; ++nt) {
    bv1[nt] = ub1[nt * 32 + m];
    bva[nt] = va[nt * 32 + m];
  }
  f32x16 acc[4];
#pragma unroll
  for (int nt = 0; nt < 4; ++nt)
#pragma unroll
    for (int r = 0; r < 16; ++r) acc[nt][r] = 0.f;
  float4 a0 = *(const float4*)aH;
  float4 a1 = *(const float4*)(aH + 4);
  block_sync_lds();

  for (int s = 0; s < 16; ++s) {
    int buf = s & 1;
    float4 na0 = a0, na1 = a1;
    if (s + 1 < 16) {
      int sp = s + 1;
      const float* pp = (sp < 8) ? (aH + sp * 16) : (aG + (sp - 8) * 16);
      na0 = *(const float4*)pp;
      na1 = *(const float4*)(pp + 4);
    }
    {
      short8* sb = buf ? sB0 : sB1;
      sb[tid] = p0;
      sb[tid + 256] = p1;
      if (s + 2 < NODE_CHUNKS) {
        p0 = gW[(size_t)(s + 2) * 512 + tid];
        p1 = gW[(size_t)(s + 2) * 512 + tid + 256];
      }
    }
    float af[8] = {a0.x, a0.y, a0.z, a0.w, a1.x, a1.y, a1.z, a1.w};
    bf16x8 ah;
#pragma unroll
    for (int j = 0; j < 8; ++j) ah[j] = (__bf16)af[j];
    const __bf16* bb = &Bt[buf][0];
#pragma unroll
    for (int nt = 0; nt < 4; ++nt) {
      bf16x8 bh = *(const bf16x8*)&bb[((0 * 4 + nt) * 64 + lane) * 8];
      bf16x8 bl = *(const bf16x8*)&bb[((1 * 4 + nt) * 64 + lane) * 8];
      acc[nt] = __builtin_amdgcn_mfma_f32_32x32x16_bf16(ah, bh, acc[nt], 0, 0, 0);
      acc[nt] = __builtin_amdgcn_mfma_f32_32x32x16_bf16(ah, bl, acc[nt], 0, 0, 0);
    }
    a0 = na0;
    a1 = na1;
    block_sync_lds();
  }

#pragma unroll
  for (int nt = 0; nt < 4; ++nt) {
#pragma unroll
    for (int r = 0; r < 16; ++r) {
      int rowi = (r & 3) + 8 * (r >> 2) + 4 * half;
      float v = acc[nt][r] + bv1[nt] + degS[wid * 32 + rowi] * bva[nt];
      hid[wid][rowi][nt * 32 + m] = (__bf16)fmaxf(v, 0.f);
      acc[nt][r] = 0.f;
    }
  }
  wait_lds();

  for (int s = 16; s < NODE_CHUNKS; ++s) {
    int buf = s & 1;
    if (s + 1 < NODE_CHUNKS) {
      short8* sb = buf ? sB0 : sB1;
      sb[tid] = p0;
      sb[tid + 256] = p1;
      if (s + 2 < NODE_CHUNKS) {
        p0 = gW[(size_t)(s + 2) * 512 + tid];
        p1 = gW[(size_t)(s + 2) * 512 + tid + 256];
      }
    }
    bf16x8 ah = *(const bf16x8*)&hid[wid][m][(s - 16) * 16 + half * 8];
    const __bf16* bb = &Bt[buf][0];
#pragma unroll
    for (int nt = 0; nt < 4; ++nt) {
      bf16x8 bh = *(const bf16x8*)&bb[((0 * 4 + nt) * 64 + lane) * 8];
      bf16x8 bl = *(const bf16x8*)&bb[((1 * 4 + nt) * 64 + lane) * 8];
      acc[nt] = __builtin_amdgcn_mfma_f32_32x32x16_bf16(ah, bh, acc[nt], 0, 0, 0);
      acc[nt] = __builtin_amdgcn_mfma_f32_32x32x16_bf16(ah, bl, acc[nt], 0, 0, 0);
    }
    if (s + 1 < NODE_CHUNKS) block_sync_lds();
  }

#pragma unroll
  for (int nt = 0; nt < 4; ++nt) {
    float b2 = ub2[nt * 32 + m];
#pragma unroll
    for (int r = 0; r < 16; ++r) {
      int rowi = (r & 3) + 8 * (r >> 2) + 4 * half;
      float* hp = h + (size_t)(nb + wid * 32 + rowi) * H + nt * 32 + m;
      *hp += acc[nt][r] + b2;
    }
  }
}

// ---------------- batch mean pooling (batch is sorted) ----------------
__global__ __launch_bounds__(128) void pool_kernel(
    const float* __restrict__ h, const int* __restrict__ batch,
    float* __restrict__ pooled, int* __restrict__ counts) {
  int j = threadIdx.x;
  int nbase = blockIdx.x * 128;
  int nend = nbase + 128;
  if (nend > NN) nend = NN;
  if (nbase >= NN) return;
  int cur = batch[nbase];
  float sum = 0.f;
  int cnt = 0;
  for (int n = nbase; n < nend; ++n) {
    int b = batch[n];
    if (b != cur) {
      unsafeAtomicAdd(&pooled[cur * H + j], sum);
      if (j == 0) atomicAdd(&counts[cur], cnt);
      sum = 0.f; cnt = 0; cur = b;
    }
    sum += h[(size_t)n * H + j];
    cnt++;
  }
  unsafeAtomicAdd(&pooled[cur * H + j], sum);
  if (j == 0) atomicAdd(&counts[cur], cnt);
}

// ---------------- readout MLP ----------------
__global__ __launch_bounds__(128) void readout_kernel(
    const float* __restrict__ pooled, const int* __restrict__ counts,
    const float* __restrict__ gf, const float* __restrict__ Wg,
    const float* __restrict__ bg, const float* __restrict__ rW1,
    const float* __restrict__ rb1, const float* __restrict__ rW2,
    const float* __restrict__ rb2, const float* __restrict__ rW3,
    const float* __restrict__ rb3, float* __restrict__ out) {
  __shared__ float fin[256];
  __shared__ float t1[128];
  __shared__ float t2[64];
  int j = threadIdx.x;
  for (int b = 0; b < NBATCH; ++b) {
    float cnt = (float)counts[b];
    if (cnt < 1.f) cnt = 1.f;
    fin[j] = pooled[b * H + j] / cnt;
    fin[H + j] = fmaf(gf[b], Wg[j], bg[j]);
    __syncthreads();
    float a = rb1[j];
    for (int k = 0; k < 256; ++k) a = fmaf(fin[k], rW1[k * H + j], a);
    t1[j] = fmaxf(a, 0.f);
    __syncthreads();
    if (j < 64) {
      float a2 = rb2[j];
      for (int k = 0; k < 128; ++k) a2 = fmaf(t1[k], rW2[k * 64 + j], a2);
      t2[j] = fmaxf(a2, 0.f);
    }
    __syncthreads();
    if (j < 64) {
      float p = t2[j] * rW3[j];
#pragma unroll
      for (int off = 32; off; off >>= 1) p += __shfl_down(p, off);
      if (j == 0) out[b] = p + rb3[0];
    }
    __syncthreads();
  }
}

extern "C" void kernel_launch(void* const* d_in, const int* in_sizes, int n_in,
                              void* d_out, int out_size, void* d_ws, size_t ws_size,
                              hipStream_t stream) {
  const float* x   = (const float*)d_in[0];
  const float* ea  = (const float*)d_in[1];
  const float* gf  = (const float*)d_in[2];
  const int*   ei  = (const int*)d_in[3];
  const int*   bat = (const int*)d_in[4];
  const float* Wn  = (const float*)d_in[5];
  const float* bn  = (const float*)d_in[6];
  const float* We  = (const float*)d_in[7];
  const float* be  = (const float*)d_in[8];
  const float* Wg  = (const float*)d_in[9];
  const float* bg  = (const float*)d_in[10];
  const float* mW1 = (const float*)d_in[11];
  const float* mb1 = (const float*)d_in[12];
  const float* mW2 = (const float*)d_in[13];
  const float* mb2 = (const float*)d_in[14];
  const float* uW1 = (const float*)d_in[15];
  const float* ub1 = (const float*)d_in[16];
  const float* uW2 = (const float*)d_in[17];
  const float* ub2 = (const float*)d_in[18];
  const float* rW1 = (const float*)d_in[19];
  const float* rb1 = (const float*)d_in[20];
  const float* rW2 = (const float*)d_in[21];
  const float* rb2 = (const float*)d_in[22];
  const float* rW3 = (const float*)d_in[23];
  const float* rb3 = (const float*)d_in[24];

  char* p = (char*)d_ws;
  float*  h      = (float*)p;  p += (size_t)NPAD * H * 4;        // 25.6 MB
  float*  aggrH  = (float*)p;  p += (size_t)NPAD * H * 4;        // 25.6 MB
  float*  z      = (float*)p;  p += (size_t)NPAD * 256 * 4;      // 51.2 MB
  float*  eaSrt  = (float*)p;  p += (size_t)NE * EDIM * 4;       // 25.6 MB
  int*    srcSrt = (int*)p;    p += (size_t)NE * 4;
  int*    dstSrt = (int*)p;    p += (size_t)NE * 4;
  int*    eidSrt = (int*)p;    p += (size_t)NE * 4;
  __bf16* ZW     = (__bf16*)p; p += (size_t)NLAYERS * 8 * ZW_CHUNK * 2;
  __bf16* WnS    = (__bf16*)p; p += (size_t)NLAYERS * NODE_CHUNKS * CHUNK_ELEMS * 2;
  float*  Wef    = (float*)p;  p += (size_t)NLAYERS * EDIM * H * 4;
  float*  bm     = (float*)p;  p += (size_t)NLAYERS * H * 4;
  float*  Wu     = (float*)p;  p += (size_t)NLAYERS * 256 * H * 4;
  float*  va     = (float*)p;  p += (size_t)NLAYERS * H * 4;
  int*    deg    = (int*)p;    p += (size_t)NPAD * 4;
  int*    cursor = (int*)p;    p += (size_t)NPAD * 4;
  float*  pooled = (float*)p;  p += (size_t)NBATCH * H * 4;
  int*    counts = (int*)p;    p += 64;

  hipMemsetAsync(deg, 0, (size_t)NPAD * 4, stream);
  hipMemsetAsync(pooled, 0, (size_t)NBATCH * H * 4, stream);
  hipMemsetAsync(counts, 0, 64, stream);

  embed_nodes_kernel<<<NN / 16, 128, 0, stream>>>(x, Wn, bn, h);
  degree_kernel<<<(NE + 255) / 256, 256, 0, stream>>>(ei, deg);
  scan_kernel<<<1, SCAN_T, 0, stream>>>(deg, cursor);
  scatter_kernel<<<(NE + 255) / 256, 256, 0, stream>>>(ei, cursor, srcSrt,
                                                       dstSrt, eidSrt);
  gather_ea_kernel<<<(NE * 16 + 1023) / 1024, 256, 0, stream>>>(ea, eidSrt, eaSrt);
  precomp_zw_kernel<<<NLAYERS * 8, 256, 0, stream>>>(mW1, ZW);
  precomp_wef_kernel<<<NLAYERS, 128, 0, stream>>>(mW1, mb1, We, be, Wef, bm);
  precomp_wu_kernel<<<NLAYERS * 257, 128, 0, stream>>>(uW1, mW2, mb2, Wu, va);
  precomp_wns_kernel<<<NLAYERS * NODE_CHUNKS, 256, 0, stream>>>(Wu, uW2, WnS);

  for (int l = 0; l < NLAYERS; ++l) {
    hipMemsetAsync(aggrH, 0, (size_t)NPAD * H * 4, stream);
    zdzs_kernel<<<NBLK, 256, 0, stream>>>(
        h, ZW + (size_t)l * 8 * ZW_CHUNK, bm + (size_t)l * H, z);
    edge_aggr_kernel<<<(NE + EAB - 1) / EAB, 256, 0, stream>>>(
        z, srcSrt, dstSrt, eaSrt, Wef + (size_t)l * EDIM * H, aggrH);
    node_update_mfma_kernel<<<NBLK, 256, 0, stream>>>(
        h, aggrH, deg, WnS + (size_t)l * NODE_CHUNKS * CHUNK_ELEMS,
        ub1 + (size_t)l * H, va + (size_t)l * H, ub2 + (size_t)l * H);
  }

  pool_kernel<<<(NN + 127) / 128, 128, 0, stream>>>(h, bat, pooled, counts);
  readout_kernel<<<1, 128, 0, stream>>>(pooled, counts, gf, Wg, bg, rW1, rb1,
                                        rW2, rb2, rW3, rb3, (float*)d_out);
}

// Round 10
// 769.884 us; speedup vs baseline: 1.2793x; 1.2067x over previous
//
#include <hip/hip_runtime.h>

#define NN 50000
#define NPAD 50048     // 391 * 128
#define NBLK 391
#define NE 400000
#define NBATCH 8
#define NDIM 32
#define EDIM 16
#define H 128
#define NLAYERS 3
#define CHUNK_ELEMS 4096   // node-kernel weight chunk: 2 hilo * 4 nt * 64 lane * 8
#define NODE_CHUNKS 24     // 16 (Wu, K=256) + 8 (uW2, K=128)
#define ZW_CHUNK 8192      // zdzs chunk: 2 hilo * 8 nt * 64 lane * 8
#define EAB 64             // edges per block in edge_aggr (4 waves x 16)

typedef __attribute__((ext_vector_type(8))) __bf16 bf16x8;
typedef __attribute__((ext_vector_type(16))) float f32x16;
typedef __attribute__((ext_vector_type(8))) short short8;
typedef __attribute__((ext_vector_type(2))) float v2f;

__device__ __forceinline__ void block_sync_lds() {
  asm volatile("s_waitcnt lgkmcnt(0)\ns_barrier" ::: "memory");
}
__device__ __forceinline__ void wait_lds() {
  asm volatile("s_waitcnt lgkmcnt(0)" ::: "memory");
}

// ---------------- node embedding: h = x @ Wn + bn ----------------
__global__ __launch_bounds__(128) void embed_nodes_kernel(
    const float* __restrict__ x, const float* __restrict__ Wn,
    const float* __restrict__ bn, float* __restrict__ h) {
  __shared__ float Ws[NDIM * H];
  __shared__ float xs[16 * NDIM];
  int j = threadIdx.x;
  int nbase = blockIdx.x * 16;
  for (int r = 0; r < NDIM; ++r) Ws[r * H + j] = Wn[r * H + j];
#pragma unroll
  for (int t = 0; t < 4; ++t) {
    int f = j + t * 128;
    xs[f] = x[nbase * NDIM + f];
  }
  __syncthreads();
  float b = bn[j];
  for (int nn = 0; nn < 16; ++nn) {
    float acc = b;
#pragma unroll
    for (int k = 0; k < NDIM; ++k)
      acc = fmaf(xs[nn * NDIM + k], Ws[k * H + j], acc);
    h[(size_t)(nbase + nn) * H + j] = acc;
  }
}

// ---------------- degree histogram over dst ----------------
__global__ __launch_bounds__(256) void degree_kernel(const int* __restrict__ ei,
                                                     int* __restrict__ deg) {
  int e = blockIdx.x * 256 + threadIdx.x;
  if (e < NE) atomicAdd(&deg[ei[NE + e]], 1);
}

// ---------------- exclusive prefix sum of deg -> cursor (one block) ----------------
#define SCAN_T 1024
#define SCAN_C 49  // 1024*49 >= 50000
__global__ __launch_bounds__(SCAN_T) void scan_kernel(
    const int* __restrict__ deg, int* __restrict__ cursor) {
  __shared__ int part[SCAN_T];
  int t = threadIdx.x;
  int base = t * SCAN_C;
  int s = 0;
  for (int i = 0; i < SCAN_C; ++i) {
    int idx = base + i;
    if (idx < NN) s += deg[idx];
  }
  part[t] = s;
  __syncthreads();
  for (int off = 1; off < SCAN_T; off <<= 1) {
    int v = (t >= off) ? part[t - off] : 0;
    __syncthreads();
    part[t] += v;
    __syncthreads();
  }
  int running = part[t] - s;  // exclusive prefix of this thread's segment
  for (int i = 0; i < SCAN_C; ++i) {
    int idx = base + i;
    if (idx < NN) {
      cursor[idx] = running;
      running += deg[idx];
    }
  }
}

// ---------------- counting-sort scatter: edges grouped by dst ----------------
__global__ __launch_bounds__(256) void scatter_kernel(
    const int* __restrict__ ei, int* __restrict__ cursor,
    int* __restrict__ srcSrt, int* __restrict__ dstSrt,
    int* __restrict__ eidSrt) {
  int e = blockIdx.x * 256 + threadIdx.x;
  if (e < NE) {
    int d = ei[NE + e];
    int pos = atomicAdd(&cursor[d], 1);
    dstSrt[pos] = d;
    srcSrt[pos] = ei[e];
    eidSrt[pos] = e;
  }
}

// ---------------- gather edge attrs into sorted order (once) ----------------
__global__ __launch_bounds__(256) void gather_ea_kernel(
    const float* __restrict__ ea, const int* __restrict__ eidSrt,
    float* __restrict__ eaSrt) {
  int j = blockIdx.x * 1024 + threadIdx.x * 4;  // float4 worth of floats
  int fl = j >> 4;  // edge (16 floats each)
  int q = (j >> 2) & 3;
  if (fl < NE) {
    int e = eidSrt[fl];
    float4 v = ((const float4*)(ea + (size_t)e * EDIM))[q];
    *(float4*)(eaSrt + (size_t)fl * EDIM + q * 4) = v;
  }
}

// ---------------- zdzs weights: mW1[0:256] -> hi/lo bf16, frag-swizzled ----------------
__global__ __launch_bounds__(256) void precomp_zw_kernel(
    const float* __restrict__ mW1, __bf16* __restrict__ ZW) {
  int l = blockIdx.x / 8;
  int c = blockIdx.x % 8;
  int tid = threadIdx.x;
  const float* w1 = mW1 + (size_t)l * 384 * H;
  __bf16* dst = ZW + ((size_t)l * 8 + c) * ZW_CHUNK;
  for (int it = 0; it < 32; ++it) {
    int flat = it * 256 + tid;
    int j = flat & 7;
    int lane = (flat >> 3) & 63;
    int nt = (flat >> 9) & 7;
    int hilo = flat >> 12;
    int k = c * 16 + ((lane >> 5) << 3) + j;
    int n = nt * 32 + (lane & 31);
    float w = (n < 128) ? w1[(size_t)k * H + n]
                        : w1[(size_t)(128 + k) * H + (n - 128)];
    __bf16 hi = (__bf16)w;
    __bf16 lo = (__bf16)(w - (float)hi);
    dst[flat] = hilo ? lo : hi;
  }
}

// ---------------- Wef = We @ mW1[256:384] (16x128), bm = mb1 + be @ ... ----------------
// loop-interchanged: w1 column value loaded once, reused across all 16 We rows
__global__ __launch_bounds__(128) void precomp_wef_kernel(
    const float* __restrict__ mW1, const float* __restrict__ mb1,
    const float* __restrict__ We, const float* __restrict__ be,
    float* __restrict__ Wef, float* __restrict__ bm) {
  int l = blockIdx.x;
  int n = threadIdx.x;
  const float* w1 = mW1 + (size_t)l * 384 * H;
  float acc[EDIM];
#pragma unroll
  for (int i = 0; i < EDIM; ++i) acc[i] = 0.f;
  float accb = 0.f;
  for (int c = 0; c < H; ++c) {
    float wv = w1[(size_t)(256 + c) * H + n];
    accb = fmaf(be[c], wv, accb);
#pragma unroll
    for (int i = 0; i < EDIM; ++i)
      acc[i] = fmaf(We[i * H + c], wv, acc[i]);
  }
#pragma unroll
  for (int i = 0; i < EDIM; ++i)
    Wef[((size_t)l * EDIM + i) * H + n] = acc[i];
  bm[l * H + n] = mb1[l * H + n] + accb;
}

// ---------------- precompute folded update weights (fp32 Wu) ----------------
__global__ __launch_bounds__(128) void precomp_wu_kernel(
    const float* __restrict__ uW1, const float* __restrict__ mW2,
    const float* __restrict__ mb2, float* __restrict__ Wu,
    float* __restrict__ va) {
  int l = blockIdx.x / 257;
  int r = blockIdx.x % 257;
  int j = threadIdx.x;
  const float* u1 = uW1 + (size_t)l * 256 * H;
  if (r < 128) {
    Wu[((size_t)l * 256 + r) * H + j] = u1[(size_t)r * H + j];
  } else if (r < 256) {
    int i = r - 128;
    const float* m2 = mW2 + ((size_t)l * H + i) * H;
    float s = 0.f;
    for (int c = 0; c < H; ++c)
      s = fmaf(m2[c], u1[(size_t)(128 + c) * H + j], s);
    Wu[((size_t)l * 256 + r) * H + j] = s;
  } else {
    float s = 0.f;
    for (int c = 0; c < H; ++c)
      s = fmaf(mb2[l * H + c], u1[(size_t)(128 + c) * H + j], s);
    va[l * H + j] = s;
  }
}

// ---------------- swizzle node weights into hi/lo frag chunks ----------------
__global__ __launch_bounds__(256) void precomp_wns_kernel(
    const float* __restrict__ Wu, const float* __restrict__ uW2,
    __bf16* __restrict__ WnS) {
  int l = blockIdx.x / NODE_CHUNKS;
  int c = blockIdx.x % NODE_CHUNKS;
  int tid = threadIdx.x;
  int nt = tid >> 6, lane = tid & 63;
  int n = nt * 32 + (lane & 31);
  int half = lane >> 5;
  __bf16* dst = WnS + ((size_t)l * NODE_CHUNKS + c) * CHUNK_ELEMS;
#pragma unroll
  for (int j = 0; j < 8; ++j) {
    float w;
    if (c < 16) {
      int k = c * 16 + half * 8 + j;
      w = Wu[((size_t)l * 256 + k) * H + n];
    } else {
      int k = (c - 16) * 16 + half * 8 + j;
      w = uW2[((size_t)l * H + k) * H + n];
    }
    __bf16 hi = (__bf16)w;
    __bf16 lo = (__bf16)(w - (float)hi);
    dst[((0 * 4 + nt) * 64 + lane) * 8 + j] = hi;
    dst[((1 * 4 + nt) * 64 + lane) * 8 + j] = lo;
  }
}

// ---------------- z = h @ [W_d|W_s] (+bm on dst half): dense MFMA GEMM ----------------
__global__ __launch_bounds__(256) void zdzs_kernel(
    const float* __restrict__ h, const __bf16* __restrict__ ZW,
    const float* __restrict__ bm, float* __restrict__ z) {
  __shared__ __align__(16) __bf16 Bt[2][ZW_CHUNK];  // 32 KB
  int tid = threadIdx.x;
  int wid = tid >> 6, lane = tid & 63, m = lane & 31, half = lane >> 5;
  int nb = blockIdx.x * 128;
  int row = nb + wid * 32 + m;
  const float* aH = h + (size_t)row * H + half * 8;
  const short8* gW = (const short8*)ZW;  // 1024 short8 per chunk
  short8* sB0 = (short8*)&Bt[0][0];
  short8* sB1 = (short8*)&Bt[1][0];
#pragma unroll
  for (int q = 0; q < 4; ++q) sB0[tid + q * 256] = gW[tid + q * 256];
  short8 p0 = gW[1024 + tid], p1 = gW[1024 + tid + 256];
  short8 p2 = gW[1024 + tid + 512], p3 = gW[1024 + tid + 768];
  f32x16 acc[8];
#pragma unroll
  for (int nt = 0; nt < 8; ++nt)
#pragma unroll
    for (int r = 0; r < 16; ++r) acc[nt][r] = 0.f;
  float4 a0 = *(const float4*)aH;
  float4 a1 = *(const float4*)(aH + 4);
  block_sync_lds();

  for (int s = 0; s < 8; ++s) {
    int buf = s & 1;
    float4 na0 = a0, na1 = a1;
    if (s + 1 < 8) {
      const float* pp = aH + (s + 1) * 16;
      na0 = *(const float4*)pp;
      na1 = *(const float4*)(pp + 4);
    }
    if (s + 1 < 8) {
      short8* sb = buf ? sB0 : sB1;
      sb[tid] = p0;
      sb[tid + 256] = p1;
      sb[tid + 512] = p2;
      sb[tid + 768] = p3;
      if (s + 2 < 8) {
        p0 = gW[(size_t)(s + 2) * 1024 + tid];
        p1 = gW[(size_t)(s + 2) * 1024 + tid + 256];
        p2 = gW[(size_t)(s + 2) * 1024 + tid + 512];
        p3 = gW[(size_t)(s + 2) * 1024 + tid + 768];
      }
    }
    float af[8] = {a0.x, a0.y, a0.z, a0.w, a1.x, a1.y, a1.z, a1.w};
    bf16x8 ah, al;
#pragma unroll
    for (int j = 0; j < 8; ++j) {
      __bf16 hi = (__bf16)af[j];
      ah[j] = hi;
      al[j] = (__bf16)(af[j] - (float)hi);
    }
    const __bf16* bb = &Bt[buf][0];
#pragma unroll
    for (int nt = 0; nt < 8; ++nt) {
      bf16x8 bh = *(const bf16x8*)&bb[((0 * 8 + nt) * 64 + lane) * 8];
      bf16x8 bl = *(const bf16x8*)&bb[((1 * 8 + nt) * 64 + lane) * 8];
      acc[nt] = __builtin_amdgcn_mfma_f32_32x32x16_bf16(ah, bh, acc[nt], 0, 0, 0);
      acc[nt] = __builtin_amdgcn_mfma_f32_32x32x16_bf16(al, bh, acc[nt], 0, 0, 0);
      acc[nt] = __builtin_amdgcn_mfma_f32_32x32x16_bf16(ah, bl, acc[nt], 0, 0, 0);
    }
    a0 = na0;
    a1 = na1;
    if (s + 1 < 8) block_sync_lds();
  }

  float bmv[4];
#pragma unroll
  for (int nt = 0; nt < 4; ++nt) bmv[nt] = bm[nt * 32 + m];
#pragma unroll
  for (int nt = 0; nt < 8; ++nt) {
    float bias = (nt < 4) ? bmv[nt] : 0.f;
#pragma unroll
    for (int r = 0; r < 16; ++r) {
      int rowi = (r & 3) + 8 * (r >> 2) + 4 * half;
      z[(size_t)(nb + wid * 32 + rowi) * 256 + nt * 32 + m] = acc[nt][r] + bias;
    }
  }
}

// ---------------- sorted-edge aggregation: aggr[dst] += relu(z_d+z_s+ze) ----------------
// 4 waves x 16 edges; lane owns cols c0=lane*2. All 32 z-loads issued up front
// (static regs -> compiler vmcnt ring, no dynamic indexing, no guards);
// ea via LDS broadcast; ze in packed fp32 (v_pk_fma); scalar segment branch.
__global__ __launch_bounds__(256) void edge_aggr_kernel(
    const float* __restrict__ z, const int* __restrict__ srcSrt,
    const int* __restrict__ dstSrt, const float* __restrict__ eaSrt,
    const float* __restrict__ Wef, float* __restrict__ aggrH) {
  __shared__ float eaS[EAB * EDIM];  // 4 KB
  __shared__ int dstS[EAB], srcS[EAB];
  int tid = threadIdx.x;
  int e0b = blockIdx.x * EAB;
  {
    float4 v = ((const float4*)(eaSrt + (size_t)e0b * EDIM))[tid];
    *(float4*)&eaS[tid * 4] = v;
  }
  if (tid < EAB) dstS[tid] = dstSrt[e0b + tid];
  else if (tid < 2 * EAB) srcS[tid - EAB] = srcSrt[e0b + tid - EAB];
  __syncthreads();
  int wid = tid >> 6, lane = tid & 63;
  int eb = wid * 16;
  int c0 = lane * 2;
  v2f w[EDIM];
#pragma unroll
  for (int k = 0; k < EDIM; ++k)
    w[k] = *(const v2f*)(Wef + (size_t)k * H + c0);
  v2f zd[16], zs[16];
#pragma unroll
  for (int i = 0; i < 16; ++i) {
    zd[i] = *(const v2f*)(z + (size_t)dstS[eb + i] * 256 + c0);
    zs[i] = *(const v2f*)(z + (size_t)srcS[eb + i] * 256 + 128 + c0);
  }
  int cur = __builtin_amdgcn_readfirstlane(dstS[eb]);
  v2f acc = {0.f, 0.f};
#pragma unroll
  for (int i = 0; i < 16; ++i) {
    const float4* ep = (const float4*)&eaS[(eb + i) * EDIM];
    float4 g0 = ep[0], g1 = ep[1], g2 = ep[2], g3 = ep[3];
    v2f ze = g0.x * w[0];
    ze += g0.y * w[1];
    ze += g0.z * w[2];
    ze += g0.w * w[3];
    ze += g1.x * w[4];
    ze += g1.y * w[5];
    ze += g1.z * w[6];
    ze += g1.w * w[7];
    ze += g2.x * w[8];
    ze += g2.y * w[9];
    ze += g2.z * w[10];
    ze += g2.w * w[11];
    ze += g3.x * w[12];
    ze += g3.y * w[13];
    ze += g3.z * w[14];
    ze += g3.w * w[15];
    int d = __builtin_amdgcn_readfirstlane(dstS[eb + i]);
    if (d != cur) {
      float* ap = aggrH + (size_t)cur * H + c0;
      unsafeAtomicAdd(ap, acc.x);
      unsafeAtomicAdd(ap + 1, acc.y);
      acc.x = 0.f;
      acc.y = 0.f;
      cur = d;
    }
    v2f t = zd[i] + zs[i] + ze;
    acc.x += fmaxf(t.x, 0.f);
    acc.y += fmaxf(t.y, 0.f);
  }
  float* ap = aggrH + (size_t)cur * H + c0;
  unsafeAtomicAdd(ap, acc.x);
  unsafeAtomicAdd(ap + 1, acc.y);
}

// ---------------- MFMA fused node update ----------------
__global__ __launch_bounds__(256) void node_update_mfma_kernel(
    float* __restrict__ h, const float* __restrict__ aggrH,
    const int* __restrict__ deg, const __bf16* __restrict__ WnS,
    const float* __restrict__ ub1, const float* __restrict__ va,
    const float* __restrict__ ub2) {
  __shared__ __align__(16) __bf16 Bt[2][CHUNK_ELEMS];
  __shared__ __bf16 hid[4][32][132];
  __shared__ float degS[128];
  int tid = threadIdx.x;
  int nb = blockIdx.x * 128;
  if (tid < 128) degS[tid] = (float)deg[nb + tid];
  int wid = tid >> 6, lane = tid & 63, m = lane & 31, half = lane >> 5;
  int row = nb + wid * 32 + m;
  const float* aH = h + (size_t)row * H + half * 8;
  const float* aG = aggrH + (size_t)row * H + half * 8;
  const short8* gW = (const short8*)WnS;
  short8* sB0 = (short8*)&Bt[0][0];
  short8* sB1 = (short8*)&Bt[1][0];
  sB0[tid] = gW[tid];
  sB0[tid + 256] = gW[tid + 256];
  short8 p0 = gW[512 + tid], p1 = gW[512 + tid + 256];
  float bv1[4], bva[4];
#pragma unroll
  for (int nt = 0; nt < 4; ++nt) {
    bv1[nt] = ub1[nt * 32 + m];
    bva[nt] = va[nt * 32 + m];
  }
  f32x16 acc[4];
#pragma unroll
  for (int nt = 0; nt < 4; ++nt)
#pragma unroll
    for (int r = 0; r < 16; ++r) acc[nt][r] = 0.f;
  float4 a0 = *(const float4*)aH;
  float4 a1 = *(const float4*)(aH + 4);
  block_sync_lds();

  for (int s = 0; s < 16; ++s) {
    int buf = s & 1;
    float4 na0 = a0, na1 = a1;
    if (s + 1 < 16) {
      int sp = s + 1;
      const float* pp = (sp < 8) ? (aH + sp * 16) : (aG + (sp - 8) * 16);
      na0 = *(const float4*)pp;
      na1 = *(const float4*)(pp + 4);
    }
    {
      short8* sb = buf ? sB0 : sB1;
      sb[tid] = p0;
      sb[tid + 256] = p1;
      if (s + 2 < NODE_CHUNKS) {
        p0 = gW[(size_t)(s + 2) * 512 + tid];
        p1 = gW[(size_t)(s + 2) * 512 + tid + 256];
      }
    }
    float af[8] = {a0.x, a0.y, a0.z, a0.w, a1.x, a1.y, a1.z, a1.w};
    bf16x8 ah;
#pragma unroll
    for (int j = 0; j < 8; ++j) ah[j] = (__bf16)af[j];
    const __bf16* bb = &Bt[buf][0];
#pragma unroll
    for (int nt = 0; nt < 4; ++nt) {
      bf16x8 bh = *(const bf16x8*)&bb[((0 * 4 + nt) * 64 + lane) * 8];
      bf16x8 bl = *(const bf16x8*)&bb[((1 * 4 + nt) * 64 + lane) * 8];
      acc[nt] = __builtin_amdgcn_mfma_f32_32x32x16_bf16(ah, bh, acc[nt], 0, 0, 0);
      acc[nt] = __builtin_amdgcn_mfma_f32_32x32x16_bf16(ah, bl, acc[nt], 0, 0, 0);
    }
    a0 = na0;
    a1 = na1;
    block_sync_lds();
  }

#pragma unroll
  for (int nt = 0; nt < 4; ++nt) {
#pragma unroll
    for (int r = 0; r < 16; ++r) {
      int rowi = (r & 3) + 8 * (r >> 2) + 4 * half;
      float v = acc[nt][r] + bv1[nt] + degS[wid * 32 + rowi] * bva[nt];
      hid[wid][rowi][nt * 32 + m] = (__bf16)fmaxf(v, 0.f);
      acc[nt][r] = 0.f;
    }
  }
  wait_lds();

  for (int s = 16; s < NODE_CHUNKS; ++s) {
    int buf = s & 1;
    if (s + 1 < NODE_CHUNKS) {
      short8* sb = buf ? sB0 : sB1;
      sb[tid] = p0;
      sb[tid + 256] = p1;
      if (s + 2 < NODE_CHUNKS) {
        p0 = gW[(size_t)(s + 2) * 512 + tid];
        p1 = gW[(size_t)(s + 2) * 512 + tid + 256];
      }
    }
    bf16x8 ah = *(const bf16x8*)&hid[wid][m][(s - 16) * 16 + half * 8];
    const __bf16* bb = &Bt[buf][0];
#pragma unroll
    for (int nt = 0; nt < 4; ++nt) {
      bf16x8 bh = *(const bf16x8*)&bb[((0 * 4 + nt) * 64 + lane) * 8];
      bf16x8 bl = *(const bf16x8*)&bb[((1 * 4 + nt) * 64 + lane) * 8];
      acc[nt] = __builtin_amdgcn_mfma_f32_32x32x16_bf16(ah, bh, acc[nt], 0, 0, 0);
      acc[nt] = __builtin_amdgcn_mfma_f32_32x32x16_bf16(ah, bl, acc[nt], 0, 0, 0);
    }
    if (s + 1 < NODE_CHUNKS) block_sync_lds();
  }

#pragma unroll
  for (int nt = 0; nt < 4; ++nt) {
    float b2 = ub2[nt * 32 + m];
#pragma unroll
    for (int r = 0; r < 16; ++r) {
      int rowi = (r & 3) + 8 * (r >> 2) + 4 * half;
      float* hp = h + (size_t)(nb + wid * 32 + rowi) * H + nt * 32 + m;
      *hp += acc[nt][r] + b2;
    }
  }
}

// ---------------- batch mean pooling (batch is sorted) ----------------
__global__ __launch_bounds__(128) void pool_kernel(
    const float* __restrict__ h, const int* __restrict__ batch,
    float* __restrict__ pooled, int* __restrict__ counts) {
  int j = threadIdx.x;
  int nbase = blockIdx.x * 128;
  int nend = nbase + 128;
  if (nend > NN) nend = NN;
  if (nbase >= NN) return;
  int cur = batch[nbase];
  float sum = 0.f;
  int cnt = 0;
  for (int n = nbase; n < nend; ++n) {
    int b = batch[n];
    if (b != cur) {
      unsafeAtomicAdd(&pooled[cur * H + j], sum);
      if (j == 0) atomicAdd(&counts[cur], cnt);
      sum = 0.f; cnt = 0; cur = b;
    }
    sum += h[(size_t)n * H + j];
    cnt++;
  }
  unsafeAtomicAdd(&pooled[cur * H + j], sum);
  if (j == 0) atomicAdd(&counts[cur], cnt);
}

// ---------------- readout MLP ----------------
__global__ __launch_bounds__(128) void readout_kernel(
    const float* __restrict__ pooled, const int* __restrict__ counts,
    const float* __restrict__ gf, const float* __restrict__ Wg,
    const float* __restrict__ bg, const float* __restrict__ rW1,
    const float* __restrict__ rb1, const float* __restrict__ rW2,
    const float* __restrict__ rb2, const float* __restrict__ rW3,
    const float* __restrict__ rb3, float* __restrict__ out) {
  __shared__ float fin[256];
  __shared__ float t1[128];
  __shared__ float t2[64];
  int j = threadIdx.x;
  for (int b = 0; b < NBATCH; ++b) {
    float cnt = (float)counts[b];
    if (cnt < 1.f) cnt = 1.f;
    fin[j] = pooled[b * H + j] / cnt;
    fin[H + j] = fmaf(gf[b], Wg[j], bg[j]);
    __syncthreads();
    float a = rb1[j];
    for (int k = 0; k < 256; ++k) a = fmaf(fin[k], rW1[k * H + j], a);
    t1[j] = fmaxf(a, 0.f);
    __syncthreads();
    if (j < 64) {
      float a2 = rb2[j];
      for (int k = 0; k < 128; ++k) a2 = fmaf(t1[k], rW2[k * 64 + j], a2);
      t2[j] = fmaxf(a2, 0.f);
    }
    __syncthreads();
    if (j < 64) {
      float p = t2[j] * rW3[j];
#pragma unroll
      for (int off = 32; off; off >>= 1) p += __shfl_down(p, off);
      if (j == 0) out[b] = p + rb3[0];
    }
    __syncthreads();
  }
}

extern "C" void kernel_launch(void* const* d_in, const int* in_sizes, int n_in,
                              void* d_out, int out_size, void* d_ws, size_t ws_size,
                              hipStream_t stream) {
  const float* x   = (const float*)d_in[0];
  const float* ea  = (const float*)d_in[1];
  const float* gf  = (const float*)d_in[2];
  const int*   ei  = (const int*)d_in[3];
  const int*   bat = (const int*)d_in[4];
  const float* Wn  = (const float*)d_in[5];
  const float* bn  = (const float*)d_in[6];
  const float* We  = (const float*)d_in[7];
  const float* be  = (const float*)d_in[8];
  const float* Wg  = (const float*)d_in[9];
  const float* bg  = (const float*)d_in[10];
  const float* mW1 = (const float*)d_in[11];
  const float* mb1 = (const float*)d_in[12];
  const float* mW2 = (const float*)d_in[13];
  const float* mb2 = (const float*)d_in[14];
  const float* uW1 = (const float*)d_in[15];
  const float* ub1 = (const float*)d_in[16];
  const float* uW2 = (const float*)d_in[17];
  const float* ub2 = (const float*)d_in[18];
  const float* rW1 = (const float*)d_in[19];
  const float* rb1 = (const float*)d_in[20];
  const float* rW2 = (const float*)d_in[21];
  const float* rb2 = (const float*)d_in[22];
  const float* rW3 = (const float*)d_in[23];
  const float* rb3 = (const float*)d_in[24];

  char* p = (char*)d_ws;
  float*  h      = (float*)p;  p += (size_t)NPAD * H * 4;        // 25.6 MB
  float*  aggrH  = (float*)p;  p += (size_t)NPAD * H * 4;        // 25.6 MB
  float*  z      = (float*)p;  p += (size_t)NPAD * 256 * 4;      // 51.2 MB
  float*  eaSrt  = (float*)p;  p += (size_t)NE * EDIM * 4;       // 25.6 MB
  int*    srcSrt = (int*)p;    p += (size_t)NE * 4;
  int*    dstSrt = (int*)p;    p += (size_t)NE * 4;
  int*    eidSrt = (int*)p;    p += (size_t)NE * 4;
  __bf16* ZW     = (__bf16*)p; p += (size_t)NLAYERS * 8 * ZW_CHUNK * 2;
  __bf16* WnS    = (__bf16*)p; p += (size_t)NLAYERS * NODE_CHUNKS * CHUNK_ELEMS * 2;
  float*  Wef    = (float*)p;  p += (size_t)NLAYERS * EDIM * H * 4;
  float*  bm     = (float*)p;  p += (size_t)NLAYERS * H * 4;
  float*  Wu     = (float*)p;  p += (size_t)NLAYERS * 256 * H * 4;
  float*  va     = (float*)p;  p += (size_t)NLAYERS * H * 4;
  int*    deg    = (int*)p;    p += (size_t)NPAD * 4;
  int*    cursor = (int*)p;    p += (size_t)NPAD * 4;
  float*  pooled = (float*)p;  p += (size_t)NBATCH * H * 4;
  int*    counts = (int*)p;    p += 64;

  hipMemsetAsync(deg, 0, (size_t)NPAD * 4, stream);
  hipMemsetAsync(pooled, 0, (size_t)NBATCH * H * 4, stream);
  hipMemsetAsync(counts, 0, 64, stream);

  embed_nodes_kernel<<<NN / 16, 128, 0, stream>>>(x, Wn, bn, h);
  degree_kernel<<<(NE + 255) / 256, 256, 0, stream>>>(ei, deg);
  scan_kernel<<<1, SCAN_T, 0, stream>>>(deg, cursor);
  scatter_kernel<<<(NE + 255) / 256, 256, 0, stream>>>(ei, cursor, srcSrt,
                                                       dstSrt, eidSrt);
  gather_ea_kernel<<<(NE * 16 + 1023) / 1024, 256, 0, stream>>>(ea, eidSrt, eaSrt);
  precomp_zw_kernel<<<NLAYERS * 8, 256, 0, stream>>>(mW1, ZW);
  precomp_wef_kernel<<<NLAYERS, 128, 0, stream>>>(mW1, mb1, We, be, Wef, bm);
  precomp_wu_kernel<<<NLAYERS * 257, 128, 0, stream>>>(uW1, mW2, mb2, Wu, va);
  precomp_wns_kernel<<<NLAYERS * NODE_CHUNKS, 256, 0, stream>>>(Wu, uW2, WnS);

  for (int l = 0; l < NLAYERS; ++l) {
    hipMemsetAsync(aggrH, 0, (size_t)NPAD * H * 4, stream);
    zdzs_kernel<<<NBLK, 256, 0, stream>>>(
        h, ZW + (size_t)l * 8 * ZW_CHUNK, bm + (size_t)l * H, z);
    edge_aggr_kernel<<<NE / EAB, 256, 0, stream>>>(
        z, srcSrt, dstSrt, eaSrt, Wef + (size_t)l * EDIM * H, aggrH);
    node_update_mfma_kernel<<<NBLK, 256, 0, stream>>>(
        h, aggrH, deg, WnS + (size_t)l * NODE_CHUNKS * CHUNK_ELEMS,
        ub1 + (size_t)l * H, va + (size_t)l * H, ub2 + (size_t)l * H);
  }

  pool_kernel<<<(NN + 127) / 128, 128, 0, stream>>>(h, bat, pooled, counts);
  readout_kernel<<<1, 128, 0, stream>>>(pooled, counts, gf, Wg, bg, rW1, rb1,
                                        rW2, rb2, rW3, rb3, (float*)d_out);
}

// Round 11
// 694.478 us; speedup vs baseline: 1.4182x; 1.1086x over previous
//
#include <hip/hip_runtime.h>

#define NN 50000
#define NPAD 50048     // 391 * 128
#define NBLK 391
#define NE 400000
#define NBATCH 8
#define NDIM 32
#define EDIM 16
#define H 128
#define NLAYERS 3
#define CHUNK_ELEMS 4096   // node-kernel weight chunk: 2 hilo * 4 nt * 64 lane * 8
#define NODE_CHUNKS 24     // 16 (Wu, K=256) + 8 (uW2, K=128)
#define ZW_CHUNK 8192      // zdzs chunk: 2 hilo * 8 nt * 64 lane * 8
#define EAB 64             // edges per block in edge_aggr (4 waves x 16)
#define NSB 196            // scan blocks: ceil(50000/256)

typedef __attribute__((ext_vector_type(8))) __bf16 bf16x8;
typedef __attribute__((ext_vector_type(16))) float f32x16;
typedef __attribute__((ext_vector_type(8))) short short8;
typedef __attribute__((ext_vector_type(2))) float v2f;

__device__ __forceinline__ void block_sync_lds() {
  asm volatile("s_waitcnt lgkmcnt(0)\ns_barrier" ::: "memory");
}
__device__ __forceinline__ void wait_lds() {
  asm volatile("s_waitcnt lgkmcnt(0)" ::: "memory");
}

// ---------------- node embedding: h = x @ Wn + bn ----------------
__global__ __launch_bounds__(128) void embed_nodes_kernel(
    const float* __restrict__ x, const float* __restrict__ Wn,
    const float* __restrict__ bn, float* __restrict__ h) {
  __shared__ float Ws[NDIM * H];
  __shared__ float xs[16 * NDIM];
  int j = threadIdx.x;
  int nbase = blockIdx.x * 16;
  for (int r = 0; r < NDIM; ++r) Ws[r * H + j] = Wn[r * H + j];
#pragma unroll
  for (int t = 0; t < 4; ++t) {
    int f = j + t * 128;
    xs[f] = x[nbase * NDIM + f];
  }
  __syncthreads();
  float b = bn[j];
  for (int nn = 0; nn < 16; ++nn) {
    float acc = b;
#pragma unroll
    for (int k = 0; k < NDIM; ++k)
      acc = fmaf(xs[nn * NDIM + k], Ws[k * H + j], acc);
    h[(size_t)(nbase + nn) * H + j] = acc;
  }
}

// ---------------- degree histogram over dst ----------------
__global__ __launch_bounds__(256) void degree_kernel(const int* __restrict__ ei,
                                                     int* __restrict__ deg) {
  int e = blockIdx.x * 256 + threadIdx.x;
  if (e < NE) atomicAdd(&deg[ei[NE + e]], 1);
}

// ---------------- parallel 3-phase exclusive scan of deg -> cursor ----------------
__global__ __launch_bounds__(256) void scan1_kernel(const int* __restrict__ deg,
                                                    int* __restrict__ bsum) {
  __shared__ int ws[4];
  int i = blockIdx.x * 256 + threadIdx.x;
  int lane = threadIdx.x & 63, wid = threadIdx.x >> 6;
  int v = (i < NN) ? deg[i] : 0;
#pragma unroll
  for (int off = 32; off; off >>= 1) v += __shfl_down(v, off);
  if (lane == 0) ws[wid] = v;
  __syncthreads();
  if (threadIdx.x == 0) bsum[blockIdx.x] = ws[0] + ws[1] + ws[2] + ws[3];
}

__global__ __launch_bounds__(256) void scan2_kernel(const int* __restrict__ bsum,
                                                    int* __restrict__ boff) {
  __shared__ int s[256];
  int t = threadIdx.x;
  int v = (t < NSB) ? bsum[t] : 0;
  s[t] = v;
  __syncthreads();
  for (int off = 1; off < 256; off <<= 1) {
    int u = (t >= off) ? s[t - off] : 0;
    __syncthreads();
    s[t] += u;
    __syncthreads();
  }
  if (t < NSB) boff[t] = s[t] - v;  // exclusive across blocks
}

__global__ __launch_bounds__(256) void scan3_kernel(const int* __restrict__ deg,
                                                    const int* __restrict__ boff,
                                                    int* __restrict__ cursor) {
  __shared__ int wsum[4], woff[4];
  int i = blockIdx.x * 256 + threadIdx.x;
  int lane = threadIdx.x & 63, wid = threadIdx.x >> 6;
  int orig = (i < NN) ? deg[i] : 0;
  int v = orig;
#pragma unroll
  for (int off = 1; off < 64; off <<= 1) {
    int u = __shfl_up(v, off);
    if (lane >= off) v += u;
  }
  if (lane == 63) wsum[wid] = v;
  __syncthreads();
  if (threadIdx.x == 0) {
    int r = 0;
#pragma unroll
    for (int w = 0; w < 4; ++w) {
      woff[w] = r;
      r += wsum[w];
    }
  }
  __syncthreads();
  if (i < NN) cursor[i] = (v - orig) + woff[wid] + boff[blockIdx.x];
}

// ---------------- counting-sort scatter: edges grouped by dst ----------------
__global__ __launch_bounds__(256) void scatter_kernel(
    const int* __restrict__ ei, int* __restrict__ cursor,
    int* __restrict__ srcSrt, int* __restrict__ dstSrt,
    int* __restrict__ eidSrt) {
  int e = blockIdx.x * 256 + threadIdx.x;
  if (e < NE) {
    int d = ei[NE + e];
    int pos = atomicAdd(&cursor[d], 1);
    dstSrt[pos] = d;
    srcSrt[pos] = ei[e];
    eidSrt[pos] = e;
  }
}

// ---------------- gather edge attrs into sorted order (once) ----------------
__global__ __launch_bounds__(256) void gather_ea_kernel(
    const float* __restrict__ ea, const int* __restrict__ eidSrt,
    float* __restrict__ eaSrt) {
  int j = blockIdx.x * 1024 + threadIdx.x * 4;  // float4 worth of floats
  int fl = j >> 4;  // edge (16 floats each)
  int q = (j >> 2) & 3;
  if (fl < NE) {
    int e = eidSrt[fl];
    float4 v = ((const float4*)(ea + (size_t)e * EDIM))[q];
    *(float4*)(eaSrt + (size_t)fl * EDIM + q * 4) = v;
  }
}

// ---------------- zdzs weights: mW1[0:256] -> hi/lo bf16, frag-swizzled ----------------
__global__ __launch_bounds__(256) void precomp_zw_kernel(
    const float* __restrict__ mW1, __bf16* __restrict__ ZW) {
  int l = blockIdx.x / 8;
  int c = blockIdx.x % 8;
  int tid = threadIdx.x;
  const float* w1 = mW1 + (size_t)l * 384 * H;
  __bf16* dst = ZW + ((size_t)l * 8 + c) * ZW_CHUNK;
  for (int it = 0; it < 32; ++it) {
    int flat = it * 256 + tid;
    int j = flat & 7;
    int lane = (flat >> 3) & 63;
    int nt = (flat >> 9) & 7;
    int hilo = flat >> 12;
    int k = c * 16 + ((lane >> 5) << 3) + j;
    int n = nt * 32 + (lane & 31);
    float w = (n < 128) ? w1[(size_t)k * H + n]
                        : w1[(size_t)(128 + k) * H + (n - 128)];
    __bf16 hi = (__bf16)w;
    __bf16 lo = (__bf16)(w - (float)hi);
    dst[flat] = hilo ? lo : hi;
  }
}

// ---------------- Wef = We @ mW1[256:384] (16x128), bm = mb1 + be @ ... ----------------
__global__ __launch_bounds__(128) void precomp_wef_kernel(
    const float* __restrict__ mW1, const float* __restrict__ mb1,
    const float* __restrict__ We, const float* __restrict__ be,
    float* __restrict__ Wef, float* __restrict__ bm) {
  int l = blockIdx.x;
  int n = threadIdx.x;
  const float* w1 = mW1 + (size_t)l * 384 * H;
  float acc[EDIM];
#pragma unroll
  for (int i = 0; i < EDIM; ++i) acc[i] = 0.f;
  float accb = 0.f;
  for (int c = 0; c < H; ++c) {
    float wv = w1[(size_t)(256 + c) * H + n];
    accb = fmaf(be[c], wv, accb);
#pragma unroll
    for (int i = 0; i < EDIM; ++i)
      acc[i] = fmaf(We[i * H + c], wv, acc[i]);
  }
#pragma unroll
  for (int i = 0; i < EDIM; ++i)
    Wef[((size_t)l * EDIM + i) * H + n] = acc[i];
  bm[l * H + n] = mb1[l * H + n] + accb;
}

// ---------------- precompute folded update weights (fp32 Wu) ----------------
__global__ __launch_bounds__(128) void precomp_wu_kernel(
    const float* __restrict__ uW1, const float* __restrict__ mW2,
    const float* __restrict__ mb2, float* __restrict__ Wu,
    float* __restrict__ va) {
  int l = blockIdx.x / 257;
  int r = blockIdx.x % 257;
  int j = threadIdx.x;
  const float* u1 = uW1 + (size_t)l * 256 * H;
  if (r < 128) {
    Wu[((size_t)l * 256 + r) * H + j] = u1[(size_t)r * H + j];
  } else if (r < 256) {
    int i = r - 128;
    const float* m2 = mW2 + ((size_t)l * H + i) * H;
    float s = 0.f;
    for (int c = 0; c < H; ++c)
      s = fmaf(m2[c], u1[(size_t)(128 + c) * H + j], s);
    Wu[((size_t)l * 256 + r) * H + j] = s;
  } else {
    float s = 0.f;
    for (int c = 0; c < H; ++c)
      s = fmaf(mb2[l * H + c], u1[(size_t)(128 + c) * H + j], s);
    va[l * H + j] = s;
  }
}

// ---------------- swizzle node weights into hi/lo frag chunks ----------------
__global__ __launch_bounds__(256) void precomp_wns_kernel(
    const float* __restrict__ Wu, const float* __restrict__ uW2,
    __bf16* __restrict__ WnS) {
  int l = blockIdx.x / NODE_CHUNKS;
  int c = blockIdx.x % NODE_CHUNKS;
  int tid = threadIdx.x;
  int nt = tid >> 6, lane = tid & 63;
  int n = nt * 32 + (lane & 31);
  int half = lane >> 5;
  __bf16* dst = WnS + ((size_t)l * NODE_CHUNKS + c) * CHUNK_ELEMS;
#pragma unroll
  for (int j = 0; j < 8; ++j) {
    float w;
    if (c < 16) {
      int k = c * 16 + half * 8 + j;
      w = Wu[((size_t)l * 256 + k) * H + n];
    } else {
      int k = (c - 16) * 16 + half * 8 + j;
      w = uW2[((size_t)l * H + k) * H + n];
    }
    __bf16 hi = (__bf16)w;
    __bf16 lo = (__bf16)(w - (float)hi);
    dst[((0 * 4 + nt) * 64 + lane) * 8 + j] = hi;
    dst[((1 * 4 + nt) * 64 + lane) * 8 + j] = lo;
  }
}

// ---------------- z = h @ [W_d|W_s] (+bm on dst half): dense MFMA GEMM ----------------
__global__ __launch_bounds__(256) void zdzs_kernel(
    const float* __restrict__ h, const __bf16* __restrict__ ZW,
    const float* __restrict__ bm, float* __restrict__ z) {
  __shared__ __align__(16) __bf16 Bt[2][ZW_CHUNK];  // 32 KB
  int tid = threadIdx.x;
  int wid = tid >> 6, lane = tid & 63, m = lane & 31, half = lane >> 5;
  int nb = blockIdx.x * 128;
  int row = nb + wid * 32 + m;
  const float* aH = h + (size_t)row * H + half * 8;
  const short8* gW = (const short8*)ZW;  // 1024 short8 per chunk
  short8* sB0 = (short8*)&Bt[0][0];
  short8* sB1 = (short8*)&Bt[1][0];
#pragma unroll
  for (int q = 0; q < 4; ++q) sB0[tid + q * 256] = gW[tid + q * 256];
  short8 p0 = gW[1024 + tid], p1 = gW[1024 + tid + 256];
  short8 p2 = gW[1024 + tid + 512], p3 = gW[1024 + tid + 768];
  f32x16 acc[8];
#pragma unroll
  for (int nt = 0; nt < 8; ++nt)
#pragma unroll
    for (int r = 0; r < 16; ++r) acc[nt][r] = 0.f;
  float4 a0 = *(const float4*)aH;
  float4 a1 = *(const float4*)(aH + 4);
  block_sync_lds();

  for (int s = 0; s < 8; ++s) {
    int buf = s & 1;
    float4 na0 = a0, na1 = a1;
    if (s + 1 < 8) {
      const float* pp = aH + (s + 1) * 16;
      na0 = *(const float4*)pp;
      na1 = *(const float4*)(pp + 4);
    }
    if (s + 1 < 8) {
      short8* sb = buf ? sB0 : sB1;
      sb[tid] = p0;
      sb[tid + 256] = p1;
      sb[tid + 512] = p2;
      sb[tid + 768] = p3;
      if (s + 2 < 8) {
        p0 = gW[(size_t)(s + 2) * 1024 + tid];
        p1 = gW[(size_t)(s + 2) * 1024 + tid + 256];
        p2 = gW[(size_t)(s + 2) * 1024 + tid + 512];
        p3 = gW[(size_t)(s + 2) * 1024 + tid + 768];
      }
    }
    float af[8] = {a0.x, a0.y, a0.z, a0.w, a1.x, a1.y, a1.z, a1.w};
    bf16x8 ah, al;
#pragma unroll
    for (int j = 0; j < 8; ++j) {
      __bf16 hi = (__bf16)af[j];
      ah[j] = hi;
      al[j] = (__bf16)(af[j] - (float)hi);
    }
    const __bf16* bb = &Bt[buf][0];
#pragma unroll
    for (int nt = 0; nt < 8; ++nt) {
      bf16x8 bh = *(const bf16x8*)&bb[((0 * 8 + nt) * 64 + lane) * 8];
      bf16x8 bl = *(const bf16x8*)&bb[((1 * 8 + nt) * 64 + lane) * 8];
      acc[nt] = __builtin_amdgcn_mfma_f32_32x32x16_bf16(ah, bh, acc[nt], 0, 0, 0);
      acc[nt] = __builtin_amdgcn_mfma_f32_32x32x16_bf16(al, bh, acc[nt], 0, 0, 0);
      acc[nt] = __builtin_amdgcn_mfma_f32_32x32x16_bf16(ah, bl, acc[nt], 0, 0, 0);
    }
    a0 = na0;
    a1 = na1;
    if (s + 1 < 8) block_sync_lds();
  }

  float bmv[4];
#pragma unroll
  for (int nt = 0; nt < 4; ++nt) bmv[nt] = bm[nt * 32 + m];
#pragma unroll
  for (int nt = 0; nt < 8; ++nt) {
    float bias = (nt < 4) ? bmv[nt] : 0.f;
#pragma unroll
    for (int r = 0; r < 16; ++r) {
      int rowi = (r & 3) + 8 * (r >> 2) + 4 * half;
      z[(size_t)(nb + wid * 32 + rowi) * 256 + nt * 32 + m] = acc[nt][r] + bias;
    }
  }
}

// ---------------- sorted-edge aggregation: aggr[dst] += relu(z_d+z_s+ze) ----------------
__global__ __launch_bounds__(256) void edge_aggr_kernel(
    const float* __restrict__ z, const int* __restrict__ srcSrt,
    const int* __restrict__ dstSrt, const float* __restrict__ eaSrt,
    const float* __restrict__ Wef, float* __restrict__ aggrH) {
  __shared__ float eaS[EAB * EDIM];  // 4 KB
  __shared__ int dstS[EAB], srcS[EAB];
  int tid = threadIdx.x;
  int e0b = blockIdx.x * EAB;
  {
    float4 v = ((const float4*)(eaSrt + (size_t)e0b * EDIM))[tid];
    *(float4*)&eaS[tid * 4] = v;
  }
  if (tid < EAB) dstS[tid] = dstSrt[e0b + tid];
  else if (tid < 2 * EAB) srcS[tid - EAB] = srcSrt[e0b + tid - EAB];
  __syncthreads();
  int wid = tid >> 6, lane = tid & 63;
  int eb = wid * 16;
  int c0 = lane * 2;
  v2f w[EDIM];
#pragma unroll
  for (int k = 0; k < EDIM; ++k)
    w[k] = *(const v2f*)(Wef + (size_t)k * H + c0);
  v2f zd[16], zs[16];
#pragma unroll
  for (int i = 0; i < 16; ++i) {
    zd[i] = *(const v2f*)(z + (size_t)dstS[eb + i] * 256 + c0);
    zs[i] = *(const v2f*)(z + (size_t)srcS[eb + i] * 256 + 128 + c0);
  }
  int cur = __builtin_amdgcn_readfirstlane(dstS[eb]);
  v2f acc = {0.f, 0.f};
#pragma unroll
  for (int i = 0; i < 16; ++i) {
    const float4* ep = (const float4*)&eaS[(eb + i) * EDIM];
    float4 g0 = ep[0], g1 = ep[1], g2 = ep[2], g3 = ep[3];
    v2f ze = g0.x * w[0];
    ze += g0.y * w[1];
    ze += g0.z * w[2];
    ze += g0.w * w[3];
    ze += g1.x * w[4];
    ze += g1.y * w[5];
    ze += g1.z * w[6];
    ze += g1.w * w[7];
    ze += g2.x * w[8];
    ze += g2.y * w[9];
    ze += g2.z * w[10];
    ze += g2.w * w[11];
    ze += g3.x * w[12];
    ze += g3.y * w[13];
    ze += g3.z * w[14];
    ze += g3.w * w[15];
    int d = __builtin_amdgcn_readfirstlane(dstS[eb + i]);
    if (d != cur) {
      float* ap = aggrH + (size_t)cur * H + c0;
      unsafeAtomicAdd(ap, acc.x);
      unsafeAtomicAdd(ap + 1, acc.y);
      acc.x = 0.f;
      acc.y = 0.f;
      cur = d;
    }
    v2f t = zd[i] + zs[i] + ze;
    acc.x += fmaxf(t.x, 0.f);
    acc.y += fmaxf(t.y, 0.f);
  }
  float* ap = aggrH + (size_t)cur * H + c0;
  unsafeAtomicAdd(ap, acc.x);
  unsafeAtomicAdd(ap + 1, acc.y);
}

// ---------------- MFMA fused node update ----------------
__global__ __launch_bounds__(256) void node_update_mfma_kernel(
    float* __restrict__ h, const float* __restrict__ aggrH,
    const int* __restrict__ deg, const __bf16* __restrict__ WnS,
    const float* __restrict__ ub1, const float* __restrict__ va,
    const float* __restrict__ ub2) {
  __shared__ __align__(16) __bf16 Bt[2][CHUNK_ELEMS];
  __shared__ __bf16 hid[4][32][132];
  __shared__ float degS[128];
  int tid = threadIdx.x;
  int nb = blockIdx.x * 128;
  if (tid < 128) degS[tid] = (float)deg[nb + tid];
  int wid = tid >> 6, lane = tid & 63, m = lane & 31, half = lane >> 5;
  int row = nb + wid * 32 + m;
  const float* aH = h + (size_t)row * H + half * 8;
  const float* aG = aggrH + (size_t)row * H + half * 8;
  const short8* gW = (const short8*)WnS;
  short8* sB0 = (short8*)&Bt[0][0];
  short8* sB1 = (short8*)&Bt[1][0];
  sB0[tid] = gW[tid];
  sB0[tid + 256] = gW[tid + 256];
  short8 p0 = gW[512 + tid], p1 = gW[512 + tid + 256];
  float bv1[4], bva[4];
#pragma unroll
  for (int nt = 0; nt < 4; ++nt) {
    bv1[nt] = ub1[nt * 32 + m];
    bva[nt] = va[nt * 32 + m];
  }
  f32x16 acc[4];
#pragma unroll
  for (int nt = 0; nt < 4; ++nt)
#pragma unroll
    for (int r = 0; r < 16; ++r) acc[nt][r] = 0.f;
  float4 a0 = *(const float4*)aH;
  float4 a1 = *(const float4*)(aH + 4);
  block_sync_lds();

  for (int s = 0; s < 16; ++s) {
    int buf = s & 1;
    float4 na0 = a0, na1 = a1;
    if (s + 1 < 16) {
      int sp = s + 1;
      const float* pp = (sp < 8) ? (aH + sp * 16) : (aG + (sp - 8) * 16);
      na0 = *(const float4*)pp;
      na1 = *(const float4*)(pp + 4);
    }
    {
      short8* sb = buf ? sB0 : sB1;
      sb[tid] = p0;
      sb[tid + 256] = p1;
      if (s + 2 < NODE_CHUNKS) {
        p0 = gW[(size_t)(s + 2) * 512 + tid];
        p1 = gW[(size_t)(s + 2) * 512 + tid + 256];
      }
    }
    float af[8] = {a0.x, a0.y, a0.z, a0.w, a1.x, a1.y, a1.z, a1.w};
    bf16x8 ah;
#pragma unroll
    for (int j = 0; j < 8; ++j) ah[j] = (__bf16)af[j];
    const __bf16* bb = &Bt[buf][0];
#pragma unroll
    for (int nt = 0; nt < 4; ++nt) {
      bf16x8 bh = *(const bf16x8*)&bb[((0 * 4 + nt) * 64 + lane) * 8];
      bf16x8 bl = *(const bf16x8*)&bb[((1 * 4 + nt) * 64 + lane) * 8];
      acc[nt] = __builtin_amdgcn_mfma_f32_32x32x16_bf16(ah, bh, acc[nt], 0, 0, 0);
      acc[nt] = __builtin_amdgcn_mfma_f32_32x32x16_bf16(ah, bl, acc[nt], 0, 0, 0);
    }
    a0 = na0;
    a1 = na1;
    block_sync_lds();
  }

#pragma unroll
  for (int nt = 0; nt < 4; ++nt) {
#pragma unroll
    for (int r = 0; r < 16; ++r) {
      int rowi = (r & 3) + 8 * (r >> 2) + 4 * half;
      float v = acc[nt][r] + bv1[nt] + degS[wid * 32 + rowi] * bva[nt];
      hid[wid][rowi][nt * 32 + m] = (__bf16)fmaxf(v, 0.f);
      acc[nt][r] = 0.f;
    }
  }
  wait_lds();

  for (int s = 16; s < NODE_CHUNKS; ++s) {
    int buf = s & 1;
    if (s + 1 < NODE_CHUNKS) {
      short8* sb = buf ? sB0 : sB1;
      sb[tid] = p0;
      sb[tid + 256] = p1;
      if (s + 2 < NODE_CHUNKS) {
        p0 = gW[(size_t)(s + 2) * 512 + tid];
        p1 = gW[(size_t)(s + 2) * 512 + tid + 256];
      }
    }
    bf16x8 ah = *(const bf16x8*)&hid[wid][m][(s - 16) * 16 + half * 8];
    const __bf16* bb = &Bt[buf][0];
#pragma unroll
    for (int nt = 0; nt < 4; ++nt) {
      bf16x8 bh = *(const bf16x8*)&bb[((0 * 4 + nt) * 64 + lane) * 8];
      bf16x8 bl = *(const bf16x8*)&bb[((1 * 4 + nt) * 64 + lane) * 8];
      acc[nt] = __builtin_amdgcn_mfma_f32_32x32x16_bf16(ah, bh, acc[nt], 0, 0, 0);
      acc[nt] = __builtin_amdgcn_mfma_f32_32x32x16_bf16(ah, bl, acc[nt], 0, 0, 0);
    }
    if (s + 1 < NODE_CHUNKS) block_sync_lds();
  }

#pragma unroll
  for (int nt = 0; nt < 4; ++nt) {
    float b2 = ub2[nt * 32 + m];
#pragma unroll
    for (int r = 0; r < 16; ++r) {
      int rowi = (r & 3) + 8 * (r >> 2) + 4 * half;
      float* hp = h + (size_t)(nb + wid * 32 + rowi) * H + nt * 32 + m;
      *hp += acc[nt][r] + b2;
    }
  }
}

// ---------------- batch mean pooling (batch is sorted) ----------------
__global__ __launch_bounds__(128) void pool_kernel(
    const float* __restrict__ h, const int* __restrict__ batch,
    float* __restrict__ pooled, int* __restrict__ counts) {
  int j = threadIdx.x;
  int nbase = blockIdx.x * 128;
  int nend = nbase + 128;
  if (nend > NN) nend = NN;
  if (nbase >= NN) return;
  int cur = batch[nbase];
  float sum = 0.f;
  int cnt = 0;
  for (int n = nbase; n < nend; ++n) {
    int b = batch[n];
    if (b != cur) {
      unsafeAtomicAdd(&pooled[cur * H + j], sum);
      if (j == 0) atomicAdd(&counts[cur], cnt);
      sum = 0.f; cnt = 0; cur = b;
    }
    sum += h[(size_t)n * H + j];
    cnt++;
  }
  unsafeAtomicAdd(&pooled[cur * H + j], sum);
  if (j == 0) atomicAdd(&counts[cur], cnt);
}

// ---------------- readout MLP ----------------
__global__ __launch_bounds__(128) void readout_kernel(
    const float* __restrict__ pooled, const int* __restrict__ counts,
    const float* __restrict__ gf, const float* __restrict__ Wg,
    const float* __restrict__ bg, const float* __restrict__ rW1,
    const float* __restrict__ rb1, const float* __restrict__ rW2,
    const float* __restrict__ rb2, const float* __restrict__ rW3,
    const float* __restrict__ rb3, float* __restrict__ out) {
  __shared__ float fin[256];
  __shared__ float t1[128];
  __shared__ float t2[64];
  int j = threadIdx.x;
  for (int b = 0; b < NBATCH; ++b) {
    float cnt = (float)counts[b];
    if (cnt < 1.f) cnt = 1.f;
    fin[j] = pooled[b * H + j] / cnt;
    fin[H + j] = fmaf(gf[b], Wg[j], bg[j]);
    __syncthreads();
    float a = rb1[j];
    for (int k = 0; k < 256; ++k) a = fmaf(fin[k], rW1[k * H + j], a);
    t1[j] = fmaxf(a, 0.f);
    __syncthreads();
    if (j < 64) {
      float a2 = rb2[j];
      for (int k = 0; k < 128; ++k) a2 = fmaf(t1[k], rW2[k * 64 + j], a2);
      t2[j] = fmaxf(a2, 0.f);
    }
    __syncthreads();
    if (j < 64) {
      float p = t2[j] * rW3[j];
#pragma unroll
      for (int off = 32; off; off >>= 1) p += __shfl_down(p, off);
      if (j == 0) out[b] = p + rb3[0];
    }
    __syncthreads();
  }
}

extern "C" void kernel_launch(void* const* d_in, const int* in_sizes, int n_in,
                              void* d_out, int out_size, void* d_ws, size_t ws_size,
                              hipStream_t stream) {
  const float* x   = (const float*)d_in[0];
  const float* ea  = (const float*)d_in[1];
  const float* gf  = (const float*)d_in[2];
  const int*   ei  = (const int*)d_in[3];
  const int*   bat = (const int*)d_in[4];
  const float* Wn  = (const float*)d_in[5];
  const float* bn  = (const float*)d_in[6];
  const float* We  = (const float*)d_in[7];
  const float* be  = (const float*)d_in[8];
  const float* Wg  = (const float*)d_in[9];
  const float* bg  = (const float*)d_in[10];
  const float* mW1 = (const float*)d_in[11];
  const float* mb1 = (const float*)d_in[12];
  const float* mW2 = (const float*)d_in[13];
  const float* mb2 = (const float*)d_in[14];
  const float* uW1 = (const float*)d_in[15];
  const float* ub1 = (const float*)d_in[16];
  const float* uW2 = (const float*)d_in[17];
  const float* ub2 = (const float*)d_in[18];
  const float* rW1 = (const float*)d_in[19];
  const float* rb1 = (const float*)d_in[20];
  const float* rW2 = (const float*)d_in[21];
  const float* rb2 = (const float*)d_in[22];
  const float* rW3 = (const float*)d_in[23];
  const float* rb3 = (const float*)d_in[24];

  char* p = (char*)d_ws;
  float*  h      = (float*)p;  p += (size_t)NPAD * H * 4;        // 25.6 MB
  float*  aggrH  = (float*)p;  p += (size_t)NPAD * H * 4;        // 25.6 MB
  float*  z      = (float*)p;  p += (size_t)NPAD * 256 * 4;      // 51.2 MB
  float*  eaSrt  = (float*)p;  p += (size_t)NE * EDIM * 4;       // 25.6 MB
  int*    srcSrt = (int*)p;    p += (size_t)NE * 4;
  int*    dstSrt = (int*)p;    p += (size_t)NE * 4;
  int*    eidSrt = (int*)p;    p += (size_t)NE * 4;
  __bf16* ZW     = (__bf16*)p; p += (size_t)NLAYERS * 8 * ZW_CHUNK * 2;
  __bf16* WnS    = (__bf16*)p; p += (size_t)NLAYERS * NODE_CHUNKS * CHUNK_ELEMS * 2;
  float*  Wef    = (float*)p;  p += (size_t)NLAYERS * EDIM * H * 4;
  float*  bm     = (float*)p;  p += (size_t)NLAYERS * H * 4;
  float*  Wu     = (float*)p;  p += (size_t)NLAYERS * 256 * H * 4;
  float*  va     = (float*)p;  p += (size_t)NLAYERS * H * 4;
  int*    deg    = (int*)p;    p += (size_t)NPAD * 4;
  int*    cursor = (int*)p;    p += (size_t)NPAD * 4;
  int*    bsum   = (int*)p;    p += 256 * 4;
  int*    boff   = (int*)p;    p += 256 * 4;
  float*  pooled = (float*)p;  p += (size_t)NBATCH * H * 4;
  int*    counts = (int*)p;    p += 64;

  hipMemsetAsync(deg, 0, (size_t)NPAD * 4, stream);
  hipMemsetAsync(pooled, 0, (size_t)NBATCH * H * 4, stream);
  hipMemsetAsync(counts, 0, 64, stream);

  embed_nodes_kernel<<<NN / 16, 128, 0, stream>>>(x, Wn, bn, h);
  degree_kernel<<<(NE + 255) / 256, 256, 0, stream>>>(ei, deg);
  scan1_kernel<<<NSB, 256, 0, stream>>>(deg, bsum);
  scan2_kernel<<<1, 256, 0, stream>>>(bsum, boff);
  scan3_kernel<<<NSB, 256, 0, stream>>>(deg, boff, cursor);
  scatter_kernel<<<(NE + 255) / 256, 256, 0, stream>>>(ei, cursor, srcSrt,
                                                       dstSrt, eidSrt);
  gather_ea_kernel<<<(NE * 16 + 1023) / 1024, 256, 0, stream>>>(ea, eidSrt, eaSrt);
  precomp_zw_kernel<<<NLAYERS * 8, 256, 0, stream>>>(mW1, ZW);
  precomp_wef_kernel<<<NLAYERS, 128, 0, stream>>>(mW1, mb1, We, be, Wef, bm);
  precomp_wu_kernel<<<NLAYERS * 257, 128, 0, stream>>>(uW1, mW2, mb2, Wu, va);
  precomp_wns_kernel<<<NLAYERS * NODE_CHUNKS, 256, 0, stream>>>(Wu, uW2, WnS);

  for (int l = 0; l < NLAYERS; ++l) {
    hipMemsetAsync(aggrH, 0, (size_t)NPAD * H * 4, stream);
    zdzs_kernel<<<NBLK, 256, 0, stream>>>(
        h, ZW + (size_t)l * 8 * ZW_CHUNK, bm + (size_t)l * H, z);
    edge_aggr_kernel<<<NE / EAB, 256, 0, stream>>>(
        z, srcSrt, dstSrt, eaSrt, Wef + (size_t)l * EDIM * H, aggrH);
    node_update_mfma_kernel<<<NBLK, 256, 0, stream>>>(
        h, aggrH, deg, WnS + (size_t)l * NODE_CHUNKS * CHUNK_ELEMS,
        ub1 + (size_t)l * H, va + (size_t)l * H, ub2 + (size_t)l * H);
  }

  pool_kernel<<<(NN + 127) / 128, 128, 0, stream>>>(h, bat, pooled, counts);
  readout_kernel<<<1, 128, 0, stream>>>(pooled, counts, gf, Wg, bg, rW1, rb1,
                                        rW2, rb2, rW3, rb3, (float*)d_out);
}

// Round 12
// 658.844 us; speedup vs baseline: 1.4949x; 1.0541x over previous
//
#include <hip/hip_runtime.h>

#define NN 50000
#define NPAD 50048     // 391 * 128
#define NBLK 391
#define NE 400000
#define NBATCH 8
#define NDIM 32
#define EDIM 16
#define H 128
#define NLAYERS 3
#define CHUNK_ELEMS 4096   // node-kernel weight chunk: 2 hilo * 4 nt * 64 lane * 8
#define NODE_CHUNKS 24     // 16 (Wu, K=256) + 8 (uW2, K=128)
#define ZW_CHUNK 8192      // zdzs chunk: 2 hilo * 8 nt * 64 lane * 8
#define EAB 64             // edges per block in edge_aggr (4 waves x 16)
#define NSB 196            // scan blocks: ceil(50000/256)

typedef __attribute__((ext_vector_type(8))) __bf16 bf16x8;
typedef __attribute__((ext_vector_type(16))) float f32x16;
typedef __attribute__((ext_vector_type(8))) short short8;
typedef __attribute__((ext_vector_type(2))) float v2f;

__device__ __forceinline__ void block_sync_lds() {
  asm volatile("s_waitcnt lgkmcnt(0)\ns_barrier" ::: "memory");
}
__device__ __forceinline__ void wait_lds() {
  asm volatile("s_waitcnt lgkmcnt(0)" ::: "memory");
}
// one dword = 2 packed bf16 -> 2 fp32 (pure bit ops)
__device__ __forceinline__ v2f bf2f(unsigned u) {
  v2f r;
  r.x = __uint_as_float(u << 16);
  r.y = __uint_as_float(u & 0xffff0000u);
  return r;
}

// ---------------- node embedding: h = x @ Wn + bn ----------------
__global__ __launch_bounds__(128) void embed_nodes_kernel(
    const float* __restrict__ x, const float* __restrict__ Wn,
    const float* __restrict__ bn, float* __restrict__ h) {
  __shared__ float Ws[NDIM * H];
  __shared__ float xs[16 * NDIM];
  int j = threadIdx.x;
  int nbase = blockIdx.x * 16;
  for (int r = 0; r < NDIM; ++r) Ws[r * H + j] = Wn[r * H + j];
#pragma unroll
  for (int t = 0; t < 4; ++t) {
    int f = j + t * 128;
    xs[f] = x[nbase * NDIM + f];
  }
  __syncthreads();
  float b = bn[j];
  for (int nn = 0; nn < 16; ++nn) {
    float acc = b;
#pragma unroll
    for (int k = 0; k < NDIM; ++k)
      acc = fmaf(xs[nn * NDIM + k], Ws[k * H + j], acc);
    h[(size_t)(nbase + nn) * H + j] = acc;
  }
}

// ---------------- degree histogram over dst ----------------
__global__ __launch_bounds__(256) void degree_kernel(const int* __restrict__ ei,
                                                     int* __restrict__ deg) {
  int e = blockIdx.x * 256 + threadIdx.x;
  if (e < NE) atomicAdd(&deg[ei[NE + e]], 1);
}

// ---------------- parallel 3-phase exclusive scan of deg -> cursor ----------------
__global__ __launch_bounds__(256) void scan1_kernel(const int* __restrict__ deg,
                                                    int* __restrict__ bsum) {
  __shared__ int ws[4];
  int i = blockIdx.x * 256 + threadIdx.x;
  int lane = threadIdx.x & 63, wid = threadIdx.x >> 6;
  int v = (i < NN) ? deg[i] : 0;
#pragma unroll
  for (int off = 32; off; off >>= 1) v += __shfl_down(v, off);
  if (lane == 0) ws[wid] = v;
  __syncthreads();
  if (threadIdx.x == 0) bsum[blockIdx.x] = ws[0] + ws[1] + ws[2] + ws[3];
}

__global__ __launch_bounds__(256) void scan2_kernel(const int* __restrict__ bsum,
                                                    int* __restrict__ boff) {
  __shared__ int s[256];
  int t = threadIdx.x;
  int v = (t < NSB) ? bsum[t] : 0;
  s[t] = v;
  __syncthreads();
  for (int off = 1; off < 256; off <<= 1) {
    int u = (t >= off) ? s[t - off] : 0;
    __syncthreads();
    s[t] += u;
    __syncthreads();
  }
  if (t < NSB) boff[t] = s[t] - v;  // exclusive across blocks
}

__global__ __launch_bounds__(256) void scan3_kernel(const int* __restrict__ deg,
                                                    const int* __restrict__ boff,
                                                    int* __restrict__ cursor) {
  __shared__ int wsum[4], woff[4];
  int i = blockIdx.x * 256 + threadIdx.x;
  int lane = threadIdx.x & 63, wid = threadIdx.x >> 6;
  int orig = (i < NN) ? deg[i] : 0;
  int v = orig;
#pragma unroll
  for (int off = 1; off < 64; off <<= 1) {
    int u = __shfl_up(v, off);
    if (lane >= off) v += u;
  }
  if (lane == 63) wsum[wid] = v;
  __syncthreads();
  if (threadIdx.x == 0) {
    int r = 0;
#pragma unroll
    for (int w = 0; w < 4; ++w) {
      woff[w] = r;
      r += wsum[w];
    }
  }
  __syncthreads();
  if (i < NN) cursor[i] = (v - orig) + woff[wid] + boff[blockIdx.x];
}

// ---------------- counting-sort scatter: edges grouped by dst ----------------
__global__ __launch_bounds__(256) void scatter_kernel(
    const int* __restrict__ ei, int* __restrict__ cursor,
    int* __restrict__ srcSrt, int* __restrict__ dstSrt,
    int* __restrict__ eidSrt) {
  int e = blockIdx.x * 256 + threadIdx.x;
  if (e < NE) {
    int d = ei[NE + e];
    int pos = atomicAdd(&cursor[d], 1);
    dstSrt[pos] = d;
    srcSrt[pos] = ei[e];
    eidSrt[pos] = e;
  }
}

// ---------------- gather edge attrs into sorted order (once) ----------------
__global__ __launch_bounds__(256) void gather_ea_kernel(
    const float* __restrict__ ea, const int* __restrict__ eidSrt,
    float* __restrict__ eaSrt) {
  int j = blockIdx.x * 1024 + threadIdx.x * 4;  // float4 worth of floats
  int fl = j >> 4;  // edge (16 floats each)
  int q = (j >> 2) & 3;
  if (fl < NE) {
    int e = eidSrt[fl];
    float4 v = ((const float4*)(ea + (size_t)e * EDIM))[q];
    *(float4*)(eaSrt + (size_t)fl * EDIM + q * 4) = v;
  }
}

// ---------------- zdzs weights: mW1[0:256] -> hi/lo bf16, frag-swizzled ----------------
__global__ __launch_bounds__(256) void precomp_zw_kernel(
    const float* __restrict__ mW1, __bf16* __restrict__ ZW) {
  int l = blockIdx.x / 8;
  int c = blockIdx.x % 8;
  int tid = threadIdx.x;
  const float* w1 = mW1 + (size_t)l * 384 * H;
  __bf16* dst = ZW + ((size_t)l * 8 + c) * ZW_CHUNK;
  for (int it = 0; it < 32; ++it) {
    int flat = it * 256 + tid;
    int j = flat & 7;
    int lane = (flat >> 3) & 63;
    int nt = (flat >> 9) & 7;
    int hilo = flat >> 12;
    int k = c * 16 + ((lane >> 5) << 3) + j;
    int n = nt * 32 + (lane & 31);
    float w = (n < 128) ? w1[(size_t)k * H + n]
                        : w1[(size_t)(128 + k) * H + (n - 128)];
    __bf16 hi = (__bf16)w;
    __bf16 lo = (__bf16)(w - (float)hi);
    dst[flat] = hilo ? lo : hi;
  }
}

// ---------------- Wef = We @ mW1[256:384] (16x128), bm = mb1 + be @ ... ----------------
__global__ __launch_bounds__(128) void precomp_wef_kernel(
    const float* __restrict__ mW1, const float* __restrict__ mb1,
    const float* __restrict__ We, const float* __restrict__ be,
    float* __restrict__ Wef, float* __restrict__ bm) {
  int l = blockIdx.x;
  int n = threadIdx.x;
  const float* w1 = mW1 + (size_t)l * 384 * H;
  float acc[EDIM];
#pragma unroll
  for (int i = 0; i < EDIM; ++i) acc[i] = 0.f;
  float accb = 0.f;
  for (int c = 0; c < H; ++c) {
    float wv = w1[(size_t)(256 + c) * H + n];
    accb = fmaf(be[c], wv, accb);
#pragma unroll
    for (int i = 0; i < EDIM; ++i)
      acc[i] = fmaf(We[i * H + c], wv, acc[i]);
  }
#pragma unroll
  for (int i = 0; i < EDIM; ++i)
    Wef[((size_t)l * EDIM + i) * H + n] = acc[i];
  bm[l * H + n] = mb1[l * H + n] + accb;
}

// ---------------- precompute folded update weights (fp32 Wu) ----------------
__global__ __launch_bounds__(128) void precomp_wu_kernel(
    const float* __restrict__ uW1, const float* __restrict__ mW2,
    const float* __restrict__ mb2, float* __restrict__ Wu,
    float* __restrict__ va) {
  int l = blockIdx.x / 257;
  int r = blockIdx.x % 257;
  int j = threadIdx.x;
  const float* u1 = uW1 + (size_t)l * 256 * H;
  if (r < 128) {
    Wu[((size_t)l * 256 + r) * H + j] = u1[(size_t)r * H + j];
  } else if (r < 256) {
    int i = r - 128;
    const float* m2 = mW2 + ((size_t)l * H + i) * H;
    float s = 0.f;
    for (int c = 0; c < H; ++c)
      s = fmaf(m2[c], u1[(size_t)(128 + c) * H + j], s);
    Wu[((size_t)l * 256 + r) * H + j] = s;
  } else {
    float s = 0.f;
    for (int c = 0; c < H; ++c)
      s = fmaf(mb2[l * H + c], u1[(size_t)(128 + c) * H + j], s);
    va[l * H + j] = s;
  }
}

// ---------------- swizzle node weights into hi/lo frag chunks ----------------
__global__ __launch_bounds__(256) void precomp_wns_kernel(
    const float* __restrict__ Wu, const float* __restrict__ uW2,
    __bf16* __restrict__ WnS) {
  int l = blockIdx.x / NODE_CHUNKS;
  int c = blockIdx.x % NODE_CHUNKS;
  int tid = threadIdx.x;
  int nt = tid >> 6, lane = tid & 63;
  int n = nt * 32 + (lane & 31);
  int half = lane >> 5;
  __bf16* dst = WnS + ((size_t)l * NODE_CHUNKS + c) * CHUNK_ELEMS;
#pragma unroll
  for (int j = 0; j < 8; ++j) {
    float w;
    if (c < 16) {
      int k = c * 16 + half * 8 + j;
      w = Wu[((size_t)l * 256 + k) * H + n];
    } else {
      int k = (c - 16) * 16 + half * 8 + j;
      w = uW2[((size_t)l * H + k) * H + n];
    }
    __bf16 hi = (__bf16)w;
    __bf16 lo = (__bf16)(w - (float)hi);
    dst[((0 * 4 + nt) * 64 + lane) * 8 + j] = hi;
    dst[((1 * 4 + nt) * 64 + lane) * 8 + j] = lo;
  }
}

// ---------------- z = h @ [W_d|W_s] (+bm on dst half) -> bf16; also zeroes aggrH ----------------
__global__ __launch_bounds__(256) void zdzs_kernel(
    const float* __restrict__ h, const __bf16* __restrict__ ZW,
    const float* __restrict__ bm, __bf16* __restrict__ z,
    float* __restrict__ aggrH) {
  __shared__ __align__(16) __bf16 Bt[2][ZW_CHUNK];  // 32 KB
  int tid = threadIdx.x;
  int wid = tid >> 6, lane = tid & 63, m = lane & 31, half = lane >> 5;
  int nb = blockIdx.x * 128;
  int row = nb + wid * 32 + m;
  const float* aH = h + (size_t)row * H + half * 8;
  const short8* gW = (const short8*)ZW;  // 1024 short8 per chunk
  short8* sB0 = (short8*)&Bt[0][0];
  short8* sB1 = (short8*)&Bt[1][0];
#pragma unroll
  for (int q = 0; q < 4; ++q) sB0[tid + q * 256] = gW[tid + q * 256];
  short8 p0 = gW[1024 + tid], p1 = gW[1024 + tid + 256];
  short8 p2 = gW[1024 + tid + 512], p3 = gW[1024 + tid + 768];
  // zero this block's aggrH rows (replaces per-layer memset dispatch)
  {
    float4 zf4 = {0.f, 0.f, 0.f, 0.f};
    float4* ag = (float4*)(aggrH + (size_t)nb * H);
#pragma unroll
    for (int q = 0; q < 16; ++q) ag[q * 256 + tid] = zf4;
  }
  f32x16 acc[8];
#pragma unroll
  for (int nt = 0; nt < 8; ++nt)
#pragma unroll
    for (int r = 0; r < 16; ++r) acc[nt][r] = 0.f;
  float4 a0 = *(const float4*)aH;
  float4 a1 = *(const float4*)(aH + 4);
  block_sync_lds();

  for (int s = 0; s < 8; ++s) {
    int buf = s & 1;
    float4 na0 = a0, na1 = a1;
    if (s + 1 < 8) {
      const float* pp = aH + (s + 1) * 16;
      na0 = *(const float4*)pp;
      na1 = *(const float4*)(pp + 4);
    }
    if (s + 1 < 8) {
      short8* sb = buf ? sB0 : sB1;
      sb[tid] = p0;
      sb[tid + 256] = p1;
      sb[tid + 512] = p2;
      sb[tid + 768] = p3;
      if (s + 2 < 8) {
        p0 = gW[(size_t)(s + 2) * 1024 + tid];
        p1 = gW[(size_t)(s + 2) * 1024 + tid + 256];
        p2 = gW[(size_t)(s + 2) * 1024 + tid + 512];
        p3 = gW[(size_t)(s + 2) * 1024 + tid + 768];
      }
    }
    float af[8] = {a0.x, a0.y, a0.z, a0.w, a1.x, a1.y, a1.z, a1.w};
    bf16x8 ah, al;
#pragma unroll
    for (int j = 0; j < 8; ++j) {
      __bf16 hi = (__bf16)af[j];
      ah[j] = hi;
      al[j] = (__bf16)(af[j] - (float)hi);
    }
    const __bf16* bb = &Bt[buf][0];
#pragma unroll
    for (int nt = 0; nt < 8; ++nt) {
      bf16x8 bh = *(const bf16x8*)&bb[((0 * 8 + nt) * 64 + lane) * 8];
      bf16x8 bl = *(const bf16x8*)&bb[((1 * 8 + nt) * 64 + lane) * 8];
      acc[nt] = __builtin_amdgcn_mfma_f32_32x32x16_bf16(ah, bh, acc[nt], 0, 0, 0);
      acc[nt] = __builtin_amdgcn_mfma_f32_32x32x16_bf16(al, bh, acc[nt], 0, 0, 0);
      acc[nt] = __builtin_amdgcn_mfma_f32_32x32x16_bf16(ah, bl, acc[nt], 0, 0, 0);
    }
    a0 = na0;
    a1 = na1;
    if (s + 1 < 8) block_sync_lds();
  }

  float bmv[4];
#pragma unroll
  for (int nt = 0; nt < 4; ++nt) bmv[nt] = bm[nt * 32 + m];
#pragma unroll
  for (int nt = 0; nt < 8; ++nt) {
    float bias = (nt < 4) ? bmv[nt] : 0.f;
#pragma unroll
    for (int r = 0; r < 16; ++r) {
      int rowi = (r & 3) + 8 * (r >> 2) + 4 * half;
      z[(size_t)(nb + wid * 32 + rowi) * 256 + nt * 32 + m] =
          (__bf16)(acc[nt][r] + bias);
    }
  }
}

// ---------------- sorted-edge aggregation: aggr[dst] += relu(z_d+z_s+ze) ----------------
// z is bf16: one dword per lane per side (2 cols), expanded by bit-shift.
__global__ __launch_bounds__(256) void edge_aggr_kernel(
    const __bf16* __restrict__ z, const int* __restrict__ srcSrt,
    const int* __restrict__ dstSrt, const float* __restrict__ eaSrt,
    const float* __restrict__ Wef, float* __restrict__ aggrH) {
  __shared__ float eaS[EAB * EDIM];  // 4 KB
  __shared__ int dstS[EAB], srcS[EAB];
  int tid = threadIdx.x;
  int e0b = blockIdx.x * EAB;
  {
    float4 v = ((const float4*)(eaSrt + (size_t)e0b * EDIM))[tid];
    *(float4*)&eaS[tid * 4] = v;
  }
  if (tid < EAB) dstS[tid] = dstSrt[e0b + tid];
  else if (tid < 2 * EAB) srcS[tid - EAB] = srcSrt[e0b + tid - EAB];
  __syncthreads();
  int wid = tid >> 6, lane = tid & 63;
  int eb = wid * 16;
  int c0 = lane * 2;
  v2f w[EDIM];
#pragma unroll
  for (int k = 0; k < EDIM; ++k)
    w[k] = *(const v2f*)(Wef + (size_t)k * H + c0);
  unsigned zdu[16], zsu[16];
#pragma unroll
  for (int i = 0; i < 16; ++i) {
    zdu[i] = *(const unsigned*)(z + (size_t)dstS[eb + i] * 256 + c0);
    zsu[i] = *(const unsigned*)(z + (size_t)srcS[eb + i] * 256 + 128 + c0);
  }
  int cur = __builtin_amdgcn_readfirstlane(dstS[eb]);
  v2f acc = {0.f, 0.f};
#pragma unroll
  for (int i = 0; i < 16; ++i) {
    const float4* ep = (const float4*)&eaS[(eb + i) * EDIM];
    float4 g0 = ep[0], g1 = ep[1], g2 = ep[2], g3 = ep[3];
    v2f ze = g0.x * w[0];
    ze += g0.y * w[1];
    ze += g0.z * w[2];
    ze += g0.w * w[3];
    ze += g1.x * w[4];
    ze += g1.y * w[5];
    ze += g1.z * w[6];
    ze += g1.w * w[7];
    ze += g2.x * w[8];
    ze += g2.y * w[9];
    ze += g2.z * w[10];
    ze += g2.w * w[11];
    ze += g3.x * w[12];
    ze += g3.y * w[13];
    ze += g3.z * w[14];
    ze += g3.w * w[15];
    int d = __builtin_amdgcn_readfirstlane(dstS[eb + i]);
    if (d != cur) {
      float* ap = aggrH + (size_t)cur * H + c0;
      unsafeAtomicAdd(ap, acc.x);
      unsafeAtomicAdd(ap + 1, acc.y);
      acc.x = 0.f;
      acc.y = 0.f;
      cur = d;
    }
    v2f t = bf2f(zdu[i]) + bf2f(zsu[i]) + ze;
    acc.x += fmaxf(t.x, 0.f);
    acc.y += fmaxf(t.y, 0.f);
  }
  float* ap = aggrH + (size_t)cur * H + c0;
  unsafeAtomicAdd(ap, acc.x);
  unsafeAtomicAdd(ap + 1, acc.y);
}

// ---------------- MFMA fused node update ----------------
__global__ __launch_bounds__(256) void node_update_mfma_kernel(
    float* __restrict__ h, const float* __restrict__ aggrH,
    const int* __restrict__ deg, const __bf16* __restrict__ WnS,
    const float* __restrict__ ub1, const float* __restrict__ va,
    const float* __restrict__ ub2) {
  __shared__ __align__(16) __bf16 Bt[2][CHUNK_ELEMS];
  __shared__ __bf16 hid[4][32][132];
  __shared__ float degS[128];
  int tid = threadIdx.x;
  int nb = blockIdx.x * 128;
  if (tid < 128) degS[tid] = (float)deg[nb + tid];
  int wid = tid >> 6, lane = tid & 63, m = lane & 31, half = lane >> 5;
  int row = nb + wid * 32 + m;
  const float* aH = h + (size_t)row * H + half * 8;
  const float* aG = aggrH + (size_t)row * H + half * 8;
  const short8* gW = (const short8*)WnS;
  short8* sB0 = (short8*)&Bt[0][0];
  short8* sB1 = (short8*)&Bt[1][0];
  sB0[tid] = gW[tid];
  sB0[tid + 256] = gW[tid + 256];
  short8 p0 = gW[512 + tid], p1 = gW[512 + tid + 256];
  float bv1[4], bva[4];
#pragma unroll
  for (int nt = 0; nt < 4; ++nt) {
    bv1[nt] = ub1[nt * 32 + m];
    bva[nt] = va[nt * 32 + m];
  }
  f32x16 acc[4];
#pragma unroll
  for (int nt = 0; nt < 4; ++nt)
#pragma unroll
    for (int r = 0; r < 16; ++r) acc[nt][r] = 0.f;
  float4 a0 = *(const float4*)aH;
  float4 a1 = *(const float4*)(aH + 4);
  block_sync_lds();

  for (int s = 0; s < 16; ++s) {
    int buf = s & 1;
    float4 na0 = a0, na1 = a1;
    if (s + 1 < 16) {
      int sp = s + 1;
      const float* pp = (sp < 8) ? (aH + sp * 16) : (aG + (sp - 8) * 16);
      na0 = *(const float4*)pp;
      na1 = *(const float4*)(pp + 4);
    }
    {
      short8* sb = buf ? sB0 : sB1;
      sb[tid] = p0;
      sb[tid + 256] = p1;
      if (s + 2 < NODE_CHUNKS) {
        p0 = gW[(size_t)(s + 2) * 512 + tid];
        p1 = gW[(size_t)(s + 2) * 512 + tid + 256];
      }
    }
    float af[8] = {a0.x, a0.y, a0.z, a0.w, a1.x, a1.y, a1.z, a1.w};
    bf16x8 ah;
#pragma unroll
    for (int j = 0; j < 8; ++j) ah[j] = (__bf16)af[j];
    const __bf16* bb = &Bt[buf][0];
#pragma unroll
    for (int nt = 0; nt < 4; ++nt) {
      bf16x8 bh = *(const bf16x8*)&bb[((0 * 4 + nt) * 64 + lane) * 8];
      bf16x8 bl = *(const bf16x8*)&bb[((1 * 4 + nt) * 64 + lane) * 8];
      acc[nt] = __builtin_amdgcn_mfma_f32_32x32x16_bf16(ah, bh, acc[nt], 0, 0, 0);
      acc[nt] = __builtin_amdgcn_mfma_f32_32x32x16_bf16(ah, bl, acc[nt], 0, 0, 0);
    }
    a0 = na0;
    a1 = na1;
    block_sync_lds();
  }

#pragma unroll
  for (int nt = 0; nt < 4; ++nt) {
#pragma unroll
    for (int r = 0; r < 16; ++r) {
      int rowi = (r & 3) + 8 * (r >> 2) + 4 * half;
      float v = acc[nt][r] + bv1[nt] + degS[wid * 32 + rowi] * bva[nt];
      hid[wid][rowi][nt * 32 + m] = (__bf16)fmaxf(v, 0.f);
      acc[nt][r] = 0.f;
    }
  }
  wait_lds();

  for (int s = 16; s < NODE_CHUNKS; ++s) {
    int buf = s & 1;
    if (s + 1 < NODE_CHUNKS) {
      short8* sb = buf ? sB0 : sB1;
      sb[tid] = p0;
      sb[tid + 256] = p1;
      if (s + 2 < NODE_CHUNKS) {
        p0 = gW[(size_t)(s + 2) * 512 + tid];
        p1 = gW[(size_t)(s + 2) * 512 + tid + 256];
      }
    }
    bf16x8 ah = *(const bf16x8*)&hid[wid][m][(s - 16) * 16 + half * 8];
    const __bf16* bb = &Bt[buf][0];
#pragma unroll
    for (int nt = 0; nt < 4; ++nt) {
      bf16x8 bh = *(const bf16x8*)&bb[((0 * 4 + nt) * 64 + lane) * 8];
      bf16x8 bl = *(const bf16x8*)&bb[((1 * 4 + nt) * 64 + lane) * 8];
      acc[nt] = __builtin_amdgcn_mfma_f32_32x32x16_bf16(ah, bh, acc[nt], 0, 0, 0);
      acc[nt] = __builtin_amdgcn_mfma_f32_32x32x16_bf16(ah, bl, acc[nt], 0, 0, 0);
    }
    if (s + 1 < NODE_CHUNKS) block_sync_lds();
  }

#pragma unroll
  for (int nt = 0; nt < 4; ++nt) {
    float b2 = ub2[nt * 32 + m];
#pragma unroll
    for (int r = 0; r < 16; ++r) {
      int rowi = (r & 3) + 8 * (r >> 2) + 4 * half;
      float* hp = h + (size_t)(nb + wid * 32 + rowi) * H + nt * 32 + m;
      *hp += acc[nt][r] + b2;
    }
  }
}

// ---------------- batch mean pooling (batch is sorted) ----------------
__global__ __launch_bounds__(128) void pool_kernel(
    const float* __restrict__ h, const int* __restrict__ batch,
    float* __restrict__ pooled, int* __restrict__ counts) {
  int j = threadIdx.x;
  int nbase = blockIdx.x * 128;
  int nend = nbase + 128;
  if (nend > NN) nend = NN;
  if (nbase >= NN) return;
  int cur = batch[nbase];
  float sum = 0.f;
  int cnt = 0;
  for (int n = nbase; n < nend; ++n) {
    int b = batch[n];
    if (b != cur) {
      unsafeAtomicAdd(&pooled[cur * H + j], sum);
      if (j == 0) atomicAdd(&counts[cur], cnt);
      sum = 0.f; cnt = 0; cur = b;
    }
    sum += h[(size_t)n * H + j];
    cnt++;
  }
  unsafeAtomicAdd(&pooled[cur * H + j], sum);
  if (j == 0) atomicAdd(&counts[cur], cnt);
}

// ---------------- readout MLP ----------------
__global__ __launch_bounds__(128) void readout_kernel(
    const float* __restrict__ pooled, const int* __restrict__ counts,
    const float* __restrict__ gf, const float* __restrict__ Wg,
    const float* __restrict__ bg, const float* __restrict__ rW1,
    const float* __restrict__ rb1, const float* __restrict__ rW2,
    const float* __restrict__ rb2, const float* __restrict__ rW3,
    const float* __restrict__ rb3, float* __restrict__ out) {
  __shared__ float fin[256];
  __shared__ float t1[128];
  __shared__ float t2[64];
  int j = threadIdx.x;
  for (int b = 0; b < NBATCH; ++b) {
    float cnt = (float)counts[b];
    if (cnt < 1.f) cnt = 1.f;
    fin[j] = pooled[b * H + j] / cnt;
    fin[H + j] = fmaf(gf[b], Wg[j], bg[j]);
    __syncthreads();
    float a = rb1[j];
    for (int k = 0; k < 256; ++k) a = fmaf(fin[k], rW1[k * H + j], a);
    t1[j] = fmaxf(a, 0.f);
    __syncthreads();
    if (j < 64) {
      float a2 = rb2[j];
      for (int k = 0; k < 128; ++k) a2 = fmaf(t1[k], rW2[k * 64 + j], a2);
      t2[j] = fmaxf(a2, 0.f);
    }
    __syncthreads();
    if (j < 64) {
      float p = t2[j] * rW3[j];
#pragma unroll
      for (int off = 32; off; off >>= 1) p += __shfl_down(p, off);
      if (j == 0) out[b] = p + rb3[0];
    }
    __syncthreads();
  }
}

extern "C" void kernel_launch(void* const* d_in, const int* in_sizes, int n_in,
                              void* d_out, int out_size, void* d_ws, size_t ws_size,
                              hipStream_t stream) {
  const float* x   = (const float*)d_in[0];
  const float* ea  = (const float*)d_in[1];
  const float* gf  = (const float*)d_in[2];
  const int*   ei  = (const int*)d_in[3];
  const int*   bat = (const int*)d_in[4];
  const float* Wn  = (const float*)d_in[5];
  const float* bn  = (const float*)d_in[6];
  const float* We  = (const float*)d_in[7];
  const float* be  = (const float*)d_in[8];
  const float* Wg  = (const float*)d_in[9];
  const float* bg  = (const float*)d_in[10];
  const float* mW1 = (const float*)d_in[11];
  const float* mb1 = (const float*)d_in[12];
  const float* mW2 = (const float*)d_in[13];
  const float* mb2 = (const float*)d_in[14];
  const float* uW1 = (const float*)d_in[15];
  const float* ub1 = (const float*)d_in[16];
  const float* uW2 = (const float*)d_in[17];
  const float* ub2 = (const float*)d_in[18];
  const float* rW1 = (const float*)d_in[19];
  const float* rb1 = (const float*)d_in[20];
  const float* rW2 = (const float*)d_in[21];
  const float* rb2 = (const float*)d_in[22];
  const float* rW3 = (const float*)d_in[23];
  const float* rb3 = (const float*)d_in[24];

  char* p = (char*)d_ws;
  float*  h      = (float*)p;  p += (size_t)NPAD * H * 4;        // 25.6 MB
  float*  aggrH  = (float*)p;  p += (size_t)NPAD * H * 4;        // 25.6 MB
  __bf16* z      = (__bf16*)p; p += (size_t)NPAD * 256 * 2;      // 25.6 MB
  float*  eaSrt  = (float*)p;  p += (size_t)NE * EDIM * 4;       // 25.6 MB
  int*    srcSrt = (int*)p;    p += (size_t)NE * 4;
  int*    dstSrt = (int*)p;    p += (size_t)NE * 4;
  int*    eidSrt = (int*)p;    p += (size_t)NE * 4;
  __bf16* ZW     = (__bf16*)p; p += (size_t)NLAYERS * 8 * ZW_CHUNK * 2;
  __bf16* WnS    = (__bf16*)p; p += (size_t)NLAYERS * NODE_CHUNKS * CHUNK_ELEMS * 2;
  float*  Wef    = (float*)p;  p += (size_t)NLAYERS * EDIM * H * 4;
  float*  bm     = (float*)p;  p += (size_t)NLAYERS * H * 4;
  float*  Wu     = (float*)p;  p += (size_t)NLAYERS * 256 * H * 4;
  float*  va     = (float*)p;  p += (size_t)NLAYERS * H * 4;
  int*    deg    = (int*)p;    p += (size_t)NPAD * 4;
  int*    cursor = (int*)p;    p += (size_t)NPAD * 4;
  int*    bsum   = (int*)p;    p += 256 * 4;
  int*    boff   = (int*)p;    p += 256 * 4;
  float*  pooled = (float*)p;  p += (size_t)NBATCH * H * 4;
  int*    counts = (int*)p;    p += 64;

  hipMemsetAsync(deg, 0, (size_t)NPAD * 4, stream);
  hipMemsetAsync(pooled, 0, (size_t)NBATCH * H * 4, stream);
  hipMemsetAsync(counts, 0, 64, stream);

  embed_nodes_kernel<<<NN / 16, 128, 0, stream>>>(x, Wn, bn, h);
  degree_kernel<<<(NE + 255) / 256, 256, 0, stream>>>(ei, deg);
  scan1_kernel<<<NSB, 256, 0, stream>>>(deg, bsum);
  scan2_kernel<<<1, 256, 0, stream>>>(bsum, boff);
  scan3_kernel<<<NSB, 256, 0, stream>>>(deg, boff, cursor);
  scatter_kernel<<<(NE + 255) / 256, 256, 0, stream>>>(ei, cursor, srcSrt,
                                                       dstSrt, eidSrt);
  gather_ea_kernel<<<(NE * 16 + 1023) / 1024, 256, 0, stream>>>(ea, eidSrt, eaSrt);
  precomp_zw_kernel<<<NLAYERS * 8, 256, 0, stream>>>(mW1, ZW);
  precomp_wef_kernel<<<NLAYERS, 128, 0, stream>>>(mW1, mb1, We, be, Wef, bm);
  precomp_wu_kernel<<<NLAYERS * 257, 128, 0, stream>>>(uW1, mW2, mb2, Wu, va);
  precomp_wns_kernel<<<NLAYERS * NODE_CHUNKS, 256, 0, stream>>>(Wu, uW2, WnS);

  for (int l = 0; l < NLAYERS; ++l) {
    zdzs_kernel<<<NBLK, 256, 0, stream>>>(
        h, ZW + (size_t)l * 8 * ZW_CHUNK, bm + (size_t)l * H, z, aggrH);
    edge_aggr_kernel<<<NE / EAB, 256, 0, stream>>>(
        z, srcSrt, dstSrt, eaSrt, Wef + (size_t)l * EDIM * H, aggrH);
    node_update_mfma_kernel<<<NBLK, 256, 0, stream>>>(
        h, aggrH, deg, WnS + (size_t)l * NODE_CHUNKS * CHUNK_ELEMS,
        ub1 + (size_t)l * H, va + (size_t)l * H, ub2 + (size_t)l * H);
  }

  pool_kernel<<<(NN + 127) / 128, 128, 0, stream>>>(h, bat, pooled, counts);
  readout_kernel<<<1, 128, 0, stream>>>(pooled, counts, gf, Wg, bg, rW1, rb1,
                                        rW2, rb2, rW3, rb3, (float*)d_out);
}

// Round 13
// 634.294 us; speedup vs baseline: 1.5528x; 1.0387x over previous
//
#include <hip/hip_runtime.h>

#define NN 50000
#define NPAD 50048     // 391 * 128
#define NBLK 391
#define NE 400000
#define NBATCH 8
#define NDIM 32
#define EDIM 16
#define H 128
#define NLAYERS 3
#define CHUNK_ELEMS 4096   // node-kernel weight chunk: 2 hilo * 4 nt * 64 lane * 8
#define NODE_CHUNKS 24     // 16 (Wu, K=256) + 8 (uW2, K=128)
#define ZW_CHUNK 8192      // zdzs chunk: 2 hilo * 8 nt * 64 lane * 8
#define EAB 64             // edges per block in edge_aggr (4 waves x 16)
#define NSB 196            // scan blocks: ceil(50000/256)

typedef __attribute__((ext_vector_type(8))) __bf16 bf16x8;
typedef __attribute__((ext_vector_type(16))) float f32x16;
typedef __attribute__((ext_vector_type(8))) short short8;
typedef __attribute__((ext_vector_type(2))) float v2f;

__device__ __forceinline__ void block_sync_lds() {
  asm volatile("s_waitcnt lgkmcnt(0)\ns_barrier" ::: "memory");
}
__device__ __forceinline__ void wait_lds() {
  asm volatile("s_waitcnt lgkmcnt(0)" ::: "memory");
}
// one dword = 2 packed bf16 -> 2 fp32 (pure bit ops)
__device__ __forceinline__ v2f bf2f(unsigned u) {
  v2f r;
  r.x = __uint_as_float(u << 16);
  r.y = __uint_as_float(u & 0xffff0000u);
  return r;
}

// ---------------- node embedding: h = x @ Wn + bn (bf16 out) ----------------
__global__ __launch_bounds__(128) void embed_nodes_kernel(
    const float* __restrict__ x, const float* __restrict__ Wn,
    const float* __restrict__ bn, __bf16* __restrict__ hb) {
  __shared__ float Ws[NDIM * H];
  __shared__ float xs[16 * NDIM];
  int j = threadIdx.x;
  int nbase = blockIdx.x * 16;
  for (int r = 0; r < NDIM; ++r) Ws[r * H + j] = Wn[r * H + j];
#pragma unroll
  for (int t = 0; t < 4; ++t) {
    int f = j + t * 128;
    xs[f] = x[nbase * NDIM + f];
  }
  __syncthreads();
  float b = bn[j];
  for (int nn = 0; nn < 16; ++nn) {
    float acc = b;
#pragma unroll
    for (int k = 0; k < NDIM; ++k)
      acc = fmaf(xs[nn * NDIM + k], Ws[k * H + j], acc);
    hb[(size_t)(nbase + nn) * H + j] = (__bf16)acc;
  }
}

// ---------------- degree histogram over dst ----------------
__global__ __launch_bounds__(256) void degree_kernel(const int* __restrict__ ei,
                                                     int* __restrict__ deg) {
  int e = blockIdx.x * 256 + threadIdx.x;
  if (e < NE) atomicAdd(&deg[ei[NE + e]], 1);
}

// ---------------- parallel 3-phase exclusive scan of deg -> cursor ----------------
__global__ __launch_bounds__(256) void scan1_kernel(const int* __restrict__ deg,
                                                    int* __restrict__ bsum) {
  __shared__ int ws[4];
  int i = blockIdx.x * 256 + threadIdx.x;
  int lane = threadIdx.x & 63, wid = threadIdx.x >> 6;
  int v = (i < NN) ? deg[i] : 0;
#pragma unroll
  for (int off = 32; off; off >>= 1) v += __shfl_down(v, off);
  if (lane == 0) ws[wid] = v;
  __syncthreads();
  if (threadIdx.x == 0) bsum[blockIdx.x] = ws[0] + ws[1] + ws[2] + ws[3];
}

__global__ __launch_bounds__(256) void scan2_kernel(const int* __restrict__ bsum,
                                                    int* __restrict__ boff) {
  __shared__ int s[256];
  int t = threadIdx.x;
  int v = (t < NSB) ? bsum[t] : 0;
  s[t] = v;
  __syncthreads();
  for (int off = 1; off < 256; off <<= 1) {
    int u = (t >= off) ? s[t - off] : 0;
    __syncthreads();
    s[t] += u;
    __syncthreads();
  }
  if (t < NSB) boff[t] = s[t] - v;  // exclusive across blocks
}

__global__ __launch_bounds__(256) void scan3_kernel(const int* __restrict__ deg,
                                                    const int* __restrict__ boff,
                                                    int* __restrict__ cursor) {
  __shared__ int wsum[4], woff[4];
  int i = blockIdx.x * 256 + threadIdx.x;
  int lane = threadIdx.x & 63, wid = threadIdx.x >> 6;
  int orig = (i < NN) ? deg[i] : 0;
  int v = orig;
#pragma unroll
  for (int off = 1; off < 64; off <<= 1) {
    int u = __shfl_up(v, off);
    if (lane >= off) v += u;
  }
  if (lane == 63) wsum[wid] = v;
  __syncthreads();
  if (threadIdx.x == 0) {
    int r = 0;
#pragma unroll
    for (int w = 0; w < 4; ++w) {
      woff[w] = r;
      r += wsum[w];
    }
  }
  __syncthreads();
  if (i < NN) cursor[i] = (v - orig) + woff[wid] + boff[blockIdx.x];
}

// ---------------- counting-sort scatter: edges grouped by dst ----------------
__global__ __launch_bounds__(256) void scatter_kernel(
    const int* __restrict__ ei, int* __restrict__ cursor,
    int* __restrict__ srcSrt, int* __restrict__ dstSrt,
    int* __restrict__ eidSrt) {
  int e = blockIdx.x * 256 + threadIdx.x;
  if (e < NE) {
    int d = ei[NE + e];
    int pos = atomicAdd(&cursor[d], 1);
    dstSrt[pos] = d;
    srcSrt[pos] = ei[e];
    eidSrt[pos] = e;
  }
}

// ---------------- gather edge attrs into sorted order, fp32 -> bf16 (once) ----------------
__global__ __launch_bounds__(256) void gather_ea_kernel(
    const float* __restrict__ ea, const int* __restrict__ eidSrt,
    __bf16* __restrict__ eaSrt) {
  int fl = blockIdx.x * 256 + threadIdx.x;
  if (fl < NE) {
    int e = eidSrt[fl];
    const float4* ep = (const float4*)(ea + (size_t)e * EDIM);
    __bf16* op = eaSrt + (size_t)fl * EDIM;
#pragma unroll
    for (int q = 0; q < 4; ++q) {
      float4 v = ep[q];
      op[q * 4 + 0] = (__bf16)v.x;
      op[q * 4 + 1] = (__bf16)v.y;
      op[q * 4 + 2] = (__bf16)v.z;
      op[q * 4 + 3] = (__bf16)v.w;
    }
  }
}

// ---------------- zdzs weights: mW1[0:256] -> hi/lo bf16, frag-swizzled ----------------
__global__ __launch_bounds__(256) void precomp_zw_kernel(
    const float* __restrict__ mW1, __bf16* __restrict__ ZW) {
  int l = blockIdx.x / 8;
  int c = blockIdx.x % 8;
  int tid = threadIdx.x;
  const float* w1 = mW1 + (size_t)l * 384 * H;
  __bf16* dst = ZW + ((size_t)l * 8 + c) * ZW_CHUNK;
  for (int it = 0; it < 32; ++it) {
    int flat = it * 256 + tid;
    int j = flat & 7;
    int lane = (flat >> 3) & 63;
    int nt = (flat >> 9) & 7;
    int hilo = flat >> 12;
    int k = c * 16 + ((lane >> 5) << 3) + j;
    int n = nt * 32 + (lane & 31);
    float w = (n < 128) ? w1[(size_t)k * H + n]
                        : w1[(size_t)(128 + k) * H + (n - 128)];
    __bf16 hi = (__bf16)w;
    __bf16 lo = (__bf16)(w - (float)hi);
    dst[flat] = hilo ? lo : hi;
  }
}

// ---------------- Wef = We @ mW1[256:384] (16x128), bm = mb1 + be @ ... ----------------
__global__ __launch_bounds__(128) void precomp_wef_kernel(
    const float* __restrict__ mW1, const float* __restrict__ mb1,
    const float* __restrict__ We, const float* __restrict__ be,
    float* __restrict__ Wef, float* __restrict__ bm) {
  int l = blockIdx.x;
  int n = threadIdx.x;
  const float* w1 = mW1 + (size_t)l * 384 * H;
  float acc[EDIM];
#pragma unroll
  for (int i = 0; i < EDIM; ++i) acc[i] = 0.f;
  float accb = 0.f;
  for (int c = 0; c < H; ++c) {
    float wv = w1[(size_t)(256 + c) * H + n];
    accb = fmaf(be[c], wv, accb);
#pragma unroll
    for (int i = 0; i < EDIM; ++i)
      acc[i] = fmaf(We[i * H + c], wv, acc[i]);
  }
#pragma unroll
  for (int i = 0; i < EDIM; ++i)
    Wef[((size_t)l * EDIM + i) * H + n] = acc[i];
  bm[l * H + n] = mb1[l * H + n] + accb;
}

// ---------------- precompute folded update weights (fp32 Wu) ----------------
__global__ __launch_bounds__(128) void precomp_wu_kernel(
    const float* __restrict__ uW1, const float* __restrict__ mW2,
    const float* __restrict__ mb2, float* __restrict__ Wu,
    float* __restrict__ va) {
  int l = blockIdx.x / 257;
  int r = blockIdx.x % 257;
  int j = threadIdx.x;
  const float* u1 = uW1 + (size_t)l * 256 * H;
  if (r < 128) {
    Wu[((size_t)l * 256 + r) * H + j] = u1[(size_t)r * H + j];
  } else if (r < 256) {
    int i = r - 128;
    const float* m2 = mW2 + ((size_t)l * H + i) * H;
    float s = 0.f;
    for (int c = 0; c < H; ++c)
      s = fmaf(m2[c], u1[(size_t)(128 + c) * H + j], s);
    Wu[((size_t)l * 256 + r) * H + j] = s;
  } else {
    float s = 0.f;
    for (int c = 0; c < H; ++c)
      s = fmaf(mb2[l * H + c], u1[(size_t)(128 + c) * H + j], s);
    va[l * H + j] = s;
  }
}

// ---------------- swizzle node weights into hi/lo frag chunks ----------------
__global__ __launch_bounds__(256) void precomp_wns_kernel(
    const float* __restrict__ Wu, const float* __restrict__ uW2,
    __bf16* __restrict__ WnS) {
  int l = blockIdx.x / NODE_CHUNKS;
  int c = blockIdx.x % NODE_CHUNKS;
  int tid = threadIdx.x;
  int nt = tid >> 6, lane = tid & 63;
  int n = nt * 32 + (lane & 31);
  int half = lane >> 5;
  __bf16* dst = WnS + ((size_t)l * NODE_CHUNKS + c) * CHUNK_ELEMS;
#pragma unroll
  for (int j = 0; j < 8; ++j) {
    float w;
    if (c < 16) {
      int k = c * 16 + half * 8 + j;
      w = Wu[((size_t)l * 256 + k) * H + n];
    } else {
      int k = (c - 16) * 16 + half * 8 + j;
      w = uW2[((size_t)l * H + k) * H + n];
    }
    __bf16 hi = (__bf16)w;
    __bf16 lo = (__bf16)(w - (float)hi);
    dst[((0 * 4 + nt) * 64 + lane) * 8 + j] = hi;
    dst[((1 * 4 + nt) * 64 + lane) * 8 + j] = lo;
  }
}

// ---------------- z = h @ [W_d|W_s] (+bm on dst half) -> bf16; also zeroes aggrH ----------------
// h is bf16 -> A frags load directly (no split): 2 MFMA/tile (A*Bh + A*Bl).
__global__ __launch_bounds__(256) void zdzs_kernel(
    const __bf16* __restrict__ hb, const __bf16* __restrict__ ZW,
    const float* __restrict__ bm, __bf16* __restrict__ z,
    float* __restrict__ aggrH) {
  __shared__ __align__(16) __bf16 Bt[2][ZW_CHUNK];  // 32 KB
  int tid = threadIdx.x;
  int wid = tid >> 6, lane = tid & 63, m = lane & 31, half = lane >> 5;
  int nb = blockIdx.x * 128;
  int row = nb + wid * 32 + m;
  const __bf16* aH = hb + (size_t)row * H + half * 8;
  const short8* gW = (const short8*)ZW;  // 1024 short8 per chunk
  short8* sB0 = (short8*)&Bt[0][0];
  short8* sB1 = (short8*)&Bt[1][0];
#pragma unroll
  for (int q = 0; q < 4; ++q) sB0[tid + q * 256] = gW[tid + q * 256];
  short8 p0 = gW[1024 + tid], p1 = gW[1024 + tid + 256];
  short8 p2 = gW[1024 + tid + 512], p3 = gW[1024 + tid + 768];
  // zero this block's aggrH rows (replaces per-layer memset dispatch)
  {
    float4 zf4 = {0.f, 0.f, 0.f, 0.f};
    float4* ag = (float4*)(aggrH + (size_t)nb * H);
#pragma unroll
    for (int q = 0; q < 16; ++q) ag[q * 256 + tid] = zf4;
  }
  f32x16 acc[8];
#pragma unroll
  for (int nt = 0; nt < 8; ++nt)
#pragma unroll
    for (int r = 0; r < 16; ++r) acc[nt][r] = 0.f;
  bf16x8 a = *(const bf16x8*)aH;
  block_sync_lds();

  for (int s = 0; s < 8; ++s) {
    int buf = s & 1;
    bf16x8 na = a;
    if (s + 1 < 8) na = *(const bf16x8*)(aH + (s + 1) * 16);
    if (s + 1 < 8) {
      short8* sb = buf ? sB0 : sB1;
      sb[tid] = p0;
      sb[tid + 256] = p1;
      sb[tid + 512] = p2;
      sb[tid + 768] = p3;
      if (s + 2 < 8) {
        p0 = gW[(size_t)(s + 2) * 1024 + tid];
        p1 = gW[(size_t)(s + 2) * 1024 + tid + 256];
        p2 = gW[(size_t)(s + 2) * 1024 + tid + 512];
        p3 = gW[(size_t)(s + 2) * 1024 + tid + 768];
      }
    }
    const __bf16* bb = &Bt[buf][0];
#pragma unroll
    for (int nt = 0; nt < 8; ++nt) {
      bf16x8 bh = *(const bf16x8*)&bb[((0 * 8 + nt) * 64 + lane) * 8];
      bf16x8 bl = *(const bf16x8*)&bb[((1 * 8 + nt) * 64 + lane) * 8];
      acc[nt] = __builtin_amdgcn_mfma_f32_32x32x16_bf16(a, bh, acc[nt], 0, 0, 0);
      acc[nt] = __builtin_amdgcn_mfma_f32_32x32x16_bf16(a, bl, acc[nt], 0, 0, 0);
    }
    a = na;
    if (s + 1 < 8) block_sync_lds();
  }

  float bmv[4];
#pragma unroll
  for (int nt = 0; nt < 4; ++nt) bmv[nt] = bm[nt * 32 + m];
#pragma unroll
  for (int nt = 0; nt < 8; ++nt) {
    float bias = (nt < 4) ? bmv[nt] : 0.f;
#pragma unroll
    for (int r = 0; r < 16; ++r) {
      int rowi = (r & 3) + 8 * (r >> 2) + 4 * half;
      z[(size_t)(nb + wid * 32 + rowi) * 256 + nt * 32 + m] =
          (__bf16)(acc[nt][r] + bias);
    }
  }
}

// ---------------- sorted-edge aggregation: aggr[dst] += relu(z_d+z_s+ze) ----------------
__global__ __launch_bounds__(256) void edge_aggr_kernel(
    const __bf16* __restrict__ z, const int* __restrict__ srcSrt,
    const int* __restrict__ dstSrt, const __bf16* __restrict__ eaSrt,
    const float* __restrict__ Wef, float* __restrict__ aggrH) {
  __shared__ float eaS[EAB * EDIM];  // 4 KB fp32
  __shared__ int dstS[EAB], srcS[EAB];
  int tid = threadIdx.x;
  int e0b = blockIdx.x * EAB;
  {
    const unsigned* eap = (const unsigned*)(eaSrt + (size_t)e0b * EDIM);
    unsigned u0 = eap[tid * 2], u1 = eap[tid * 2 + 1];
    v2f f0 = bf2f(u0), f1 = bf2f(u1);
    float4 w4 = {f0.x, f0.y, f1.x, f1.y};
    *(float4*)&eaS[tid * 4] = w4;
  }
  if (tid < EAB) dstS[tid] = dstSrt[e0b + tid];
  else if (tid < 2 * EAB) srcS[tid - EAB] = srcSrt[e0b + tid - EAB];
  __syncthreads();
  int wid = tid >> 6, lane = tid & 63;
  int eb = wid * 16;
  int c0 = lane * 2;
  v2f w[EDIM];
#pragma unroll
  for (int k = 0; k < EDIM; ++k)
    w[k] = *(const v2f*)(Wef + (size_t)k * H + c0);
  unsigned zdu[16], zsu[16];
#pragma unroll
  for (int i = 0; i < 16; ++i) {
    zdu[i] = *(const unsigned*)(z + (size_t)dstS[eb + i] * 256 + c0);
    zsu[i] = *(const unsigned*)(z + (size_t)srcS[eb + i] * 256 + 128 + c0);
  }
  int cur = __builtin_amdgcn_readfirstlane(dstS[eb]);
  v2f acc = {0.f, 0.f};
#pragma unroll
  for (int i = 0; i < 16; ++i) {
    const float4* ep = (const float4*)&eaS[(eb + i) * EDIM];
    float4 g0 = ep[0], g1 = ep[1], g2 = ep[2], g3 = ep[3];
    v2f ze = g0.x * w[0];
    ze += g0.y * w[1];
    ze += g0.z * w[2];
    ze += g0.w * w[3];
    ze += g1.x * w[4];
    ze += g1.y * w[5];
    ze += g1.z * w[6];
    ze += g1.w * w[7];
    ze += g2.x * w[8];
    ze += g2.y * w[9];
    ze += g2.z * w[10];
    ze += g2.w * w[11];
    ze += g3.x * w[12];
    ze += g3.y * w[13];
    ze += g3.z * w[14];
    ze += g3.w * w[15];
    int d = __builtin_amdgcn_readfirstlane(dstS[eb + i]);
    if (d != cur) {
      float* ap = aggrH + (size_t)cur * H + c0;
      unsafeAtomicAdd(ap, acc.x);
      unsafeAtomicAdd(ap + 1, acc.y);
      acc.x = 0.f;
      acc.y = 0.f;
      cur = d;
    }
    v2f t = bf2f(zdu[i]) + bf2f(zsu[i]) + ze;
    acc.x += fmaxf(t.x, 0.f);
    acc.y += fmaxf(t.y, 0.f);
  }
  float* ap = aggrH + (size_t)cur * H + c0;
  unsafeAtomicAdd(ap, acc.x);
  unsafeAtomicAdd(ap + 1, acc.y);
}

// ---------------- MFMA fused node update (h bf16) ----------------
__global__ __launch_bounds__(256) void node_update_mfma_kernel(
    __bf16* __restrict__ hb, const float* __restrict__ aggrH,
    const int* __restrict__ deg, const __bf16* __restrict__ WnS,
    const float* __restrict__ ub1, const float* __restrict__ va,
    const float* __restrict__ ub2) {
  __shared__ __align__(16) __bf16 Bt[2][CHUNK_ELEMS];
  __shared__ __bf16 hid[4][32][132];
  __shared__ float degS[128];
  int tid = threadIdx.x;
  int nb = blockIdx.x * 128;
  if (tid < 128) degS[tid] = (float)deg[nb + tid];
  int wid = tid >> 6, lane = tid & 63, m = lane & 31, half = lane >> 5;
  int row = nb + wid * 32 + m;
  const __bf16* aHb = hb + (size_t)row * H + half * 8;
  const float* aG = aggrH + (size_t)row * H + half * 8;
  const short8* gW = (const short8*)WnS;
  short8* sB0 = (short8*)&Bt[0][0];
  short8* sB1 = (short8*)&Bt[1][0];
  sB0[tid] = gW[tid];
  sB0[tid + 256] = gW[tid + 256];
  short8 p0 = gW[512 + tid], p1 = gW[512 + tid + 256];
  float bv1[4], bva[4];
#pragma unroll
  for (int nt = 0; nt < 4; ++nt) {
    bv1[nt] = ub1[nt * 32 + m];
    bva[nt] = va[nt * 32 + m];
  }
  f32x16 acc[4];
#pragma unroll
  for (int nt = 0; nt < 4; ++nt)
#pragma unroll
    for (int r = 0; r < 16; ++r) acc[nt][r] = 0.f;
  bf16x8 acur = *(const bf16x8*)aHb;
  block_sync_lds();

  for (int s = 0; s < 16; ++s) {
    int buf = s & 1;
    bf16x8 anext = acur;
    if (s + 1 < 16) {
      int sp = s + 1;
      if (sp < 8) {
        anext = *(const bf16x8*)(aHb + sp * 16);
      } else {
        const float* pp = aG + (sp - 8) * 16;
        float4 f0 = *(const float4*)pp;
        float4 f1 = *(const float4*)(pp + 4);
        float af[8] = {f0.x, f0.y, f0.z, f0.w, f1.x, f1.y, f1.z, f1.w};
#pragma unroll
        for (int j = 0; j < 8; ++j) anext[j] = (__bf16)af[j];
      }
    }
    {
      short8* sb = buf ? sB0 : sB1;
      sb[tid] = p0;
      sb[tid + 256] = p1;
      if (s + 2 < NODE_CHUNKS) {
        p0 = gW[(size_t)(s + 2) * 512 + tid];
        p1 = gW[(size_t)(s + 2) * 512 + tid + 256];
      }
    }
    const __bf16* bb = &Bt[buf][0];
#pragma unroll
    for (int nt = 0; nt < 4; ++nt) {
      bf16x8 bh = *(const bf16x8*)&bb[((0 * 4 + nt) * 64 + lane) * 8];
      bf16x8 bl = *(const bf16x8*)&bb[((1 * 4 + nt) * 64 + lane) * 8];
      acc[nt] = __builtin_amdgcn_mfma_f32_32x32x16_bf16(acur, bh, acc[nt], 0, 0, 0);
      acc[nt] = __builtin_amdgcn_mfma_f32_32x32x16_bf16(acur, bl, acc[nt], 0, 0, 0);
    }
    acur = anext;
    block_sync_lds();
  }

#pragma unroll
  for (int nt = 0; nt < 4; ++nt) {
#pragma unroll
    for (int r = 0; r < 16; ++r) {
      int rowi = (r & 3) + 8 * (r >> 2) + 4 * half;
      float v = acc[nt][r] + bv1[nt] + degS[wid * 32 + rowi] * bva[nt];
      hid[wid][rowi][nt * 32 + m] = (__bf16)fmaxf(v, 0.f);
      acc[nt][r] = 0.f;
    }
  }
  wait_lds();

  for (int s = 16; s < NODE_CHUNKS; ++s) {
    int buf = s & 1;
    if (s + 1 < NODE_CHUNKS) {
      short8* sb = buf ? sB0 : sB1;
      sb[tid] = p0;
      sb[tid + 256] = p1;
      if (s + 2 < NODE_CHUNKS) {
        p0 = gW[(size_t)(s + 2) * 512 + tid];
        p1 = gW[(size_t)(s + 2) * 512 + tid + 256];
      }
    }
    bf16x8 ah = *(const bf16x8*)&hid[wid][m][(s - 16) * 16 + half * 8];
    const __bf16* bb = &Bt[buf][0];
#pragma unroll
    for (int nt = 0; nt < 4; ++nt) {
      bf16x8 bh = *(const bf16x8*)&bb[((0 * 4 + nt) * 64 + lane) * 8];
      bf16x8 bl = *(const bf16x8*)&bb[((1 * 4 + nt) * 64 + lane) * 8];
      acc[nt] = __builtin_amdgcn_mfma_f32_32x32x16_bf16(ah, bh, acc[nt], 0, 0, 0);
      acc[nt] = __builtin_amdgcn_mfma_f32_32x32x16_bf16(ah, bl, acc[nt], 0, 0, 0);
    }
    if (s + 1 < NODE_CHUNKS) block_sync_lds();
  }

#pragma unroll
  for (int nt = 0; nt < 4; ++nt) {
    float b2 = ub2[nt * 32 + m];
#pragma unroll
    for (int r = 0; r < 16; ++r) {
      int rowi = (r & 3) + 8 * (r >> 2) + 4 * half;
      size_t idx = (size_t)(nb + wid * 32 + rowi) * H + nt * 32 + m;
      float hv = (float)hb[idx];
      hb[idx] = (__bf16)(hv + acc[nt][r] + b2);
    }
  }
}

// ---------------- batch mean pooling (batch is sorted) ----------------
__global__ __launch_bounds__(128) void pool_kernel(
    const __bf16* __restrict__ hb, const int* __restrict__ batch,
    float* __restrict__ pooled, int* __restrict__ counts) {
  int j = threadIdx.x;
  int nbase = blockIdx.x * 128;
  int nend = nbase + 128;
  if (nend > NN) nend = NN;
  if (nbase >= NN) return;
  int cur = batch[nbase];
  float sum = 0.f;
  int cnt = 0;
  for (int n = nbase; n < nend; ++n) {
    int b = batch[n];
    if (b != cur) {
      unsafeAtomicAdd(&pooled[cur * H + j], sum);
      if (j == 0) atomicAdd(&counts[cur], cnt);
      sum = 0.f; cnt = 0; cur = b;
    }
    sum += (float)hb[(size_t)n * H + j];
    cnt++;
  }
  unsafeAtomicAdd(&pooled[cur * H + j], sum);
  if (j == 0) atomicAdd(&counts[cur], cnt);
}

// ---------------- readout MLP ----------------
__global__ __launch_bounds__(128) void readout_kernel(
    const float* __restrict__ pooled, const int* __restrict__ counts,
    const float* __restrict__ gf, const float* __restrict__ Wg,
    const float* __restrict__ bg, const float* __restrict__ rW1,
    const float* __restrict__ rb1, const float* __restrict__ rW2,
    const float* __restrict__ rb2, const float* __restrict__ rW3,
    const float* __restrict__ rb3, float* __restrict__ out) {
  __shared__ float fin[256];
  __shared__ float t1[128];
  __shared__ float t2[64];
  int j = threadIdx.x;
  for (int b = 0; b < NBATCH; ++b) {
    float cnt = (float)counts[b];
    if (cnt < 1.f) cnt = 1.f;
    fin[j] = pooled[b * H + j] / cnt;
    fin[H + j] = fmaf(gf[b], Wg[j], bg[j]);
    __syncthreads();
    float a = rb1[j];
    for (int k = 0; k < 256; ++k) a = fmaf(fin[k], rW1[k * H + j], a);
    t1[j] = fmaxf(a, 0.f);
    __syncthreads();
    if (j < 64) {
      float a2 = rb2[j];
      for (int k = 0; k < 128; ++k) a2 = fmaf(t1[k], rW2[k * 64 + j], a2);
      t2[j] = fmaxf(a2, 0.f);
    }
    __syncthreads();
    if (j < 64) {
      float p = t2[j] * rW3[j];
#pragma unroll
      for (int off = 32; off; off >>= 1) p += __shfl_down(p, off);
      if (j == 0) out[b] = p + rb3[0];
    }
    __syncthreads();
  }
}

extern "C" void kernel_launch(void* const* d_in, const int* in_sizes, int n_in,
                              void* d_out, int out_size, void* d_ws, size_t ws_size,
                              hipStream_t stream) {
  const float* x   = (const float*)d_in[0];
  const float* ea  = (const float*)d_in[1];
  const float* gf  = (const float*)d_in[2];
  const int*   ei  = (const int*)d_in[3];
  const int*   bat = (const int*)d_in[4];
  const float* Wn  = (const float*)d_in[5];
  const float* bn  = (const float*)d_in[6];
  const float* We  = (const float*)d_in[7];
  const float* be  = (const float*)d_in[8];
  const float* Wg  = (const float*)d_in[9];
  const float* bg  = (const float*)d_in[10];
  const float* mW1 = (const float*)d_in[11];
  const float* mb1 = (const float*)d_in[12];
  const float* mW2 = (const float*)d_in[13];
  const float* mb2 = (const float*)d_in[14];
  const float* uW1 = (const float*)d_in[15];
  const float* ub1 = (const float*)d_in[16];
  const float* uW2 = (const float*)d_in[17];
  const float* ub2 = (const float*)d_in[18];
  const float* rW1 = (const float*)d_in[19];
  const float* rb1 = (const float*)d_in[20];
  const float* rW2 = (const float*)d_in[21];
  const float* rb2 = (const float*)d_in[22];
  const float* rW3 = (const float*)d_in[23];
  const float* rb3 = (const float*)d_in[24];

  char* p = (char*)d_ws;
  __bf16* hb     = (__bf16*)p; p += (size_t)NPAD * H * 2;        // 12.8 MB
  float*  aggrH  = (float*)p;  p += (size_t)NPAD * H * 4;        // 25.6 MB
  __bf16* z      = (__bf16*)p; p += (size_t)NPAD * 256 * 2;      // 25.6 MB
  __bf16* eaSrt  = (__bf16*)p; p += (size_t)NE * EDIM * 2;       // 12.8 MB
  int*    srcSrt = (int*)p;    p += (size_t)NE * 4;
  int*    dstSrt = (int*)p;    p += (size_t)NE * 4;
  int*    eidSrt = (int*)p;    p += (size_t)NE * 4;
  __bf16* ZW     = (__bf16*)p; p += (size_t)NLAYERS * 8 * ZW_CHUNK * 2;
  __bf16* WnS    = (__bf16*)p; p += (size_t)NLAYERS * NODE_CHUNKS * CHUNK_ELEMS * 2;
  float*  Wef    = (float*)p;  p += (size_t)NLAYERS * EDIM * H * 4;
  float*  bm     = (float*)p;  p += (size_t)NLAYERS * H * 4;
  float*  Wu     = (float*)p;  p += (size_t)NLAYERS * 256 * H * 4;
  float*  va     = (float*)p;  p += (size_t)NLAYERS * H * 4;
  int*    deg    = (int*)p;    p += (size_t)NPAD * 4;
  int*    cursor = (int*)p;    p += (size_t)NPAD * 4;
  int*    bsum   = (int*)p;    p += 256 * 4;
  int*    boff   = (int*)p;    p += 256 * 4;
  float*  pooled = (float*)p;  p += (size_t)NBATCH * H * 4;
  int*    counts = (int*)p;    p += 64;

  hipMemsetAsync(deg, 0, (size_t)NPAD * 4, stream);
  hipMemsetAsync(pooled, 0, (size_t)NBATCH * H * 4, stream);
  hipMemsetAsync(counts, 0, 64, stream);

  embed_nodes_kernel<<<NN / 16, 128, 0, stream>>>(x, Wn, bn, hb);
  degree_kernel<<<(NE + 255) / 256, 256, 0, stream>>>(ei, deg);
  scan1_kernel<<<NSB, 256, 0, stream>>>(deg, bsum);
  scan2_kernel<<<1, 256, 0, stream>>>(bsum, boff);
  scan3_kernel<<<NSB, 256, 0, stream>>>(deg, boff, cursor);
  scatter_kernel<<<(NE + 255) / 256, 256, 0, stream>>>(ei, cursor, srcSrt,
                                                       dstSrt, eidSrt);
  gather_ea_kernel<<<(NE + 255) / 256, 256, 0, stream>>>(ea, eidSrt, eaSrt);
  precomp_zw_kernel<<<NLAYERS * 8, 256, 0, stream>>>(mW1, ZW);
  precomp_wef_kernel<<<NLAYERS, 128, 0, stream>>>(mW1, mb1, We, be, Wef, bm);
  precomp_wu_kernel<<<NLAYERS * 257, 128, 0, stream>>>(uW1, mW2, mb2, Wu, va);
  precomp_wns_kernel<<<NLAYERS * NODE_CHUNKS, 256, 0, stream>>>(Wu, uW2, WnS);

  for (int l = 0; l < NLAYERS; ++l) {
    zdzs_kernel<<<NBLK, 256, 0, stream>>>(
        hb, ZW + (size_t)l * 8 * ZW_CHUNK, bm + (size_t)l * H, z, aggrH);
    edge_aggr_kernel<<<NE / EAB, 256, 0, stream>>>(
        z, srcSrt, dstSrt, eaSrt, Wef + (size_t)l * EDIM * H, aggrH);
    node_update_mfma_kernel<<<NBLK, 256, 0, stream>>>(
        hb, aggrH, deg, WnS + (size_t)l * NODE_CHUNKS * CHUNK_ELEMS,
        ub1 + (size_t)l * H, va + (size_t)l * H, ub2 + (size_t)l * H);
  }

  pool_kernel<<<(NN + 127) / 128, 128, 0, stream>>>(hb, bat, pooled, counts);
  readout_kernel<<<1, 128, 0, stream>>>(pooled, counts, gf, Wg, bg, rW1, rb1,
                                        rW2, rb2, rW3, rb3, (float*)d_out);
}

// Round 14
// 615.681 us; speedup vs baseline: 1.5997x; 1.0302x over previous
//
#include <hip/hip_runtime.h>

#define NN 50000
#define NPAD 50048     // 391 * 128
#define NBLK 391
#define NE 400000
#define NBATCH 8
#define NDIM 32
#define EDIM 16
#define H 128
#define NLAYERS 3
#define CHUNK_ELEMS 4096   // node-kernel weight chunk: 2 hilo * 4 nt * 64 lane * 8
#define NODE_CHUNKS 24     // 16 (Wu, K=256) + 8 (uW2, K=128)
#define ZW_CHUNK 8192      // zdzs chunk: 2 hilo * 8 nt * 64 lane * 8
#define NSB 196            // scan blocks: ceil(50000/256)

typedef __attribute__((ext_vector_type(8))) __bf16 bf16x8;
typedef __attribute__((ext_vector_type(16))) float f32x16;
typedef __attribute__((ext_vector_type(8))) short short8;
typedef __attribute__((ext_vector_type(2))) float v2f;

__device__ __forceinline__ void block_sync_lds() {
  asm volatile("s_waitcnt lgkmcnt(0)\ns_barrier" ::: "memory");
}
__device__ __forceinline__ void wait_lds() {
  asm volatile("s_waitcnt lgkmcnt(0)" ::: "memory");
}
// one dword = 2 packed bf16 -> 2 fp32 (pure bit ops)
__device__ __forceinline__ v2f bf2f(unsigned u) {
  v2f r;
  r.x = __uint_as_float(u << 16);
  r.y = __uint_as_float(u & 0xffff0000u);
  return r;
}

// ---------------- node embedding: h = x @ Wn + bn (bf16 out) ----------------
__global__ __launch_bounds__(128) void embed_nodes_kernel(
    const float* __restrict__ x, const float* __restrict__ Wn,
    const float* __restrict__ bn, __bf16* __restrict__ hb) {
  __shared__ float Ws[NDIM * H];
  __shared__ float xs[16 * NDIM];
  int j = threadIdx.x;
  int nbase = blockIdx.x * 16;
  for (int r = 0; r < NDIM; ++r) Ws[r * H + j] = Wn[r * H + j];
#pragma unroll
  for (int t = 0; t < 4; ++t) {
    int f = j + t * 128;
    xs[f] = x[nbase * NDIM + f];
  }
  __syncthreads();
  float b = bn[j];
  for (int nn = 0; nn < 16; ++nn) {
    float acc = b;
#pragma unroll
    for (int k = 0; k < NDIM; ++k)
      acc = fmaf(xs[nn * NDIM + k], Ws[k * H + j], acc);
    hb[(size_t)(nbase + nn) * H + j] = (__bf16)acc;
  }
}

// ---------------- degree histogram over dst ----------------
__global__ __launch_bounds__(256) void degree_kernel(const int* __restrict__ ei,
                                                     int* __restrict__ deg) {
  int e = blockIdx.x * 256 + threadIdx.x;
  if (e < NE) atomicAdd(&deg[ei[NE + e]], 1);
}

// ---------------- parallel 3-phase exclusive scan of deg -> cursor ----------------
__global__ __launch_bounds__(256) void scan1_kernel(const int* __restrict__ deg,
                                                    int* __restrict__ bsum) {
  __shared__ int ws[4];
  int i = blockIdx.x * 256 + threadIdx.x;
  int lane = threadIdx.x & 63, wid = threadIdx.x >> 6;
  int v = (i < NN) ? deg[i] : 0;
#pragma unroll
  for (int off = 32; off; off >>= 1) v += __shfl_down(v, off);
  if (lane == 0) ws[wid] = v;
  __syncthreads();
  if (threadIdx.x == 0) bsum[blockIdx.x] = ws[0] + ws[1] + ws[2] + ws[3];
}

__global__ __launch_bounds__(256) void scan2_kernel(const int* __restrict__ bsum,
                                                    int* __restrict__ boff) {
  __shared__ int s[256];
  int t = threadIdx.x;
  int v = (t < NSB) ? bsum[t] : 0;
  s[t] = v;
  __syncthreads();
  for (int off = 1; off < 256; off <<= 1) {
    int u = (t >= off) ? s[t - off] : 0;
    __syncthreads();
    s[t] += u;
    __syncthreads();
  }
  if (t < NSB) boff[t] = s[t] - v;  // exclusive across blocks
}

__global__ __launch_bounds__(256) void scan3_kernel(const int* __restrict__ deg,
                                                    const int* __restrict__ boff,
                                                    int* __restrict__ cursor) {
  __shared__ int wsum[4], woff[4];
  int i = blockIdx.x * 256 + threadIdx.x;
  int lane = threadIdx.x & 63, wid = threadIdx.x >> 6;
  int orig = (i < NN) ? deg[i] : 0;
  int v = orig;
#pragma unroll
  for (int off = 1; off < 64; off <<= 1) {
    int u = __shfl_up(v, off);
    if (lane >= off) v += u;
  }
  if (lane == 63) wsum[wid] = v;
  __syncthreads();
  if (threadIdx.x == 0) {
    int r = 0;
#pragma unroll
    for (int w = 0; w < 4; ++w) {
      woff[w] = r;
      r += wsum[w];
    }
  }
  __syncthreads();
  if (i < NN) cursor[i] = (v - orig) + woff[wid] + boff[blockIdx.x];
}

// ---------------- counting-sort scatter: edges grouped by dst ----------------
// after this kernel, cursor[n] == END offset of node n's segment (CSR rowptr).
__global__ __launch_bounds__(256) void scatter_kernel(
    const int* __restrict__ ei, int* __restrict__ cursor,
    int* __restrict__ srcSrt, int* __restrict__ dstSrt,
    int* __restrict__ eidSrt) {
  int e = blockIdx.x * 256 + threadIdx.x;
  if (e < NE) {
    int d = ei[NE + e];
    int pos = atomicAdd(&cursor[d], 1);
    dstSrt[pos] = d;
    srcSrt[pos] = ei[e];
    eidSrt[pos] = e;
  }
}

// ---------------- gather edge attrs into sorted order, fp32 -> bf16 (once) ----------------
__global__ __launch_bounds__(256) void gather_ea_kernel(
    const float* __restrict__ ea, const int* __restrict__ eidSrt,
    __bf16* __restrict__ eaSrt) {
  int fl = blockIdx.x * 256 + threadIdx.x;
  if (fl < NE) {
    int e = eidSrt[fl];
    const float4* ep = (const float4*)(ea + (size_t)e * EDIM);
    __bf16* op = eaSrt + (size_t)fl * EDIM;
#pragma unroll
    for (int q = 0; q < 4; ++q) {
      float4 v = ep[q];
      op[q * 4 + 0] = (__bf16)v.x;
      op[q * 4 + 1] = (__bf16)v.y;
      op[q * 4 + 2] = (__bf16)v.z;
      op[q * 4 + 3] = (__bf16)v.w;
    }
  }
}

// ---------------- zdzs weights: mW1[0:256] -> hi/lo bf16, frag-swizzled ----------------
__global__ __launch_bounds__(256) void precomp_zw_kernel(
    const float* __restrict__ mW1, __bf16* __restrict__ ZW) {
  int l = blockIdx.x / 8;
  int c = blockIdx.x % 8;
  int tid = threadIdx.x;
  const float* w1 = mW1 + (size_t)l * 384 * H;
  __bf16* dst = ZW + ((size_t)l * 8 + c) * ZW_CHUNK;
  for (int it = 0; it < 32; ++it) {
    int flat = it * 256 + tid;
    int j = flat & 7;
    int lane = (flat >> 3) & 63;
    int nt = (flat >> 9) & 7;
    int hilo = flat >> 12;
    int k = c * 16 + ((lane >> 5) << 3) + j;
    int n = nt * 32 + (lane & 31);
    float w = (n < 128) ? w1[(size_t)k * H + n]
                        : w1[(size_t)(128 + k) * H + (n - 128)];
    __bf16 hi = (__bf16)w;
    __bf16 lo = (__bf16)(w - (float)hi);
    dst[flat] = hilo ? lo : hi;
  }
}

// ---------------- Wef = We @ mW1[256:384] (16x128), bm = mb1 + be @ ... ----------------
__global__ __launch_bounds__(128) void precomp_wef_kernel(
    const float* __restrict__ mW1, const float* __restrict__ mb1,
    const float* __restrict__ We, const float* __restrict__ be,
    float* __restrict__ Wef, float* __restrict__ bm) {
  int l = blockIdx.x;
  int n = threadIdx.x;
  const float* w1 = mW1 + (size_t)l * 384 * H;
  float acc[EDIM];
#pragma unroll
  for (int i = 0; i < EDIM; ++i) acc[i] = 0.f;
  float accb = 0.f;
  for (int c = 0; c < H; ++c) {
    float wv = w1[(size_t)(256 + c) * H + n];
    accb = fmaf(be[c], wv, accb);
#pragma unroll
    for (int i = 0; i < EDIM; ++i)
      acc[i] = fmaf(We[i * H + c], wv, acc[i]);
  }
#pragma unroll
  for (int i = 0; i < EDIM; ++i)
    Wef[((size_t)l * EDIM + i) * H + n] = acc[i];
  bm[l * H + n] = mb1[l * H + n] + accb;
}

// ---------------- precompute folded update weights (fp32 Wu) ----------------
__global__ __launch_bounds__(128) void precomp_wu_kernel(
    const float* __restrict__ uW1, const float* __restrict__ mW2,
    const float* __restrict__ mb2, float* __restrict__ Wu,
    float* __restrict__ va) {
  int l = blockIdx.x / 257;
  int r = blockIdx.x % 257;
  int j = threadIdx.x;
  const float* u1 = uW1 + (size_t)l * 256 * H;
  if (r < 128) {
    Wu[((size_t)l * 256 + r) * H + j] = u1[(size_t)r * H + j];
  } else if (r < 256) {
    int i = r - 128;
    const float* m2 = mW2 + ((size_t)l * H + i) * H;
    float s = 0.f;
    for (int c = 0; c < H; ++c)
      s = fmaf(m2[c], u1[(size_t)(128 + c) * H + j], s);
    Wu[((size_t)l * 256 + r) * H + j] = s;
  } else {
    float s = 0.f;
    for (int c = 0; c < H; ++c)
      s = fmaf(mb2[l * H + c], u1[(size_t)(128 + c) * H + j], s);
    va[l * H + j] = s;
  }
}

// ---------------- swizzle node weights into hi/lo frag chunks ----------------
__global__ __launch_bounds__(256) void precomp_wns_kernel(
    const float* __restrict__ Wu, const float* __restrict__ uW2,
    __bf16* __restrict__ WnS) {
  int l = blockIdx.x / NODE_CHUNKS;
  int c = blockIdx.x % NODE_CHUNKS;
  int tid = threadIdx.x;
  int nt = tid >> 6, lane = tid & 63;
  int n = nt * 32 + (lane & 31);
  int half = lane >> 5;
  __bf16* dst = WnS + ((size_t)l * NODE_CHUNKS + c) * CHUNK_ELEMS;
#pragma unroll
  for (int j = 0; j < 8; ++j) {
    float w;
    if (c < 16) {
      int k = c * 16 + half * 8 + j;
      w = Wu[((size_t)l * 256 + k) * H + n];
    } else {
      int k = (c - 16) * 16 + half * 8 + j;
      w = uW2[((size_t)l * H + k) * H + n];
    }
    __bf16 hi = (__bf16)w;
    __bf16 lo = (__bf16)(w - (float)hi);
    dst[((0 * 4 + nt) * 64 + lane) * 8 + j] = hi;
    dst[((1 * 4 + nt) * 64 + lane) * 8 + j] = lo;
  }
}

// ---------------- z = h @ [W_d|W_s] (+bm on dst half) -> bf16 ----------------
// h is bf16 -> A frags load directly (no split): 2 MFMA/tile (A*Bh + A*Bl).
__global__ __launch_bounds__(256) void zdzs_kernel(
    const __bf16* __restrict__ hb, const __bf16* __restrict__ ZW,
    const float* __restrict__ bm, __bf16* __restrict__ z) {
  __shared__ __align__(16) __bf16 Bt[2][ZW_CHUNK];  // 32 KB
  int tid = threadIdx.x;
  int wid = tid >> 6, lane = tid & 63, m = lane & 31, half = lane >> 5;
  int nb = blockIdx.x * 128;
  int row = nb + wid * 32 + m;
  const __bf16* aH = hb + (size_t)row * H + half * 8;
  const short8* gW = (const short8*)ZW;  // 1024 short8 per chunk
  short8* sB0 = (short8*)&Bt[0][0];
  short8* sB1 = (short8*)&Bt[1][0];
#pragma unroll
  for (int q = 0; q < 4; ++q) sB0[tid + q * 256] = gW[tid + q * 256];
  short8 p0 = gW[1024 + tid], p1 = gW[1024 + tid + 256];
  short8 p2 = gW[1024 + tid + 512], p3 = gW[1024 + tid + 768];
  f32x16 acc[8];
#pragma unroll
  for (int nt = 0; nt < 8; ++nt)
#pragma unroll
    for (int r = 0; r < 16; ++r) acc[nt][r] = 0.f;
  bf16x8 a = *(const bf16x8*)aH;
  block_sync_lds();

  for (int s = 0; s < 8; ++s) {
    int buf = s & 1;
    bf16x8 na = a;
    if (s + 1 < 8) na = *(const bf16x8*)(aH + (s + 1) * 16);
    if (s + 1 < 8) {
      short8* sb = buf ? sB0 : sB1;
      sb[tid] = p0;
      sb[tid + 256] = p1;
      sb[tid + 512] = p2;
      sb[tid + 768] = p3;
      if (s + 2 < 8) {
        p0 = gW[(size_t)(s + 2) * 1024 + tid];
        p1 = gW[(size_t)(s + 2) * 1024 + tid + 256];
        p2 = gW[(size_t)(s + 2) * 1024 + tid + 512];
        p3 = gW[(size_t)(s + 2) * 1024 + tid + 768];
      }
    }
    const __bf16* bb = &Bt[buf][0];
#pragma unroll
    for (int nt = 0; nt < 8; ++nt) {
      bf16x8 bh = *(const bf16x8*)&bb[((0 * 8 + nt) * 64 + lane) * 8];
      bf16x8 bl = *(const bf16x8*)&bb[((1 * 8 + nt) * 64 + lane) * 8];
      acc[nt] = __builtin_amdgcn_mfma_f32_32x32x16_bf16(a, bh, acc[nt], 0, 0, 0);
      acc[nt] = __builtin_amdgcn_mfma_f32_32x32x16_bf16(a, bl, acc[nt], 0, 0, 0);
    }
    a = na;
    if (s + 1 < 8) block_sync_lds();
  }

  float bmv[4];
#pragma unroll
  for (int nt = 0; nt < 4; ++nt) bmv[nt] = bm[nt * 32 + m];
#pragma unroll
  for (int nt = 0; nt < 8; ++nt) {
    float bias = (nt < 4) ? bmv[nt] : 0.f;
#pragma unroll
    for (int r = 0; r < 16; ++r) {
      int rowi = (r & 3) + 8 * (r >> 2) + 4 * half;
      z[(size_t)(nb + wid * 32 + rowi) * 256 + nt * 32 + m] =
          (__bf16)(acc[nt][r] + bias);
    }
  }
}

// ---------------- node-parallel CSR aggregation: aggr[n] = sum relu(zd+zs+ze) ----------------
// one wave per node; cursor[n] = segment end (start = cursor[n-1]); z_d loaded
// once per node; src/ea loads wave-uniform (broadcast); plain coalesced store.
__global__ __launch_bounds__(256) void edge_aggr_kernel(
    const __bf16* __restrict__ z, const int* __restrict__ srcSrt,
    const int* __restrict__ cend, const __bf16* __restrict__ eaSrt,
    const float* __restrict__ Wef, float* __restrict__ aggrH) {
  int node = blockIdx.x * 4 + (threadIdx.x >> 6);
  int lane = threadIdx.x & 63;
  int c0 = lane * 2;
  v2f w[EDIM];
#pragma unroll
  for (int k = 0; k < EDIM; ++k)
    w[k] = *(const v2f*)(Wef + (size_t)k * H + c0);
  int end = cend[node];
  int start = node ? cend[node - 1] : 0;
  v2f acc = {0.f, 0.f};
  if (start < end) {
    v2f zd = bf2f(*(const unsigned*)(z + (size_t)node * 256 + c0));
    int sN = srcSrt[start];
    for (int e = start; e < end; ++e) {
      int s = sN;
      unsigned zsu = *(const unsigned*)(z + (size_t)s * 256 + 128 + c0);
      const uint4* eap = (const uint4*)(eaSrt + (size_t)e * EDIM);
      uint4 u0 = eap[0], u1 = eap[1];
      if (e + 1 < end) sN = srcSrt[e + 1];
      v2f p, ze;
      p = bf2f(u0.x); ze = p.x * w[0];   ze += p.y * w[1];
      p = bf2f(u0.y); ze += p.x * w[2];  ze += p.y * w[3];
      p = bf2f(u0.z); ze += p.x * w[4];  ze += p.y * w[5];
      p = bf2f(u0.w); ze += p.x * w[6];  ze += p.y * w[7];
      p = bf2f(u1.x); ze += p.x * w[8];  ze += p.y * w[9];
      p = bf2f(u1.y); ze += p.x * w[10]; ze += p.y * w[11];
      p = bf2f(u1.z); ze += p.x * w[12]; ze += p.y * w[13];
      p = bf2f(u1.w); ze += p.x * w[14]; ze += p.y * w[15];
      v2f t = zd + bf2f(zsu) + ze;
      acc.x += fmaxf(t.x, 0.f);
      acc.y += fmaxf(t.y, 0.f);
    }
  }
  *(v2f*)(aggrH + (size_t)node * H + c0) = acc;
}

// ---------------- MFMA fused node update (h bf16) ----------------
__global__ __launch_bounds__(256) void node_update_mfma_kernel(
    __bf16* __restrict__ hb, const float* __restrict__ aggrH,
    const int* __restrict__ deg, const __bf16* __restrict__ WnS,
    const float* __restrict__ ub1, const float* __restrict__ va,
    const float* __restrict__ ub2) {
  __shared__ __align__(16) __bf16 Bt[2][CHUNK_ELEMS];
  __shared__ __bf16 hid[4][32][132];
  __shared__ float degS[128];
  int tid = threadIdx.x;
  int nb = blockIdx.x * 128;
  if (tid < 128) degS[tid] = (float)deg[nb + tid];
  int wid = tid >> 6, lane = tid & 63, m = lane & 31, half = lane >> 5;
  int row = nb + wid * 32 + m;
  const __bf16* aHb = hb + (size_t)row * H + half * 8;
  const float* aG = aggrH + (size_t)row * H + half * 8;
  const short8* gW = (const short8*)WnS;
  short8* sB0 = (short8*)&Bt[0][0];
  short8* sB1 = (short8*)&Bt[1][0];
  sB0[tid] = gW[tid];
  sB0[tid + 256] = gW[tid + 256];
  short8 p0 = gW[512 + tid], p1 = gW[512 + tid + 256];
  float bv1[4], bva[4];
#pragma unroll
  for (int nt = 0; nt < 4; ++nt) {
    bv1[nt] = ub1[nt * 32 + m];
    bva[nt] = va[nt * 32 + m];
  }
  f32x16 acc[4];
#pragma unroll
  for (int nt = 0; nt < 4; ++nt)
#pragma unroll
    for (int r = 0; r < 16; ++r) acc[nt][r] = 0.f;
  bf16x8 acur = *(const bf16x8*)aHb;
  block_sync_lds();

  for (int s = 0; s < 16; ++s) {
    int buf = s & 1;
    bf16x8 anext = acur;
    if (s + 1 < 16) {
      int sp = s + 1;
      if (sp < 8) {
        anext = *(const bf16x8*)(aHb + sp * 16);
      } else {
        const float* pp = aG + (sp - 8) * 16;
        float4 f0 = *(const float4*)pp;
        float4 f1 = *(const float4*)(pp + 4);
        float af[8] = {f0.x, f0.y, f0.z, f0.w, f1.x, f1.y, f1.z, f1.w};
#pragma unroll
        for (int j = 0; j < 8; ++j) anext[j] = (__bf16)af[j];
      }
    }
    {
      short8* sb = buf ? sB0 : sB1;
      sb[tid] = p0;
      sb[tid + 256] = p1;
      if (s + 2 < NODE_CHUNKS) {
        p0 = gW[(size_t)(s + 2) * 512 + tid];
        p1 = gW[(size_t)(s + 2) * 512 + tid + 256];
      }
    }
    const __bf16* bb = &Bt[buf][0];
#pragma unroll
    for (int nt = 0; nt < 4; ++nt) {
      bf16x8 bh = *(const bf16x8*)&bb[((0 * 4 + nt) * 64 + lane) * 8];
      bf16x8 bl = *(const bf16x8*)&bb[((1 * 4 + nt) * 64 + lane) * 8];
      acc[nt] = __builtin_amdgcn_mfma_f32_32x32x16_bf16(acur, bh, acc[nt], 0, 0, 0);
      acc[nt] = __builtin_amdgcn_mfma_f32_32x32x16_bf16(acur, bl, acc[nt], 0, 0, 0);
    }
    acur = anext;
    block_sync_lds();
  }

#pragma unroll
  for (int nt = 0; nt < 4; ++nt) {
#pragma unroll
    for (int r = 0; r < 16; ++r) {
      int rowi = (r & 3) + 8 * (r >> 2) + 4 * half;
      float v = acc[nt][r] + bv1[nt] + degS[wid * 32 + rowi] * bva[nt];
      hid[wid][rowi][nt * 32 + m] = (__bf16)fmaxf(v, 0.f);
      acc[nt][r] = 0.f;
    }
  }
  wait_lds();

  for (int s = 16; s < NODE_CHUNKS; ++s) {
    int buf = s & 1;
    if (s + 1 < NODE_CHUNKS) {
      short8* sb = buf ? sB0 : sB1;
      sb[tid] = p0;
      sb[tid + 256] = p1;
      if (s + 2 < NODE_CHUNKS) {
        p0 = gW[(size_t)(s + 2) * 512 + tid];
        p1 = gW[(size_t)(s + 2) * 512 + tid + 256];
      }
    }
    bf16x8 ah = *(const bf16x8*)&hid[wid][m][(s - 16) * 16 + half * 8];
    const __bf16* bb = &Bt[buf][0];
#pragma unroll
    for (int nt = 0; nt < 4; ++nt) {
      bf16x8 bh = *(const bf16x8*)&bb[((0 * 4 + nt) * 64 + lane) * 8];
      bf16x8 bl = *(const bf16x8*)&bb[((1 * 4 + nt) * 64 + lane) * 8];
      acc[nt] = __builtin_amdgcn_mfma_f32_32x32x16_bf16(ah, bh, acc[nt], 0, 0, 0);
      acc[nt] = __builtin_amdgcn_mfma_f32_32x32x16_bf16(ah, bl, acc[nt], 0, 0, 0);
    }
    if (s + 1 < NODE_CHUNKS) block_sync_lds();
  }

#pragma unroll
  for (int nt = 0; nt < 4; ++nt) {
    float b2 = ub2[nt * 32 + m];
#pragma unroll
    for (int r = 0; r < 16; ++r) {
      int rowi = (r & 3) + 8 * (r >> 2) + 4 * half;
      size_t idx = (size_t)(nb + wid * 32 + rowi) * H + nt * 32 + m;
      float hv = (float)hb[idx];
      hb[idx] = (__bf16)(hv + acc[nt][r] + b2);
    }
  }
}

// ---------------- batch mean pooling (batch is sorted) ----------------
__global__ __launch_bounds__(128) void pool_kernel(
    const __bf16* __restrict__ hb, const int* __restrict__ batch,
    float* __restrict__ pooled, int* __restrict__ counts) {
  int j = threadIdx.x;
  int nbase = blockIdx.x * 128;
  int nend = nbase + 128;
  if (nend > NN) nend = NN;
  if (nbase >= NN) return;
  int cur = batch[nbase];
  float sum = 0.f;
  int cnt = 0;
  for (int n = nbase; n < nend; ++n) {
    int b = batch[n];
    if (b != cur) {
      unsafeAtomicAdd(&pooled[cur * H + j], sum);
      if (j == 0) atomicAdd(&counts[cur], cnt);
      sum = 0.f; cnt = 0; cur = b;
    }
    sum += (float)hb[(size_t)n * H + j];
    cnt++;
  }
  unsafeAtomicAdd(&pooled[cur * H + j], sum);
  if (j == 0) atomicAdd(&counts[cur], cnt);
}

// ---------------- readout MLP ----------------
__global__ __launch_bounds__(128) void readout_kernel(
    const float* __restrict__ pooled, const int* __restrict__ counts,
    const float* __restrict__ gf, const float* __restrict__ Wg,
    const float* __restrict__ bg, const float* __restrict__ rW1,
    const float* __restrict__ rb1, const float* __restrict__ rW2,
    const float* __restrict__ rb2, const float* __restrict__ rW3,
    const float* __restrict__ rb3, float* __restrict__ out) {
  __shared__ float fin[256];
  __shared__ float t1[128];
  __shared__ float t2[64];
  int j = threadIdx.x;
  for (int b = 0; b < NBATCH; ++b) {
    float cnt = (float)counts[b];
    if (cnt < 1.f) cnt = 1.f;
    fin[j] = pooled[b * H + j] / cnt;
    fin[H + j] = fmaf(gf[b], Wg[j], bg[j]);
    __syncthreads();
    float a = rb1[j];
    for (int k = 0; k < 256; ++k) a = fmaf(fin[k], rW1[k * H + j], a);
    t1[j] = fmaxf(a, 0.f);
    __syncthreads();
    if (j < 64) {
      float a2 = rb2[j];
      for (int k = 0; k < 128; ++k) a2 = fmaf(t1[k], rW2[k * 64 + j], a2);
      t2[j] = fmaxf(a2, 0.f);
    }
    __syncthreads();
    if (j < 64) {
      float p = t2[j] * rW3[j];
#pragma unroll
      for (int off = 32; off; off >>= 1) p += __shfl_down(p, off);
      if (j == 0) out[b] = p + rb3[0];
    }
    __syncthreads();
  }
}

extern "C" void kernel_launch(void* const* d_in, const int* in_sizes, int n_in,
                              void* d_out, int out_size, void* d_ws, size_t ws_size,
                              hipStream_t stream) {
  const float* x   = (const float*)d_in[0];
  const float* ea  = (const float*)d_in[1];
  const float* gf  = (const float*)d_in[2];
  const int*   ei  = (const int*)d_in[3];
  const int*   bat = (const int*)d_in[4];
  const float* Wn  = (const float*)d_in[5];
  const float* bn  = (const float*)d_in[6];
  const float* We  = (const float*)d_in[7];
  const float* be  = (const float*)d_in[8];
  const float* Wg  = (const float*)d_in[9];
  const float* bg  = (const float*)d_in[10];
  const float* mW1 = (const float*)d_in[11];
  const float* mb1 = (const float*)d_in[12];
  const float* mW2 = (const float*)d_in[13];
  const float* mb2 = (const float*)d_in[14];
  const float* uW1 = (const float*)d_in[15];
  const float* ub1 = (const float*)d_in[16];
  const float* uW2 = (const float*)d_in[17];
  const float* ub2 = (const float*)d_in[18];
  const float* rW1 = (const float*)d_in[19];
  const float* rb1 = (const float*)d_in[20];
  const float* rW2 = (const float*)d_in[21];
  const float* rb2 = (const float*)d_in[22];
  const float* rW3 = (const float*)d_in[23];
  const float* rb3 = (const float*)d_in[24];

  char* p = (char*)d_ws;
  __bf16* hb     = (__bf16*)p; p += (size_t)NPAD * H * 2;        // 12.8 MB
  float*  aggrH  = (float*)p;  p += (size_t)NPAD * H * 4;        // 25.6 MB
  __bf16* z      = (__bf16*)p; p += (size_t)NPAD * 256 * 2;      // 25.6 MB
  __bf16* eaSrt  = (__bf16*)p; p += (size_t)NE * EDIM * 2;       // 12.8 MB
  int*    srcSrt = (int*)p;    p += (size_t)NE * 4;
  int*    dstSrt = (int*)p;    p += (size_t)NE * 4;
  int*    eidSrt = (int*)p;    p += (size_t)NE * 4;
  __bf16* ZW     = (__bf16*)p; p += (size_t)NLAYERS * 8 * ZW_CHUNK * 2;
  __bf16* WnS    = (__bf16*)p; p += (size_t)NLAYERS * NODE_CHUNKS * CHUNK_ELEMS * 2;
  float*  Wef    = (float*)p;  p += (size_t)NLAYERS * EDIM * H * 4;
  float*  bm     = (float*)p;  p += (size_t)NLAYERS * H * 4;
  float*  Wu     = (float*)p;  p += (size_t)NLAYERS * 256 * H * 4;
  float*  va     = (float*)p;  p += (size_t)NLAYERS * H * 4;
  int*    deg    = (int*)p;    p += (size_t)NPAD * 4;
  int*    cursor = (int*)p;    p += (size_t)NPAD * 4;
  int*    bsum   = (int*)p;    p += 256 * 4;
  int*    boff   = (int*)p;    p += 256 * 4;
  float*  pooled = (float*)p;  p += (size_t)NBATCH * H * 4;
  int*    counts = (int*)p;    p += 64;

  hipMemsetAsync(deg, 0, (size_t)NPAD * 4, stream);
  hipMemsetAsync(cursor, 0, (size_t)NPAD * 4, stream);  // tail stays 0 -> empty segments for pad nodes
  hipMemsetAsync(pooled, 0, (size_t)NBATCH * H * 4, stream);
  hipMemsetAsync(counts, 0, 64, stream);

  embed_nodes_kernel<<<NN / 16, 128, 0, stream>>>(x, Wn, bn, hb);
  degree_kernel<<<(NE + 255) / 256, 256, 0, stream>>>(ei, deg);
  scan1_kernel<<<NSB, 256, 0, stream>>>(deg, bsum);
  scan2_kernel<<<1, 256, 0, stream>>>(bsum, boff);
  scan3_kernel<<<NSB, 256, 0, stream>>>(deg, boff, cursor);
  scatter_kernel<<<(NE + 255) / 256, 256, 0, stream>>>(ei, cursor, srcSrt,
                                                       dstSrt, eidSrt);
  gather_ea_kernel<<<(NE + 255) / 256, 256, 0, stream>>>(ea, eidSrt, eaSrt);
  precomp_zw_kernel<<<NLAYERS * 8, 256, 0, stream>>>(mW1, ZW);
  precomp_wef_kernel<<<NLAYERS, 128, 0, stream>>>(mW1, mb1, We, be, Wef, bm);
  precomp_wu_kernel<<<NLAYERS * 257, 128, 0, stream>>>(uW1, mW2, mb2, Wu, va);
  precomp_wns_kernel<<<NLAYERS * NODE_CHUNKS, 256, 0, stream>>>(Wu, uW2, WnS);

  for (int l = 0; l < NLAYERS; ++l) {
    zdzs_kernel<<<NBLK, 256, 0, stream>>>(
        hb, ZW + (size_t)l * 8 * ZW_CHUNK, bm + (size_t)l * H, z);
    edge_aggr_kernel<<<NPAD / 4, 256, 0, stream>>>(
        z, srcSrt, cursor, eaSrt, Wef + (size_t)l * EDIM * H, aggrH);
    node_update_mfma_kernel<<<NBLK, 256, 0, stream>>>(
        hb, aggrH, deg, WnS + (size_t)l * NODE_CHUNKS * CHUNK_ELEMS,
        ub1 + (size_t)l * H, va + (size_t)l * H, ub2 + (size_t)l * H);
  }

  pool_kernel<<<(NN + 127) / 128, 128, 0, stream>>>(hb, bat, pooled, counts);
  readout_kernel<<<1, 128, 0, stream>>>(pooled, counts, gf, Wg, bg, rW1, rb1,
                                        rW2, rb2, rW3, rb3, (float*)d_out);
}